// Round 10
// baseline (4188.124 us; speedup 1.0000x reference)
//
#include <hip/hip_runtime.h>
#include <math.h>

#define PI_D 3.14159265358979323846

// ---------------- workspace layout (float units) ----------------
#define IMG224 50176
#define IMG112 12544
// factorized DFT tables: per (N,dir): [W1:N1*N1 | W2:N2*N2 | TW:N2*N1] float2
static const size_t OFF_FT224F = 0;
static const size_t OFF_FT224I = 2048;
static const size_t OFF_FT112F = 4096;
static const size_t OFF_FT112I = 6144;
static const size_t OFF_F56I  = 250880;    // 6272 (dense 56 inverse)
static const size_t OFF_PSI   = 257152;    // 16*50176
static const size_t OFF_PHI0  = 1059968;
static const size_t OFF_PHI1  = 1110144;
static const size_t OFF_GK    = 1122688;   // 3888 keys
static const size_t OFF_XH    = 1126784;   // 4816896
static const size_t OFF_POOL  = 5943680;
// arena: A0, A1, A23 = 9633792 floats each -> ~139 MB total (< known-good 149 MB)

// ---------------- helpers ----------------
__device__ inline unsigned fkey(float v) {
    int b = __float_as_int(v);
    return (b >= 0) ? ((unsigned)b | 0x80000000u) : ~(unsigned)b;
}
__device__ inline float funkey(unsigned u) {
    int b = (u & 0x80000000u) ? (int)(u & 0x7fffffffu) : (int)~u;
    return __int_as_float(b);
}
__device__ inline void cmac(float2& a, float2 z, float2 w) {
    a.x += z.x * w.x - z.y * w.y;
    a.y += z.x * w.y + z.y * w.x;
}

// ---------------- table builders ----------------
__global__ void k_dft(float2* out, int n, double sign, double scale) {
    int i = blockIdx.x * blockDim.x + threadIdx.x;
    if (i >= n * n) return;
    int c = i / n, k = i % n;
    int m = (c * k) % n;
    double ang = sign * 2.0 * PI_D * (double)m / (double)n;
    out[i] = make_float2((float)(scale * cos(ang)), (float)(scale * sin(ang)));
}

__global__ void k_fact(float2* o, int N1, int N2, double sign, double scale) {
    int total = N1 * N1 + N2 * N2 + N2 * N1;
    int N = N1 * N2;
    for (int i = blockIdx.x * blockDim.x + threadIdx.x; i < total; i += blockDim.x * gridDim.x) {
        double ang; double sc = 1.0;
        if (i < N1 * N1) {
            int n1 = i / N1, k1 = i % N1;
            ang = sign * 2.0 * PI_D * (double)((n1 * k1) % N1) / (double)N1;
        } else if (i < N1 * N1 + N2 * N2) {
            int j = i - N1 * N1; int n2 = j / N2, k2 = j % N2;
            ang = sign * 2.0 * PI_D * (double)((n2 * k2) % N2) / (double)N2;
            sc = scale;
        } else {
            int j = i - N1 * N1 - N2 * N2; int n2 = j / N1, k1 = j % N1;
            ang = sign * 2.0 * PI_D * (double)((n2 * k1) % N) / (double)N;
        }
        o[i] = make_float2((float)(sc * cos(ang)), (float)(sc * sin(ang)));
    }
}

__global__ void k_psi(float* out) {
    int i = blockIdx.x * blockDim.x + threadIdx.x;
    if (i >= 16 * IMG224) return;
    int jl = i / IMG224, p = i % IMG224;
    int r = p / 224, c = p % 224;
    int j = jl >> 3, l = jl & 7;
    double fr = (r < 112) ? (double)r : (double)(r - 224);
    double fc = (c < 112) ? (double)c : (double)(c - 224);
    double wx = 2.0 * PI_D * fr / 224.0;
    double wy = 2.0 * PI_D * fc / 224.0;
    double theta = (double)l * PI_D / 8.0;
    double xi = (3.0 * PI_D / 4.0) / (double)(1 << j);
    double sg = 0.8 * (double)(1 << j);
    double ct = cos(theta), st = sin(theta);
    double u = ct * wx + st * wy;
    double v = -st * wx + ct * wy;
    double vs = v / 0.5;
    double s2 = 0.5 * sg * sg;
    double gab = exp(-s2 * ((u - xi) * (u - xi) + vs * vs));
    double gau = exp(-s2 * (u * u + vs * vs));
    double kap = exp(-s2 * xi * xi);
    out[i] = (float)(gab - kap * gau);
}

__global__ void k_phi(float* phi0, float* phi1) {
    int i = blockIdx.x * blockDim.x + threadIdx.x;
    const double sp = 1.6;
    const double s2 = 0.5 * sp * sp;
    if (i < IMG224) {
        int r = i / 224, c = i % 224;
        double fr = (r < 112) ? (double)r : (double)(r - 224);
        double fc = (c < 112) ? (double)c : (double)(c - 224);
        double wx = 2.0 * PI_D * fr / 224.0;
        double wy = 2.0 * PI_D * fc / 224.0;
        phi0[i] = (float)exp(-s2 * (wx * wx + wy * wy));
    } else if (i < IMG224 + IMG112) {
        int p = i - IMG224, a = p / 112, b = p % 112;
        double sum = 0.0;
        for (int ii = 0; ii < 2; ++ii)
            for (int jj = 0; jj < 2; ++jj) {
                int r = a + 112 * ii, c = b + 112 * jj;
                double fr = (r < 112) ? (double)r : (double)(r - 224);
                double fc = (c < 112) ? (double)c : (double)(c - 224);
                double wx = 2.0 * PI_D * fr / 224.0;
                double wy = 2.0 * PI_D * fc / 224.0;
                sum += exp(-s2 * (wx * wx + wy * wy));
            }
        phi1[p] = (float)(0.25 * sum);
    }
}

__global__ void k_zero(unsigned* gk, int n) {
    int i = blockIdx.x * blockDim.x + threadIdx.x;
    if (i < n) gk[i] = 0u;
}

// ---------------- rk: row pass, two-stage, single LDS buffer, no cross-barrier regs ----
// Pass1 in-place (per-thread residue-class ownership; R9-verified correct).
// Pass2 reads Z -> computes -> writes DIRECTLY to global (no LDS write, no barrier,
// no registers live across a barrier -> no scratch spill; R9's VGPR=40 spill fix).
// swzImg>0: XCD swizzle (R6: FETCH 76->16MB on F-step).
template<int N1, int N2, int TA, int FOLD, int BS, bool REAL>
__global__ __launch_bounds__(BS) void rk(
    const void* __restrict__ inBase, int inShift,
    const float* __restrict__ fltBase, int fltMask,
    const float2* __restrict__ FT, float2* __restrict__ out,
    int swzImg, int inStride, int inOff)
{
    constexpr int N = N1 * N2;
    constexpr int NIN = N * FOLD;
    constexpr int ZS = N + 2;
    __shared__ float2 Z[TA * ZS];
    const float2* W1 = FT;
    const float2* W2 = FT + N1 * N1;
    const float2* TW = FT + N1 * N1 + N2 * N2;
    const int bx = blockIdx.x, a0 = blockIdx.y * TA, t = threadIdx.x;
    int gIn, gFlt, gOut;
    if (swzImg > 0) {
        int img = bx % swzImg, sub = bx / swzImg;
        gIn = img * inStride + inOff; gFlt = sub; gOut = img * (gridDim.x / swzImg) + sub;
    } else {
        gIn = bx >> inShift; gFlt = bx & fltMask; gOut = bx;
    }

    if (REAL) {
        const float* in = (const float*)inBase + (size_t)gIn * N * N;
        for (int r = 0; r < TA; ++r)
            for (int b = t; b < N; b += BS)
                Z[r * ZS + b] = make_float2(in[(size_t)(a0 + r) * N + b], 0.f);
    } else {
        const float2* in = (const float2*)inBase + (size_t)gIn * (NIN * NIN);
        const float* flt = fltBase + (size_t)gFlt * (NIN * NIN);
        const float s = 1.0f / (float)(FOLD * FOLD);
        for (int r = 0; r < TA; ++r) {
            int a = a0 + r;
            for (int b = t; b < N; b += BS) {
                float re = 0.f, im = 0.f;
#pragma unroll
                for (int i = 0; i < FOLD; ++i)
#pragma unroll
                    for (int j = 0; j < FOLD; ++j) {
                        int idx = (a + N * i) * NIN + (b + N * j);
                        float2 v = in[idx];
                        float f = flt[idx];
                        re += v.x * f; im += v.y * f;
                    }
                Z[r * ZS + b] = make_float2(re * s, im * s);
            }
        }
    }
    __syncthreads();
    // pass 1 (in-place): thread (r,n2) owns residue class n2 of row r.
    for (int idx = t; idx < TA * N2; idx += BS) {
        int r = idx / N2, n2 = idx % N2;
        float2 v[N1];
#pragma unroll
        for (int n1 = 0; n1 < N1; ++n1) v[n1] = Z[r * ZS + n1 * N2 + n2];
#pragma unroll
        for (int k1 = 0; k1 < N1; ++k1) {
            float2 acc = make_float2(0.f, 0.f);
#pragma unroll
            for (int n1 = 0; n1 < N1; ++n1) cmac(acc, v[n1], W1[n1 * N1 + k1]);
            float2 tw = TW[n2 * N1 + k1];
            float2 o;
            o.x = acc.x * tw.x - acc.y * tw.y;
            o.y = acc.x * tw.y + acc.y * tw.x;
            Z[r * ZS + k1 * N2 + n2] = o;
        }
    }
    __syncthreads();
    // pass 2: read own slice -> compute -> write straight to global.
    // Lanes (r,k1): for fixed k2, 16 consecutive k1 lanes write 16 contiguous float2
    // (128B segments) -> acceptable coalescing; HBM is at ~10% of peak here.
    for (int idx = t; idx < TA * N1; idx += BS) {
        int r = idx / N1, k1 = idx % N1;
        float2 v[N2];
#pragma unroll
        for (int n2 = 0; n2 < N2; ++n2) v[n2] = Z[r * ZS + k1 * N2 + n2];
        float2* orow = out + ((size_t)gOut * N + (a0 + r)) * N;
#pragma unroll
        for (int k2 = 0; k2 < N2; ++k2) {
            float2 acc = make_float2(0.f, 0.f);
#pragma unroll
            for (int n2 = 0; n2 < N2; ++n2) cmac(acc, v[n2], W2[n2 * N2 + k2]);
            orow[k1 + N1 * k2] = acc;
        }
    }
}

// ---------------- ck1/ck2: split column pass (proven structure; R5/R7: do NOT fuse) ----
template<int N1, int N2, int SPLIT, int BS>
__global__ __launch_bounds__(BS) void ck1(
    const float2* __restrict__ in, const float2* __restrict__ FT, float2* __restrict__ out)
{
    constexpr int N = N1 * N2;
    constexpr int NC = N / SPLIT;
    const float2* W1 = FT;
    const float2* TW = FT + N1 * N1 + N2 * N2;
    const int g = blockIdx.x / SPLIT, half = blockIdx.x % SPLIT;
    const int n2 = blockIdx.y, t = threadIdx.x;
    if (2 * t >= NC) return;
    const int b0 = 2 * t + half * NC;
    const float2* I = in + (size_t)g * N * N;
    float2 acc[N1][2];
#pragma unroll
    for (int k1 = 0; k1 < N1; ++k1) { acc[k1][0] = make_float2(0.f, 0.f); acc[k1][1] = make_float2(0.f, 0.f); }
    for (int n1 = 0; n1 < N1; ++n1) {
        float4 v = *reinterpret_cast<const float4*>(&I[(size_t)(n1 * N2 + n2) * N + b0]);
        float2 v0 = make_float2(v.x, v.y), v1 = make_float2(v.z, v.w);
#pragma unroll
        for (int k1 = 0; k1 < N1; ++k1) {
            float2 w = W1[n1 * N1 + k1];
            cmac(acc[k1][0], v0, w);
            cmac(acc[k1][1], v1, w);
        }
    }
#pragma unroll
    for (int k1 = 0; k1 < N1; ++k1) {
        float2 tw = TW[n2 * N1 + k1];
        float2 a0, a1;
        a0.x = acc[k1][0].x * tw.x - acc[k1][0].y * tw.y;
        a0.y = acc[k1][0].x * tw.y + acc[k1][0].y * tw.x;
        a1.x = acc[k1][1].x * tw.x - acc[k1][1].y * tw.y;
        a1.y = acc[k1][1].x * tw.y + acc[k1][1].y * tw.x;
        *reinterpret_cast<float4*>(&out[((size_t)g * N + (k1 * N2 + n2)) * N + b0]) =
            make_float4(a0.x, a0.y, a1.x, a1.y);
    }
}

template<int N1, int N2, int SPLIT, int MODE, int BS>
__global__ __launch_bounds__(BS) void ck2(
    const float2* __restrict__ in, const float2* __restrict__ FT,
    float2* __restrict__ outc, float* __restrict__ outr)
{
    constexpr int N = N1 * N2;
    constexpr int NC = N / SPLIT;
    const float2* W2 = FT + N1 * N1;
    const int g = blockIdx.x / SPLIT, half = blockIdx.x % SPLIT;
    const int k1 = blockIdx.y, t = threadIdx.x;
    if (2 * t >= NC) return;
    const int b0 = 2 * t + half * NC;
    const float2* I = in + (size_t)g * N * N;
    float2 acc[N2][2];
#pragma unroll
    for (int k2 = 0; k2 < N2; ++k2) { acc[k2][0] = make_float2(0.f, 0.f); acc[k2][1] = make_float2(0.f, 0.f); }
    for (int n2 = 0; n2 < N2; ++n2) {
        float4 v = *reinterpret_cast<const float4*>(&I[(size_t)(k1 * N2 + n2) * N + b0]);
        float2 v0 = make_float2(v.x, v.y), v1 = make_float2(v.z, v.w);
#pragma unroll
        for (int k2 = 0; k2 < N2; ++k2) {
            float2 w = W2[n2 * N2 + k2];
            cmac(acc[k2][0], v0, w);
            cmac(acc[k2][1], v1, w);
        }
    }
    if (MODE == 0) {
#pragma unroll
        for (int k2 = 0; k2 < N2; ++k2)
            *reinterpret_cast<float4*>(&outc[((size_t)g * N + (k1 + N1 * k2)) * N + b0]) =
                make_float4(acc[k2][0].x, acc[k2][0].y, acc[k2][1].x, acc[k2][1].y);
    } else {
#pragma unroll
        for (int k2 = 0; k2 < N2; ++k2) {
            size_t o = ((size_t)g * N + (k1 + N1 * k2)) * N + b0;
            outr[o]     = sqrtf(acc[k2][0].x * acc[k2][0].x + acc[k2][0].y * acc[k2][0].y);
            outr[o + 1] = sqrtf(acc[k2][1].x * acc[k2][1].x + acc[k2][1].y * acc[k2][1].y);
        }
    }
}

// ---------------- 56-res dense kernels (R6-proven) ----------------
template<int NOUT, int FOLD, int TA, int BS>
__global__ __launch_bounds__(BS) void rowpass_c(
    const float2* __restrict__ inBase, int inShift,
    const float* __restrict__ fltBase, int fltMask,
    const float2* __restrict__ W, float2* __restrict__ out)
{
    constexpr int NIN = NOUT * FOLD;
    __shared__ float2 Z[TA * NOUT];
    const int g = blockIdx.x;
    const int a0 = blockIdx.y * TA;
    const float2* in = inBase + (size_t)(g >> inShift) * (NIN * NIN);
    const float* flt = fltBase + (size_t)(g & fltMask) * (NIN * NIN);
    const int t = threadIdx.x;
    const float s = 1.0f / (float)(FOLD * FOLD);
    for (int r = 0; r < TA; ++r) {
        const int a = a0 + r;
        for (int b = t; b < NOUT; b += BS) {
            float re = 0.f, im = 0.f;
#pragma unroll
            for (int i = 0; i < FOLD; ++i)
#pragma unroll
                for (int j = 0; j < FOLD; ++j) {
                    const int idx = (a + NOUT * i) * NIN + (b + NOUT * j);
                    float2 v = in[idx];
                    float f = flt[idx];
                    re += v.x * f; im += v.y * f;
                }
            Z[r * NOUT + b] = make_float2(re * s, im * s);
        }
    }
    __syncthreads();
    const int k0 = 2 * t;
    if (k0 < NOUT) {
        float2 acc[TA][2];
#pragma unroll
        for (int r = 0; r < TA; ++r) {
            acc[r][0] = make_float2(0.f, 0.f);
            acc[r][1] = make_float2(0.f, 0.f);
        }
        for (int b = 0; b < NOUT; ++b) {
            float4 w = *reinterpret_cast<const float4*>(&W[b * NOUT + k0]);
#pragma unroll
            for (int r = 0; r < TA; ++r) {
                float2 z = Z[r * NOUT + b];
                acc[r][0].x += z.x * w.x - z.y * w.y;
                acc[r][0].y += z.x * w.y + z.y * w.x;
                acc[r][1].x += z.x * w.z - z.y * w.w;
                acc[r][1].y += z.x * w.w + z.y * w.z;
            }
        }
        float2* o = out + ((size_t)g * NOUT + a0) * NOUT + k0;
#pragma unroll
        for (int r = 0; r < TA; ++r)
            *reinterpret_cast<float4*>(&o[(size_t)r * NOUT]) =
                make_float4(acc[r][0].x, acc[r][0].y, acc[r][1].x, acc[r][1].y);
    }
}

template<int N, int TK, int BS>
__global__ __launch_bounds__(BS) void colpass_max(
    const float2* __restrict__ in, const float2* __restrict__ W,
    unsigned* __restrict__ gk, int slotBase, int slotShift, int slotMask)
{
    __shared__ float2 Wl[N * TK];
    const int g = blockIdx.x;
    const int k0 = blockIdx.y * TK;
    const float2* I = in + (size_t)g * (N * N);
    const int t = threadIdx.x;
    for (int idx = t; idx < N * TK; idx += BS) {
        int a = idx / TK, kt = idx % TK;
        Wl[idx] = W[a * N + k0 + kt];
    }
    __syncthreads();
    const int b0 = 2 * t;
    float m = -INFINITY;
    if (b0 < N) {
        float2 acc[TK][2];
#pragma unroll
        for (int kt = 0; kt < TK; ++kt) {
            acc[kt][0] = make_float2(0.f, 0.f);
            acc[kt][1] = make_float2(0.f, 0.f);
        }
        for (int a = 0; a < N; ++a) {
            float4 v = *reinterpret_cast<const float4*>(&I[(size_t)a * N + b0]);
#pragma unroll
            for (int kt = 0; kt < TK; ++kt) {
                float2 w = Wl[a * TK + kt];
                acc[kt][0].x += w.x * v.x - w.y * v.y;
                acc[kt][1].x += w.x * v.z - w.y * v.w;
            }
        }
#pragma unroll
        for (int kt = 0; kt < TK; ++kt)
            m = fmaxf(m, fmaxf(acc[kt][0].x, acc[kt][1].x));
    }
    for (int off = 32; off > 0; off >>= 1)
        m = fmaxf(m, __shfl_down(m, off, 64));
    if (t == 0) {
        int slot = slotBase + ((g >> slotShift) * 81) + (g & slotMask);
        atomicMax(&gk[slot], fkey(m));
    }
}

// ---------------- classifier head ----------------
__global__ void k_linear(const unsigned* __restrict__ gk, const float* __restrict__ Wl,
                         const float* __restrict__ bl, float* __restrict__ out)
{
    int i = blockIdx.x * blockDim.x + threadIdx.x;
    if (i >= 16 * 1000) return;
    int b = i / 1000, o = i % 1000;
    float s = bl[o];
    for (int f = 0; f < 243; ++f)
        s += funkey(gk[b * 243 + f]) * Wl[o * 243 + f];
    out[i] = s;
}

// ---------------- launch ----------------
extern "C" void kernel_launch(void* const* d_in, const int* in_sizes, int n_in,
                              void* d_out, int out_size, void* d_ws, size_t ws_size,
                              hipStream_t stream)
{
    const float* x  = (const float*)d_in[0];
    const float* Wl = (const float*)d_in[1];
    const float* bl = (const float*)d_in[2];
    float* out = (float*)d_out;
    float* ws = (float*)d_ws;

    float2* FT224F = (float2*)(ws + OFF_FT224F);
    float2* FT224I = (float2*)(ws + OFF_FT224I);
    float2* FT112F = (float2*)(ws + OFF_FT112F);
    float2* FT112I = (float2*)(ws + OFF_FT112I);
    float2* F56I  = (float2*)(ws + OFF_F56I);
    float* PSI0 = ws + OFF_PSI;
    float* PSI1 = ws + OFF_PSI + 8 * IMG224;
    float* PHI0 = ws + OFF_PHI0;
    float* PHI1 = ws + OFF_PHI1;
    unsigned* GK = (unsigned*)(ws + OFF_GK);
    float2* XH  = (float2*)(ws + OFF_XH);
    float* A0  = ws + OFF_POOL;          // 9633792 floats
    float* A1  = A0 + 9633792;           // 9633792
    float* A23 = A1 + 9633792;           // 9633792

    // tables
    k_fact<<<4, 256, 0, stream>>>(FT224F, 16, 14, -1.0, 1.0);
    k_fact<<<4, 256, 0, stream>>>(FT224I, 16, 14,  1.0, 1.0 / 224.0);
    k_fact<<<4, 256, 0, stream>>>(FT112F, 16, 7,  -1.0, 1.0);
    k_fact<<<4, 256, 0, stream>>>(FT112I, 16, 7,   1.0, 1.0 / 112.0);
    k_dft<<<(56*56 + 255) / 256, 256, 0, stream>>>(F56I, 56, 1.0, 1.0 / 56.0);
    k_psi<<<(16 * IMG224 + 255) / 256, 256, 0, stream>>>(ws + OFF_PSI);
    k_phi<<<(IMG224 + IMG112 + 255) / 256, 256, 0, stream>>>(PHI0, PHI1);
    k_zero<<<(3888 + 255) / 256, 256, 0, stream>>>(GK, 3888);

    // ---- fft2(x) -> XH ----
    rk<16, 14, 8, 1, 128, true><<<dim3(48, 28), 128, 0, stream>>>(x, 0, nullptr, 0, FT224F, (float2*)A0, 0, 0, 0);
    ck1<16, 14, 2, 64><<<dim3(96, 14), 64, 0, stream>>>((float2*)A0, FT224F, (float2*)A1);
    ck2<16, 14, 2, 0, 64><<<dim3(96, 16), 64, 0, stream>>>((float2*)A1, FT224F, XH, nullptr);

    // ---- s0 -> GK slot img*81+0 ----
    rowpass_c<56, 4, 8, 64><<<dim3(48, 7), 64, 0, stream>>>(XH, 0, PHI0, 0, F56I, (float2*)A1);
    colpass_max<56, 8, 64><<<dim3(48, 7), 64, 0, stream>>>((float2*)A1, F56I, GK, 0, 0, 0);

    // ---- pair-batched first order j1=0 (+ second order); g = img*2 + lc, l1 = 2c+lc ----
    for (int c = 0; c < 4; ++c) {
        // A: ifft rows of xh*psi0[l1] -> A0 (96 groups)
        rk<16, 14, 8, 1, 128, false><<<dim3(96, 28), 128, 0, stream>>>(
            XH, 1, PSI0 + (size_t)(2 * c) * IMG224, 1, FT224I, (float2*)A0, 0, 0, 0);
        // B: ifft cols + |.| -> A23 (real u1)
        ck1<16, 14, 2, 64><<<dim3(192, 14), 64, 0, stream>>>((float2*)A0, FT224I, (float2*)A1);
        ck2<16, 14, 2, 1, 64><<<dim3(192, 16), 64, 0, stream>>>((float2*)A1, FT224I, nullptr, A23);
        // C: fft rows of u1 (real) -> A0
        rk<16, 14, 8, 1, 128, true><<<dim3(96, 28), 128, 0, stream>>>(A23, 0, nullptr, 0, FT224F, (float2*)A0, 0, 0, 0);
        // D: fft cols -> V1 (A0)
        ck1<16, 14, 2, 64><<<dim3(192, 14), 64, 0, stream>>>((float2*)A0, FT224F, (float2*)A1);
        ck2<16, 14, 2, 0, 64><<<dim3(192, 16), 64, 0, stream>>>((float2*)A1, FT224F, (float2*)A0, nullptr);
        // E: s1 -> GK slot img*81 + 1 + 2c + lc
        rowpass_c<56, 4, 8, 64><<<dim3(96, 7), 64, 0, stream>>>((float2*)A0, 0, PHI0, 0, F56I, (float2*)A1);
        colpass_max<56, 8, 64><<<dim3(96, 7), 64, 0, stream>>>((float2*)A1, F56I, GK, 1 + 2 * c, 1, 1);
        // second order per l1 in pair (V1 stays live in A0)
        for (int lc = 0; lc < 2; ++lc) {
            int l1 = 2 * c + lc;
            // F: ifft112 rows of fold(V1*psi1[l2],2) [XCD swizzle] -> A1
            rk<16, 7, 16, 2, 128, false><<<dim3(384, 7), 128, 0, stream>>>(
                (float2*)A0, 0, PSI1, 7, FT112I, (float2*)A1, 48, 2, lc);
            // G: ifft112 cols + |.| : A1 -> A23 (stage1) -> A1 (real u2)
            ck1<16, 7, 1, 64><<<dim3(384, 7), 64, 0, stream>>>((float2*)A1, FT112I, (float2*)A23);
            ck2<16, 7, 1, 1, 64><<<dim3(384, 16), 64, 0, stream>>>((float2*)A23, FT112I, nullptr, A1);
            // H: fft112 rows of u2 (real) -> A23
            rk<16, 7, 16, 1, 128, true><<<dim3(384, 7), 128, 0, stream>>>(A1, 0, nullptr, 0, FT112F, (float2*)A23, 0, 0, 0);
            // I: fft112 cols: A23 -> A1 (stage1) -> A23 (u2h)
            ck1<16, 7, 1, 64><<<dim3(384, 7), 64, 0, stream>>>((float2*)A23, FT112F, (float2*)A1);
            ck2<16, 7, 1, 0, 64><<<dim3(384, 16), 64, 0, stream>>>((float2*)A1, FT112F, (float2*)A23, nullptr);
            // JK: s2 -> GK slot img*81 + 17 + 8*l1 + l2
            rowpass_c<56, 2, 8, 64><<<dim3(384, 7), 64, 0, stream>>>((float2*)A23, 0, PHI1, 0, F56I, (float2*)A1);
            colpass_max<56, 8, 64><<<dim3(384, 7), 64, 0, stream>>>((float2*)A1, F56I, GK, 17 + 8 * l1, 3, 7);
        }
    }

    // ---- first order j1=1 (8 orientations, g = img*8+l) ----
    rk<16, 7, 16, 2, 128, false><<<dim3(384, 7), 128, 0, stream>>>(XH, 0, PSI1, 7, FT112I, (float2*)A1, 48, 1, 0);
    ck1<16, 7, 1, 64><<<dim3(384, 7), 64, 0, stream>>>((float2*)A1, FT112I, (float2*)A23);
    ck2<16, 7, 1, 1, 64><<<dim3(384, 16), 64, 0, stream>>>((float2*)A23, FT112I, nullptr, A1);
    rk<16, 7, 16, 1, 128, true><<<dim3(384, 7), 128, 0, stream>>>(A1, 0, nullptr, 0, FT112F, (float2*)A23, 0, 0, 0);
    ck1<16, 7, 1, 64><<<dim3(384, 7), 64, 0, stream>>>((float2*)A23, FT112F, (float2*)A1);
    ck2<16, 7, 1, 0, 64><<<dim3(384, 16), 64, 0, stream>>>((float2*)A1, FT112F, (float2*)A23, nullptr);
    rowpass_c<56, 2, 8, 64><<<dim3(384, 7), 64, 0, stream>>>((float2*)A23, 0, PHI1, 0, F56I, (float2*)A1);
    colpass_max<56, 8, 64><<<dim3(384, 7), 64, 0, stream>>>((float2*)A1, F56I, GK, 9, 3, 7);

    // head
    k_linear<<<(16000 + 255) / 256, 256, 0, stream>>>(GK, Wl, bl, out);
}

// Round 11
// 3259.149 us; speedup vs baseline: 1.2850x; 1.2850x over previous
//
#include <hip/hip_runtime.h>
#include <math.h>

#define PI_D 3.14159265358979323846

// ---------------- workspace layout (float units) ----------------
#define IMG224 50176
#define IMG112 12544
// factorized DFT tables: per (N,dir): [W1:N1*N1 | W2:N2*N2 | TW:N2*N1] float2
static const size_t OFF_FT224F = 0;
static const size_t OFF_FT224I = 2048;
static const size_t OFF_FT112F = 4096;
static const size_t OFF_FT112I = 6144;
static const size_t OFF_F56I  = 250880;    // 6272 (dense 56 inverse)
static const size_t OFF_PSI   = 257152;    // 16*50176
static const size_t OFF_PHI0  = 1059968;
static const size_t OFF_PHI1  = 1110144;
static const size_t OFF_GK    = 1122688;   // 3888 keys
static const size_t OFF_XH    = 1126784;   // 4816896
static const size_t OFF_POOL  = 5943680;
// arena: A0, A1, A23 = 9633792 floats each -> ~139 MB total (< known-good 149 MB)

// ---------------- helpers ----------------
__device__ inline unsigned fkey(float v) {
    int b = __float_as_int(v);
    return (b >= 0) ? ((unsigned)b | 0x80000000u) : ~(unsigned)b;
}
__device__ inline float funkey(unsigned u) {
    int b = (u & 0x80000000u) ? (int)(u & 0x7fffffffu) : (int)~u;
    return __int_as_float(b);
}
__device__ inline void cmac(float2& a, float2 z, float2 w) {
    a.x += z.x * w.x - z.y * w.y;
    a.y += z.x * w.y + z.y * w.x;
}

// ---------------- table builders ----------------
__global__ void k_dft(float2* out, int n, double sign, double scale) {
    int i = blockIdx.x * blockDim.x + threadIdx.x;
    if (i >= n * n) return;
    int c = i / n, k = i % n;
    int m = (c * k) % n;
    double ang = sign * 2.0 * PI_D * (double)m / (double)n;
    out[i] = make_float2((float)(scale * cos(ang)), (float)(scale * sin(ang)));
}

__global__ void k_fact(float2* o, int N1, int N2, double sign, double scale) {
    int total = N1 * N1 + N2 * N2 + N2 * N1;
    int N = N1 * N2;
    for (int i = blockIdx.x * blockDim.x + threadIdx.x; i < total; i += blockDim.x * gridDim.x) {
        double ang; double sc = 1.0;
        if (i < N1 * N1) {
            int n1 = i / N1, k1 = i % N1;
            ang = sign * 2.0 * PI_D * (double)((n1 * k1) % N1) / (double)N1;
        } else if (i < N1 * N1 + N2 * N2) {
            int j = i - N1 * N1; int n2 = j / N2, k2 = j % N2;
            ang = sign * 2.0 * PI_D * (double)((n2 * k2) % N2) / (double)N2;
            sc = scale;
        } else {
            int j = i - N1 * N1 - N2 * N2; int n2 = j / N1, k1 = j % N1;
            ang = sign * 2.0 * PI_D * (double)((n2 * k1) % N) / (double)N;
        }
        o[i] = make_float2((float)(sc * cos(ang)), (float)(sc * sin(ang)));
    }
}

__global__ void k_psi(float* out) {
    int i = blockIdx.x * blockDim.x + threadIdx.x;
    if (i >= 16 * IMG224) return;
    int jl = i / IMG224, p = i % IMG224;
    int r = p / 224, c = p % 224;
    int j = jl >> 3, l = jl & 7;
    double fr = (r < 112) ? (double)r : (double)(r - 224);
    double fc = (c < 112) ? (double)c : (double)(c - 224);
    double wx = 2.0 * PI_D * fr / 224.0;
    double wy = 2.0 * PI_D * fc / 224.0;
    double theta = (double)l * PI_D / 8.0;
    double xi = (3.0 * PI_D / 4.0) / (double)(1 << j);
    double sg = 0.8 * (double)(1 << j);
    double ct = cos(theta), st = sin(theta);
    double u = ct * wx + st * wy;
    double v = -st * wx + ct * wy;
    double vs = v / 0.5;
    double s2 = 0.5 * sg * sg;
    double gab = exp(-s2 * ((u - xi) * (u - xi) + vs * vs));
    double gau = exp(-s2 * (u * u + vs * vs));
    double kap = exp(-s2 * xi * xi);
    out[i] = (float)(gab - kap * gau);
}

__global__ void k_phi(float* phi0, float* phi1) {
    int i = blockIdx.x * blockDim.x + threadIdx.x;
    const double sp = 1.6;
    const double s2 = 0.5 * sp * sp;
    if (i < IMG224) {
        int r = i / 224, c = i % 224;
        double fr = (r < 112) ? (double)r : (double)(r - 224);
        double fc = (c < 112) ? (double)c : (double)(c - 224);
        double wx = 2.0 * PI_D * fr / 224.0;
        double wy = 2.0 * PI_D * fc / 224.0;
        phi0[i] = (float)exp(-s2 * (wx * wx + wy * wy));
    } else if (i < IMG224 + IMG112) {
        int p = i - IMG224, a = p / 112, b = p % 112;
        double sum = 0.0;
        for (int ii = 0; ii < 2; ++ii)
            for (int jj = 0; jj < 2; ++jj) {
                int r = a + 112 * ii, c = b + 112 * jj;
                double fr = (r < 112) ? (double)r : (double)(r - 224);
                double fc = (c < 112) ? (double)c : (double)(c - 224);
                double wx = 2.0 * PI_D * fr / 224.0;
                double wy = 2.0 * PI_D * fc / 224.0;
                sum += exp(-s2 * (wx * wx + wy * wy));
            }
        phi1[p] = (float)(0.25 * sum);
    }
}

__global__ void k_zero(unsigned* gk, int n) {
    int i = blockIdx.x * blockDim.x + threadIdx.x;
    if (i < n) gk[i] = 0u;
}

// ---------------- rk: row pass, two-stage (N=N1*N2), fused in LDS ----------------
// R8-proven structure (separate Z+T, VGPR=128, no spill). R9/R10 lesson: the in-place
// variant triggers a VGPR=40 allocation + 2.5x VALU issue — do NOT in-place this.
// R11: TA halved vs R8 (224:8->4, 112:16->8) => LDS 29.7->14.8KB, occupancy cap
// 5->8 blocks/CU (VGPR-capped), same per-thread code shape.
// swzImg>0: XCD swizzle (R6: FETCH 76->16MB on F-step).
template<int N1, int N2, int TA, int FOLD, int BS, bool REAL>
__global__ __launch_bounds__(BS) void rk(
    const void* __restrict__ inBase, int inShift,
    const float* __restrict__ fltBase, int fltMask,
    const float2* __restrict__ FT, float2* __restrict__ out,
    int swzImg, int inStride, int inOff)
{
    constexpr int N = N1 * N2;
    constexpr int NIN = N * FOLD;
    constexpr int ZS = N + 2;
    constexpr int TS = N2 * (N1 + 1);
    __shared__ float2 Z[TA * ZS];
    __shared__ float2 T[TA * TS];
    const float2* W1 = FT;
    const float2* W2 = FT + N1 * N1;
    const float2* TW = FT + N1 * N1 + N2 * N2;
    const int bx = blockIdx.x, a0 = blockIdx.y * TA, t = threadIdx.x;
    int gIn, gFlt, gOut;
    if (swzImg > 0) {
        int img = bx % swzImg, sub = bx / swzImg;
        gIn = img * inStride + inOff; gFlt = sub; gOut = img * (gridDim.x / swzImg) + sub;
    } else {
        gIn = bx >> inShift; gFlt = bx & fltMask; gOut = bx;
    }

    if (REAL) {
        const float* in = (const float*)inBase + (size_t)gIn * N * N;
        for (int r = 0; r < TA; ++r)
            for (int b = t; b < N; b += BS)
                Z[r * ZS + b] = make_float2(in[(size_t)(a0 + r) * N + b], 0.f);
    } else {
        const float2* in = (const float2*)inBase + (size_t)gIn * (NIN * NIN);
        const float* flt = fltBase + (size_t)gFlt * (NIN * NIN);
        const float s = 1.0f / (float)(FOLD * FOLD);
        for (int r = 0; r < TA; ++r) {
            int a = a0 + r;
            for (int b = t; b < N; b += BS) {
                float re = 0.f, im = 0.f;
#pragma unroll
                for (int i = 0; i < FOLD; ++i)
#pragma unroll
                    for (int j = 0; j < FOLD; ++j) {
                        int idx = (a + N * i) * NIN + (b + N * j);
                        float2 v = in[idx];
                        float f = flt[idx];
                        re += v.x * f; im += v.y * f;
                    }
                Z[r * ZS + b] = make_float2(re * s, im * s);
            }
        }
    }
    __syncthreads();
    // pass 1: (r,n2) -> T[r][n2][k1]
    for (int idx = t; idx < TA * N2; idx += BS) {
        int r = idx / N2, n2 = idx % N2;
        float2 acc[N1];
#pragma unroll
        for (int k1 = 0; k1 < N1; ++k1) acc[k1] = make_float2(0.f, 0.f);
        for (int n1 = 0; n1 < N1; ++n1) {
            float2 zv = Z[r * ZS + n1 * N2 + n2];
#pragma unroll
            for (int k1 = 0; k1 < N1; ++k1) cmac(acc[k1], zv, W1[n1 * N1 + k1]);
        }
#pragma unroll
        for (int k1 = 0; k1 < N1; ++k1) {
            float2 tw = TW[n2 * N1 + k1];
            float2 a2;
            a2.x = acc[k1].x * tw.x - acc[k1].y * tw.y;
            a2.y = acc[k1].x * tw.y + acc[k1].y * tw.x;
            T[r * TS + n2 * (N1 + 1) + k1] = a2;
        }
    }
    __syncthreads();
    // pass 2: (r,k1) -> Z[r][k1+N1*k2]
    for (int idx = t; idx < TA * N1; idx += BS) {
        int r = idx / N1, k1 = idx % N1;
        float2 acc[N2];
#pragma unroll
        for (int k2 = 0; k2 < N2; ++k2) acc[k2] = make_float2(0.f, 0.f);
        for (int n2 = 0; n2 < N2; ++n2) {
            float2 tv = T[r * TS + n2 * (N1 + 1) + k1];
#pragma unroll
            for (int k2 = 0; k2 < N2; ++k2) cmac(acc[k2], tv, W2[n2 * N2 + k2]);
        }
#pragma unroll
        for (int k2 = 0; k2 < N2; ++k2) Z[r * ZS + k1 + N1 * k2] = acc[k2];
    }
    __syncthreads();
    for (int r = 0; r < TA; ++r) {
        float2* o = out + ((size_t)gOut * N + (a0 + r)) * N;
        for (int b = t; b < N; b += BS) o[b] = Z[r * ZS + b];
    }
}

// ---------------- ck1/ck2: split column pass (proven structure; R5/R7: do NOT fuse) ----
template<int N1, int N2, int SPLIT, int BS>
__global__ __launch_bounds__(BS) void ck1(
    const float2* __restrict__ in, const float2* __restrict__ FT, float2* __restrict__ out)
{
    constexpr int N = N1 * N2;
    constexpr int NC = N / SPLIT;
    const float2* W1 = FT;
    const float2* TW = FT + N1 * N1 + N2 * N2;
    const int g = blockIdx.x / SPLIT, half = blockIdx.x % SPLIT;
    const int n2 = blockIdx.y, t = threadIdx.x;
    if (2 * t >= NC) return;
    const int b0 = 2 * t + half * NC;
    const float2* I = in + (size_t)g * N * N;
    float2 acc[N1][2];
#pragma unroll
    for (int k1 = 0; k1 < N1; ++k1) { acc[k1][0] = make_float2(0.f, 0.f); acc[k1][1] = make_float2(0.f, 0.f); }
    for (int n1 = 0; n1 < N1; ++n1) {
        float4 v = *reinterpret_cast<const float4*>(&I[(size_t)(n1 * N2 + n2) * N + b0]);
        float2 v0 = make_float2(v.x, v.y), v1 = make_float2(v.z, v.w);
#pragma unroll
        for (int k1 = 0; k1 < N1; ++k1) {
            float2 w = W1[n1 * N1 + k1];
            cmac(acc[k1][0], v0, w);
            cmac(acc[k1][1], v1, w);
        }
    }
#pragma unroll
    for (int k1 = 0; k1 < N1; ++k1) {
        float2 tw = TW[n2 * N1 + k1];
        float2 a0, a1;
        a0.x = acc[k1][0].x * tw.x - acc[k1][0].y * tw.y;
        a0.y = acc[k1][0].x * tw.y + acc[k1][0].y * tw.x;
        a1.x = acc[k1][1].x * tw.x - acc[k1][1].y * tw.y;
        a1.y = acc[k1][1].x * tw.y + acc[k1][1].y * tw.x;
        *reinterpret_cast<float4*>(&out[((size_t)g * N + (k1 * N2 + n2)) * N + b0]) =
            make_float4(a0.x, a0.y, a1.x, a1.y);
    }
}

template<int N1, int N2, int SPLIT, int MODE, int BS>
__global__ __launch_bounds__(BS) void ck2(
    const float2* __restrict__ in, const float2* __restrict__ FT,
    float2* __restrict__ outc, float* __restrict__ outr)
{
    constexpr int N = N1 * N2;
    constexpr int NC = N / SPLIT;
    const float2* W2 = FT + N1 * N1;
    const int g = blockIdx.x / SPLIT, half = blockIdx.x % SPLIT;
    const int k1 = blockIdx.y, t = threadIdx.x;
    if (2 * t >= NC) return;
    const int b0 = 2 * t + half * NC;
    const float2* I = in + (size_t)g * N * N;
    float2 acc[N2][2];
#pragma unroll
    for (int k2 = 0; k2 < N2; ++k2) { acc[k2][0] = make_float2(0.f, 0.f); acc[k2][1] = make_float2(0.f, 0.f); }
    for (int n2 = 0; n2 < N2; ++n2) {
        float4 v = *reinterpret_cast<const float4*>(&I[(size_t)(k1 * N2 + n2) * N + b0]);
        float2 v0 = make_float2(v.x, v.y), v1 = make_float2(v.z, v.w);
#pragma unroll
        for (int k2 = 0; k2 < N2; ++k2) {
            float2 w = W2[n2 * N2 + k2];
            cmac(acc[k2][0], v0, w);
            cmac(acc[k2][1], v1, w);
        }
    }
    if (MODE == 0) {
#pragma unroll
        for (int k2 = 0; k2 < N2; ++k2)
            *reinterpret_cast<float4*>(&outc[((size_t)g * N + (k1 + N1 * k2)) * N + b0]) =
                make_float4(acc[k2][0].x, acc[k2][0].y, acc[k2][1].x, acc[k2][1].y);
    } else {
#pragma unroll
        for (int k2 = 0; k2 < N2; ++k2) {
            size_t o = ((size_t)g * N + (k1 + N1 * k2)) * N + b0;
            outr[o]     = sqrtf(acc[k2][0].x * acc[k2][0].x + acc[k2][0].y * acc[k2][0].y);
            outr[o + 1] = sqrtf(acc[k2][1].x * acc[k2][1].x + acc[k2][1].y * acc[k2][1].y);
        }
    }
}

// ---------------- 56-res dense kernels (R6-proven) ----------------
template<int NOUT, int FOLD, int TA, int BS>
__global__ __launch_bounds__(BS) void rowpass_c(
    const float2* __restrict__ inBase, int inShift,
    const float* __restrict__ fltBase, int fltMask,
    const float2* __restrict__ W, float2* __restrict__ out)
{
    constexpr int NIN = NOUT * FOLD;
    __shared__ float2 Z[TA * NOUT];
    const int g = blockIdx.x;
    const int a0 = blockIdx.y * TA;
    const float2* in = inBase + (size_t)(g >> inShift) * (NIN * NIN);
    const float* flt = fltBase + (size_t)(g & fltMask) * (NIN * NIN);
    const int t = threadIdx.x;
    const float s = 1.0f / (float)(FOLD * FOLD);
    for (int r = 0; r < TA; ++r) {
        const int a = a0 + r;
        for (int b = t; b < NOUT; b += BS) {
            float re = 0.f, im = 0.f;
#pragma unroll
            for (int i = 0; i < FOLD; ++i)
#pragma unroll
                for (int j = 0; j < FOLD; ++j) {
                    const int idx = (a + NOUT * i) * NIN + (b + NOUT * j);
                    float2 v = in[idx];
                    float f = flt[idx];
                    re += v.x * f; im += v.y * f;
                }
            Z[r * NOUT + b] = make_float2(re * s, im * s);
        }
    }
    __syncthreads();
    const int k0 = 2 * t;
    if (k0 < NOUT) {
        float2 acc[TA][2];
#pragma unroll
        for (int r = 0; r < TA; ++r) {
            acc[r][0] = make_float2(0.f, 0.f);
            acc[r][1] = make_float2(0.f, 0.f);
        }
        for (int b = 0; b < NOUT; ++b) {
            float4 w = *reinterpret_cast<const float4*>(&W[b * NOUT + k0]);
#pragma unroll
            for (int r = 0; r < TA; ++r) {
                float2 z = Z[r * NOUT + b];
                acc[r][0].x += z.x * w.x - z.y * w.y;
                acc[r][0].y += z.x * w.y + z.y * w.x;
                acc[r][1].x += z.x * w.z - z.y * w.w;
                acc[r][1].y += z.x * w.w + z.y * w.z;
            }
        }
        float2* o = out + ((size_t)g * NOUT + a0) * NOUT + k0;
#pragma unroll
        for (int r = 0; r < TA; ++r)
            *reinterpret_cast<float4*>(&o[(size_t)r * NOUT]) =
                make_float4(acc[r][0].x, acc[r][0].y, acc[r][1].x, acc[r][1].y);
    }
}

template<int N, int TK, int BS>
__global__ __launch_bounds__(BS) void colpass_max(
    const float2* __restrict__ in, const float2* __restrict__ W,
    unsigned* __restrict__ gk, int slotBase, int slotShift, int slotMask)
{
    __shared__ float2 Wl[N * TK];
    const int g = blockIdx.x;
    const int k0 = blockIdx.y * TK;
    const float2* I = in + (size_t)g * (N * N);
    const int t = threadIdx.x;
    for (int idx = t; idx < N * TK; idx += BS) {
        int a = idx / TK, kt = idx % TK;
        Wl[idx] = W[a * N + k0 + kt];
    }
    __syncthreads();
    const int b0 = 2 * t;
    float m = -INFINITY;
    if (b0 < N) {
        float2 acc[TK][2];
#pragma unroll
        for (int kt = 0; kt < TK; ++kt) {
            acc[kt][0] = make_float2(0.f, 0.f);
            acc[kt][1] = make_float2(0.f, 0.f);
        }
        for (int a = 0; a < N; ++a) {
            float4 v = *reinterpret_cast<const float4*>(&I[(size_t)a * N + b0]);
#pragma unroll
            for (int kt = 0; kt < TK; ++kt) {
                float2 w = Wl[a * TK + kt];
                acc[kt][0].x += w.x * v.x - w.y * v.y;
                acc[kt][1].x += w.x * v.z - w.y * v.w;
            }
        }
#pragma unroll
        for (int kt = 0; kt < TK; ++kt)
            m = fmaxf(m, fmaxf(acc[kt][0].x, acc[kt][1].x));
    }
    for (int off = 32; off > 0; off >>= 1)
        m = fmaxf(m, __shfl_down(m, off, 64));
    if (t == 0) {
        int slot = slotBase + ((g >> slotShift) * 81) + (g & slotMask);
        atomicMax(&gk[slot], fkey(m));
    }
}

// ---------------- classifier head ----------------
__global__ void k_linear(const unsigned* __restrict__ gk, const float* __restrict__ Wl,
                         const float* __restrict__ bl, float* __restrict__ out)
{
    int i = blockIdx.x * blockDim.x + threadIdx.x;
    if (i >= 16 * 1000) return;
    int b = i / 1000, o = i % 1000;
    float s = bl[o];
    for (int f = 0; f < 243; ++f)
        s += funkey(gk[b * 243 + f]) * Wl[o * 243 + f];
    out[i] = s;
}

// ---------------- launch ----------------
extern "C" void kernel_launch(void* const* d_in, const int* in_sizes, int n_in,
                              void* d_out, int out_size, void* d_ws, size_t ws_size,
                              hipStream_t stream)
{
    const float* x  = (const float*)d_in[0];
    const float* Wl = (const float*)d_in[1];
    const float* bl = (const float*)d_in[2];
    float* out = (float*)d_out;
    float* ws = (float*)d_ws;

    float2* FT224F = (float2*)(ws + OFF_FT224F);
    float2* FT224I = (float2*)(ws + OFF_FT224I);
    float2* FT112F = (float2*)(ws + OFF_FT112F);
    float2* FT112I = (float2*)(ws + OFF_FT112I);
    float2* F56I  = (float2*)(ws + OFF_F56I);
    float* PSI0 = ws + OFF_PSI;
    float* PSI1 = ws + OFF_PSI + 8 * IMG224;
    float* PHI0 = ws + OFF_PHI0;
    float* PHI1 = ws + OFF_PHI1;
    unsigned* GK = (unsigned*)(ws + OFF_GK);
    float2* XH  = (float2*)(ws + OFF_XH);
    float* A0  = ws + OFF_POOL;          // 9633792 floats
    float* A1  = A0 + 9633792;           // 9633792
    float* A23 = A1 + 9633792;           // 9633792

    // tables
    k_fact<<<4, 256, 0, stream>>>(FT224F, 16, 14, -1.0, 1.0);
    k_fact<<<4, 256, 0, stream>>>(FT224I, 16, 14,  1.0, 1.0 / 224.0);
    k_fact<<<4, 256, 0, stream>>>(FT112F, 16, 7,  -1.0, 1.0);
    k_fact<<<4, 256, 0, stream>>>(FT112I, 16, 7,   1.0, 1.0 / 112.0);
    k_dft<<<(56*56 + 255) / 256, 256, 0, stream>>>(F56I, 56, 1.0, 1.0 / 56.0);
    k_psi<<<(16 * IMG224 + 255) / 256, 256, 0, stream>>>(ws + OFF_PSI);
    k_phi<<<(IMG224 + IMG112 + 255) / 256, 256, 0, stream>>>(PHI0, PHI1);
    k_zero<<<(3888 + 255) / 256, 256, 0, stream>>>(GK, 3888);

    // ---- fft2(x) -> XH ----
    rk<16, 14, 4, 1, 128, true><<<dim3(48, 56), 128, 0, stream>>>(x, 0, nullptr, 0, FT224F, (float2*)A0, 0, 0, 0);
    ck1<16, 14, 2, 64><<<dim3(96, 14), 64, 0, stream>>>((float2*)A0, FT224F, (float2*)A1);
    ck2<16, 14, 2, 0, 64><<<dim3(96, 16), 64, 0, stream>>>((float2*)A1, FT224F, XH, nullptr);

    // ---- s0 -> GK slot img*81+0 ----
    rowpass_c<56, 4, 8, 64><<<dim3(48, 7), 64, 0, stream>>>(XH, 0, PHI0, 0, F56I, (float2*)A1);
    colpass_max<56, 8, 64><<<dim3(48, 7), 64, 0, stream>>>((float2*)A1, F56I, GK, 0, 0, 0);

    // ---- pair-batched first order j1=0 (+ second order); g = img*2 + lc, l1 = 2c+lc ----
    for (int c = 0; c < 4; ++c) {
        // A: ifft rows of xh*psi0[l1] -> A0 (96 groups)
        rk<16, 14, 4, 1, 128, false><<<dim3(96, 56), 128, 0, stream>>>(
            XH, 1, PSI0 + (size_t)(2 * c) * IMG224, 1, FT224I, (float2*)A0, 0, 0, 0);
        // B: ifft cols + |.| -> A23 (real u1)
        ck1<16, 14, 2, 64><<<dim3(192, 14), 64, 0, stream>>>((float2*)A0, FT224I, (float2*)A1);
        ck2<16, 14, 2, 1, 64><<<dim3(192, 16), 64, 0, stream>>>((float2*)A1, FT224I, nullptr, A23);
        // C: fft rows of u1 (real) -> A0
        rk<16, 14, 4, 1, 128, true><<<dim3(96, 56), 128, 0, stream>>>(A23, 0, nullptr, 0, FT224F, (float2*)A0, 0, 0, 0);
        // D: fft cols -> V1 (A0)
        ck1<16, 14, 2, 64><<<dim3(192, 14), 64, 0, stream>>>((float2*)A0, FT224F, (float2*)A1);
        ck2<16, 14, 2, 0, 64><<<dim3(192, 16), 64, 0, stream>>>((float2*)A1, FT224F, (float2*)A0, nullptr);
        // E: s1 -> GK slot img*81 + 1 + 2c + lc
        rowpass_c<56, 4, 8, 64><<<dim3(96, 7), 64, 0, stream>>>((float2*)A0, 0, PHI0, 0, F56I, (float2*)A1);
        colpass_max<56, 8, 64><<<dim3(96, 7), 64, 0, stream>>>((float2*)A1, F56I, GK, 1 + 2 * c, 1, 1);
        // second order per l1 in pair (V1 stays live in A0)
        for (int lc = 0; lc < 2; ++lc) {
            int l1 = 2 * c + lc;
            // F: ifft112 rows of fold(V1*psi1[l2],2) [XCD swizzle] -> A1
            rk<16, 7, 8, 2, 128, false><<<dim3(384, 14), 128, 0, stream>>>(
                (float2*)A0, 0, PSI1, 7, FT112I, (float2*)A1, 48, 2, lc);
            // G: ifft112 cols + |.| : A1 -> A23 (stage1) -> A1 (real u2)
            ck1<16, 7, 1, 64><<<dim3(384, 7), 64, 0, stream>>>((float2*)A1, FT112I, (float2*)A23);
            ck2<16, 7, 1, 1, 64><<<dim3(384, 16), 64, 0, stream>>>((float2*)A23, FT112I, nullptr, A1);
            // H: fft112 rows of u2 (real) -> A23
            rk<16, 7, 8, 1, 128, true><<<dim3(384, 14), 128, 0, stream>>>(A1, 0, nullptr, 0, FT112F, (float2*)A23, 0, 0, 0);
            // I: fft112 cols: A23 -> A1 (stage1) -> A23 (u2h)
            ck1<16, 7, 1, 64><<<dim3(384, 7), 64, 0, stream>>>((float2*)A23, FT112F, (float2*)A1);
            ck2<16, 7, 1, 0, 64><<<dim3(384, 16), 64, 0, stream>>>((float2*)A1, FT112F, (float2*)A23, nullptr);
            // JK: s2 -> GK slot img*81 + 17 + 8*l1 + l2
            rowpass_c<56, 2, 8, 64><<<dim3(384, 7), 64, 0, stream>>>((float2*)A23, 0, PHI1, 0, F56I, (float2*)A1);
            colpass_max<56, 8, 64><<<dim3(384, 7), 64, 0, stream>>>((float2*)A1, F56I, GK, 17 + 8 * l1, 3, 7);
        }
    }

    // ---- first order j1=1 (8 orientations, g = img*8+l) ----
    rk<16, 7, 8, 2, 128, false><<<dim3(384, 14), 128, 0, stream>>>(XH, 0, PSI1, 7, FT112I, (float2*)A1, 48, 1, 0);
    ck1<16, 7, 1, 64><<<dim3(384, 7), 64, 0, stream>>>((float2*)A1, FT112I, (float2*)A23);
    ck2<16, 7, 1, 1, 64><<<dim3(384, 16), 64, 0, stream>>>((float2*)A23, FT112I, nullptr, A1);
    rk<16, 7, 8, 1, 128, true><<<dim3(384, 14), 128, 0, stream>>>(A1, 0, nullptr, 0, FT112F, (float2*)A23, 0, 0, 0);
    ck1<16, 7, 1, 64><<<dim3(384, 7), 64, 0, stream>>>((float2*)A23, FT112F, (float2*)A1);
    ck2<16, 7, 1, 0, 64><<<dim3(384, 16), 64, 0, stream>>>((float2*)A1, FT112F, (float2*)A23, nullptr);
    rowpass_c<56, 2, 8, 64><<<dim3(384, 7), 64, 0, stream>>>((float2*)A23, 0, PHI1, 0, F56I, (float2*)A1);
    colpass_max<56, 8, 64><<<dim3(384, 7), 64, 0, stream>>>((float2*)A1, F56I, GK, 9, 3, 7);

    // head
    k_linear<<<(16000 + 255) / 256, 256, 0, stream>>>(GK, Wl, bl, out);
}

// Round 12
// 3258.786 us; speedup vs baseline: 1.2852x; 1.0001x over previous
//
#include <hip/hip_runtime.h>
#include <math.h>

#define PI_D 3.14159265358979323846

// ---------------- workspace layout (float units) ----------------
#define IMG224 50176
#define IMG112 12544
// factorized DFT tables: per (N,dir): [W1:N1*N1 | W2:N2*N2 | TW:N2*N1] float2
static const size_t OFF_FT224F = 0;
static const size_t OFF_FT224I = 2048;
static const size_t OFF_FT112F = 4096;
static const size_t OFF_FT112I = 6144;
static const size_t OFF_F56I  = 250880;    // 6272 (dense 56 inverse)
static const size_t OFF_PSI   = 257152;    // 16*50176
static const size_t OFF_PHI0  = 1059968;
static const size_t OFF_PHI1  = 1110144;
static const size_t OFF_GK    = 1122688;   // 3888 keys
static const size_t OFF_XH    = 1126784;   // 4816896
static const size_t OFF_POOL  = 5943680;
// arena: A0, A1, A23 = 9633792 floats each -> ~139 MB total (< known-good 149 MB)

// ---------------- helpers ----------------
__device__ inline unsigned fkey(float v) {
    int b = __float_as_int(v);
    return (b >= 0) ? ((unsigned)b | 0x80000000u) : ~(unsigned)b;
}
__device__ inline float funkey(unsigned u) {
    int b = (u & 0x80000000u) ? (int)(u & 0x7fffffffu) : (int)~u;
    return __int_as_float(b);
}
__device__ inline void cmac(float2& a, float2 z, float2 w) {
    a.x += z.x * w.x - z.y * w.y;
    a.y += z.x * w.y + z.y * w.x;
}

// ---------------- table builders ----------------
__global__ void k_dft(float2* out, int n, double sign, double scale) {
    int i = blockIdx.x * blockDim.x + threadIdx.x;
    if (i >= n * n) return;
    int c = i / n, k = i % n;
    int m = (c * k) % n;
    double ang = sign * 2.0 * PI_D * (double)m / (double)n;
    out[i] = make_float2((float)(scale * cos(ang)), (float)(scale * sin(ang)));
}

__global__ void k_fact(float2* o, int N1, int N2, double sign, double scale) {
    int total = N1 * N1 + N2 * N2 + N2 * N1;
    int N = N1 * N2;
    for (int i = blockIdx.x * blockDim.x + threadIdx.x; i < total; i += blockDim.x * gridDim.x) {
        double ang; double sc = 1.0;
        if (i < N1 * N1) {
            int n1 = i / N1, k1 = i % N1;
            ang = sign * 2.0 * PI_D * (double)((n1 * k1) % N1) / (double)N1;
        } else if (i < N1 * N1 + N2 * N2) {
            int j = i - N1 * N1; int n2 = j / N2, k2 = j % N2;
            ang = sign * 2.0 * PI_D * (double)((n2 * k2) % N2) / (double)N2;
            sc = scale;
        } else {
            int j = i - N1 * N1 - N2 * N2; int n2 = j / N1, k1 = j % N1;
            ang = sign * 2.0 * PI_D * (double)((n2 * k1) % N) / (double)N;
        }
        o[i] = make_float2((float)(sc * cos(ang)), (float)(sc * sin(ang)));
    }
}

__global__ void k_psi(float* out) {
    int i = blockIdx.x * blockDim.x + threadIdx.x;
    if (i >= 16 * IMG224) return;
    int jl = i / IMG224, p = i % IMG224;
    int r = p / 224, c = p % 224;
    int j = jl >> 3, l = jl & 7;
    double fr = (r < 112) ? (double)r : (double)(r - 224);
    double fc = (c < 112) ? (double)c : (double)(c - 224);
    double wx = 2.0 * PI_D * fr / 224.0;
    double wy = 2.0 * PI_D * fc / 224.0;
    double theta = (double)l * PI_D / 8.0;
    double xi = (3.0 * PI_D / 4.0) / (double)(1 << j);
    double sg = 0.8 * (double)(1 << j);
    double ct = cos(theta), st = sin(theta);
    double u = ct * wx + st * wy;
    double v = -st * wx + ct * wy;
    double vs = v / 0.5;
    double s2 = 0.5 * sg * sg;
    double gab = exp(-s2 * ((u - xi) * (u - xi) + vs * vs));
    double gau = exp(-s2 * (u * u + vs * vs));
    double kap = exp(-s2 * xi * xi);
    out[i] = (float)(gab - kap * gau);
}

__global__ void k_phi(float* phi0, float* phi1) {
    int i = blockIdx.x * blockDim.x + threadIdx.x;
    const double sp = 1.6;
    const double s2 = 0.5 * sp * sp;
    if (i < IMG224) {
        int r = i / 224, c = i % 224;
        double fr = (r < 112) ? (double)r : (double)(r - 224);
        double fc = (c < 112) ? (double)c : (double)(c - 224);
        double wx = 2.0 * PI_D * fr / 224.0;
        double wy = 2.0 * PI_D * fc / 224.0;
        phi0[i] = (float)exp(-s2 * (wx * wx + wy * wy));
    } else if (i < IMG224 + IMG112) {
        int p = i - IMG224, a = p / 112, b = p % 112;
        double sum = 0.0;
        for (int ii = 0; ii < 2; ++ii)
            for (int jj = 0; jj < 2; ++jj) {
                int r = a + 112 * ii, c = b + 112 * jj;
                double fr = (r < 112) ? (double)r : (double)(r - 224);
                double fc = (c < 112) ? (double)c : (double)(c - 224);
                double wx = 2.0 * PI_D * fr / 224.0;
                double wy = 2.0 * PI_D * fc / 224.0;
                sum += exp(-s2 * (wx * wx + wy * wy));
            }
        phi1[p] = (float)(0.25 * sum);
    }
}

__global__ void k_zero(unsigned* gk, int n) {
    int i = blockIdx.x * blockDim.x + threadIdx.x;
    if (i < n) gk[i] = 0u;
}

// ---------------- rk: row pass, two-stage (N=N1*N2), fused in LDS ----------------
// R8-proven two-buffer structure (R9/R10: in-place variant triggers VGPR=40 + 2.5x
// VALU — retired). R11: TA halved -> LDS 14.8KB, occupancy 31%; but pass lanes
// dropped to 56/128 (the flat F-step dur). R12: split output dim across lanes:
// pass1 thread (r,n2,h) does N1/S1 k1's (112/128 lanes); pass2 (r,k1,h) does
// N2/S2 k2's (128/128). Same LDS, same schedule, full lanes.
// swzImg>0: XCD swizzle (R6: FETCH 76->16MB on F-step).
template<int N1, int N2, int TA, int FOLD, int BS, bool REAL, int S1, int S2>
__global__ __launch_bounds__(BS) void rk(
    const void* __restrict__ inBase, int inShift,
    const float* __restrict__ fltBase, int fltMask,
    const float2* __restrict__ FT, float2* __restrict__ out,
    int swzImg, int inStride, int inOff)
{
    constexpr int N = N1 * N2;
    constexpr int NIN = N * FOLD;
    constexpr int ZS = N + 2;
    constexpr int TS = N2 * (N1 + 1);
    constexpr int K1C = N1 / S1;
    constexpr int K2C = N2 / S2;
    __shared__ float2 Z[TA * ZS];
    __shared__ float2 T[TA * TS];
    const float2* W1 = FT;
    const float2* W2 = FT + N1 * N1;
    const float2* TW = FT + N1 * N1 + N2 * N2;
    const int bx = blockIdx.x, a0 = blockIdx.y * TA, t = threadIdx.x;
    int gIn, gFlt, gOut;
    if (swzImg > 0) {
        int img = bx % swzImg, sub = bx / swzImg;
        gIn = img * inStride + inOff; gFlt = sub; gOut = img * (gridDim.x / swzImg) + sub;
    } else {
        gIn = bx >> inShift; gFlt = bx & fltMask; gOut = bx;
    }

    if (REAL) {
        const float* in = (const float*)inBase + (size_t)gIn * N * N;
        for (int r = 0; r < TA; ++r)
            for (int b = t; b < N; b += BS)
                Z[r * ZS + b] = make_float2(in[(size_t)(a0 + r) * N + b], 0.f);
    } else {
        const float2* in = (const float2*)inBase + (size_t)gIn * (NIN * NIN);
        const float* flt = fltBase + (size_t)gFlt * (NIN * NIN);
        const float s = 1.0f / (float)(FOLD * FOLD);
        for (int r = 0; r < TA; ++r) {
            int a = a0 + r;
            for (int b = t; b < N; b += BS) {
                float re = 0.f, im = 0.f;
#pragma unroll
                for (int i = 0; i < FOLD; ++i)
#pragma unroll
                    for (int j = 0; j < FOLD; ++j) {
                        int idx = (a + N * i) * NIN + (b + N * j);
                        float2 v = in[idx];
                        float f = flt[idx];
                        re += v.x * f; im += v.y * f;
                    }
                Z[r * ZS + b] = make_float2(re * s, im * s);
            }
        }
    }
    __syncthreads();
    // pass 1: thread (r, n2, h) -> T[r][n2][h*K1C .. +K1C)
    // (h=0,1) pairs read identical Z addresses -> LDS broadcast (free).
    for (int idx = t; idx < TA * N2 * S1; idx += BS) {
        int r = idx / (N2 * S1);
        int rem = idx % (N2 * S1);
        int n2 = rem / S1, h = rem % S1;
        float2 acc[K1C];
#pragma unroll
        for (int kk = 0; kk < K1C; ++kk) acc[kk] = make_float2(0.f, 0.f);
        for (int n1 = 0; n1 < N1; ++n1) {
            float2 zv = Z[r * ZS + n1 * N2 + n2];
#pragma unroll
            for (int kk = 0; kk < K1C; ++kk) cmac(acc[kk], zv, W1[n1 * N1 + h * K1C + kk]);
        }
#pragma unroll
        for (int kk = 0; kk < K1C; ++kk) {
            int k1 = h * K1C + kk;
            float2 tw = TW[n2 * N1 + k1];
            float2 a2;
            a2.x = acc[kk].x * tw.x - acc[kk].y * tw.y;
            a2.y = acc[kk].x * tw.y + acc[kk].y * tw.x;
            T[r * TS + n2 * (N1 + 1) + k1] = a2;
        }
    }
    __syncthreads();
    // pass 2: thread (r, k1, h) -> Z[r][k1 + N1*(h*K2C .. +K2C)]
    for (int idx = t; idx < TA * N1 * S2; idx += BS) {
        int r = idx / (N1 * S2);
        int rem = idx % (N1 * S2);
        int k1 = rem / S2, h = rem % S2;
        float2 acc[K2C];
#pragma unroll
        for (int kk = 0; kk < K2C; ++kk) acc[kk] = make_float2(0.f, 0.f);
        for (int n2 = 0; n2 < N2; ++n2) {
            float2 tv = T[r * TS + n2 * (N1 + 1) + k1];
#pragma unroll
            for (int kk = 0; kk < K2C; ++kk) cmac(acc[kk], tv, W2[n2 * N2 + h * K2C + kk]);
        }
#pragma unroll
        for (int kk = 0; kk < K2C; ++kk) Z[r * ZS + k1 + N1 * (h * K2C + kk)] = acc[kk];
    }
    __syncthreads();
    for (int r = 0; r < TA; ++r) {
        float2* o = out + ((size_t)gOut * N + (a0 + r)) * N;
        for (int b = t; b < N; b += BS) o[b] = Z[r * ZS + b];
    }
}

// ---------------- ck1/ck2: split column pass (proven structure; R5/R7: do NOT fuse) ----
template<int N1, int N2, int SPLIT, int BS>
__global__ __launch_bounds__(BS) void ck1(
    const float2* __restrict__ in, const float2* __restrict__ FT, float2* __restrict__ out)
{
    constexpr int N = N1 * N2;
    constexpr int NC = N / SPLIT;
    const float2* W1 = FT;
    const float2* TW = FT + N1 * N1 + N2 * N2;
    const int g = blockIdx.x / SPLIT, half = blockIdx.x % SPLIT;
    const int n2 = blockIdx.y, t = threadIdx.x;
    if (2 * t >= NC) return;
    const int b0 = 2 * t + half * NC;
    const float2* I = in + (size_t)g * N * N;
    float2 acc[N1][2];
#pragma unroll
    for (int k1 = 0; k1 < N1; ++k1) { acc[k1][0] = make_float2(0.f, 0.f); acc[k1][1] = make_float2(0.f, 0.f); }
    for (int n1 = 0; n1 < N1; ++n1) {
        float4 v = *reinterpret_cast<const float4*>(&I[(size_t)(n1 * N2 + n2) * N + b0]);
        float2 v0 = make_float2(v.x, v.y), v1 = make_float2(v.z, v.w);
#pragma unroll
        for (int k1 = 0; k1 < N1; ++k1) {
            float2 w = W1[n1 * N1 + k1];
            cmac(acc[k1][0], v0, w);
            cmac(acc[k1][1], v1, w);
        }
    }
#pragma unroll
    for (int k1 = 0; k1 < N1; ++k1) {
        float2 tw = TW[n2 * N1 + k1];
        float2 a0, a1;
        a0.x = acc[k1][0].x * tw.x - acc[k1][0].y * tw.y;
        a0.y = acc[k1][0].x * tw.y + acc[k1][0].y * tw.x;
        a1.x = acc[k1][1].x * tw.x - acc[k1][1].y * tw.y;
        a1.y = acc[k1][1].x * tw.y + acc[k1][1].y * tw.x;
        *reinterpret_cast<float4*>(&out[((size_t)g * N + (k1 * N2 + n2)) * N + b0]) =
            make_float4(a0.x, a0.y, a1.x, a1.y);
    }
}

template<int N1, int N2, int SPLIT, int MODE, int BS>
__global__ __launch_bounds__(BS) void ck2(
    const float2* __restrict__ in, const float2* __restrict__ FT,
    float2* __restrict__ outc, float* __restrict__ outr)
{
    constexpr int N = N1 * N2;
    constexpr int NC = N / SPLIT;
    const float2* W2 = FT + N1 * N1;
    const int g = blockIdx.x / SPLIT, half = blockIdx.x % SPLIT;
    const int k1 = blockIdx.y, t = threadIdx.x;
    if (2 * t >= NC) return;
    const int b0 = 2 * t + half * NC;
    const float2* I = in + (size_t)g * N * N;
    float2 acc[N2][2];
#pragma unroll
    for (int k2 = 0; k2 < N2; ++k2) { acc[k2][0] = make_float2(0.f, 0.f); acc[k2][1] = make_float2(0.f, 0.f); }
    for (int n2 = 0; n2 < N2; ++n2) {
        float4 v = *reinterpret_cast<const float4*>(&I[(size_t)(k1 * N2 + n2) * N + b0]);
        float2 v0 = make_float2(v.x, v.y), v1 = make_float2(v.z, v.w);
#pragma unroll
        for (int k2 = 0; k2 < N2; ++k2) {
            float2 w = W2[n2 * N2 + k2];
            cmac(acc[k2][0], v0, w);
            cmac(acc[k2][1], v1, w);
        }
    }
    if (MODE == 0) {
#pragma unroll
        for (int k2 = 0; k2 < N2; ++k2)
            *reinterpret_cast<float4*>(&outc[((size_t)g * N + (k1 + N1 * k2)) * N + b0]) =
                make_float4(acc[k2][0].x, acc[k2][0].y, acc[k2][1].x, acc[k2][1].y);
    } else {
#pragma unroll
        for (int k2 = 0; k2 < N2; ++k2) {
            size_t o = ((size_t)g * N + (k1 + N1 * k2)) * N + b0;
            outr[o]     = sqrtf(acc[k2][0].x * acc[k2][0].x + acc[k2][0].y * acc[k2][0].y);
            outr[o + 1] = sqrtf(acc[k2][1].x * acc[k2][1].x + acc[k2][1].y * acc[k2][1].y);
        }
    }
}

// ---------------- 56-res dense kernels (R6-proven) ----------------
template<int NOUT, int FOLD, int TA, int BS>
__global__ __launch_bounds__(BS) void rowpass_c(
    const float2* __restrict__ inBase, int inShift,
    const float* __restrict__ fltBase, int fltMask,
    const float2* __restrict__ W, float2* __restrict__ out)
{
    constexpr int NIN = NOUT * FOLD;
    __shared__ float2 Z[TA * NOUT];
    const int g = blockIdx.x;
    const int a0 = blockIdx.y * TA;
    const float2* in = inBase + (size_t)(g >> inShift) * (NIN * NIN);
    const float* flt = fltBase + (size_t)(g & fltMask) * (NIN * NIN);
    const int t = threadIdx.x;
    const float s = 1.0f / (float)(FOLD * FOLD);
    for (int r = 0; r < TA; ++r) {
        const int a = a0 + r;
        for (int b = t; b < NOUT; b += BS) {
            float re = 0.f, im = 0.f;
#pragma unroll
            for (int i = 0; i < FOLD; ++i)
#pragma unroll
                for (int j = 0; j < FOLD; ++j) {
                    const int idx = (a + NOUT * i) * NIN + (b + NOUT * j);
                    float2 v = in[idx];
                    float f = flt[idx];
                    re += v.x * f; im += v.y * f;
                }
            Z[r * NOUT + b] = make_float2(re * s, im * s);
        }
    }
    __syncthreads();
    const int k0 = 2 * t;
    if (k0 < NOUT) {
        float2 acc[TA][2];
#pragma unroll
        for (int r = 0; r < TA; ++r) {
            acc[r][0] = make_float2(0.f, 0.f);
            acc[r][1] = make_float2(0.f, 0.f);
        }
        for (int b = 0; b < NOUT; ++b) {
            float4 w = *reinterpret_cast<const float4*>(&W[b * NOUT + k0]);
#pragma unroll
            for (int r = 0; r < TA; ++r) {
                float2 z = Z[r * NOUT + b];
                acc[r][0].x += z.x * w.x - z.y * w.y;
                acc[r][0].y += z.x * w.y + z.y * w.x;
                acc[r][1].x += z.x * w.z - z.y * w.w;
                acc[r][1].y += z.x * w.w + z.y * w.z;
            }
        }
        float2* o = out + ((size_t)g * NOUT + a0) * NOUT + k0;
#pragma unroll
        for (int r = 0; r < TA; ++r)
            *reinterpret_cast<float4*>(&o[(size_t)r * NOUT]) =
                make_float4(acc[r][0].x, acc[r][0].y, acc[r][1].x, acc[r][1].y);
    }
}

template<int N, int TK, int BS>
__global__ __launch_bounds__(BS) void colpass_max(
    const float2* __restrict__ in, const float2* __restrict__ W,
    unsigned* __restrict__ gk, int slotBase, int slotShift, int slotMask)
{
    __shared__ float2 Wl[N * TK];
    const int g = blockIdx.x;
    const int k0 = blockIdx.y * TK;
    const float2* I = in + (size_t)g * (N * N);
    const int t = threadIdx.x;
    for (int idx = t; idx < N * TK; idx += BS) {
        int a = idx / TK, kt = idx % TK;
        Wl[idx] = W[a * N + k0 + kt];
    }
    __syncthreads();
    const int b0 = 2 * t;
    float m = -INFINITY;
    if (b0 < N) {
        float2 acc[TK][2];
#pragma unroll
        for (int kt = 0; kt < TK; ++kt) {
            acc[kt][0] = make_float2(0.f, 0.f);
            acc[kt][1] = make_float2(0.f, 0.f);
        }
        for (int a = 0; a < N; ++a) {
            float4 v = *reinterpret_cast<const float4*>(&I[(size_t)a * N + b0]);
#pragma unroll
            for (int kt = 0; kt < TK; ++kt) {
                float2 w = Wl[a * TK + kt];
                acc[kt][0].x += w.x * v.x - w.y * v.y;
                acc[kt][1].x += w.x * v.z - w.y * v.w;
            }
        }
#pragma unroll
        for (int kt = 0; kt < TK; ++kt)
            m = fmaxf(m, fmaxf(acc[kt][0].x, acc[kt][1].x));
    }
    for (int off = 32; off > 0; off >>= 1)
        m = fmaxf(m, __shfl_down(m, off, 64));
    if (t == 0) {
        int slot = slotBase + ((g >> slotShift) * 81) + (g & slotMask);
        atomicMax(&gk[slot], fkey(m));
    }
}

// ---------------- classifier head ----------------
__global__ void k_linear(const unsigned* __restrict__ gk, const float* __restrict__ Wl,
                         const float* __restrict__ bl, float* __restrict__ out)
{
    int i = blockIdx.x * blockDim.x + threadIdx.x;
    if (i >= 16 * 1000) return;
    int b = i / 1000, o = i % 1000;
    float s = bl[o];
    for (int f = 0; f < 243; ++f)
        s += funkey(gk[b * 243 + f]) * Wl[o * 243 + f];
    out[i] = s;
}

// ---------------- launch ----------------
extern "C" void kernel_launch(void* const* d_in, const int* in_sizes, int n_in,
                              void* d_out, int out_size, void* d_ws, size_t ws_size,
                              hipStream_t stream)
{
    const float* x  = (const float*)d_in[0];
    const float* Wl = (const float*)d_in[1];
    const float* bl = (const float*)d_in[2];
    float* out = (float*)d_out;
    float* ws = (float*)d_ws;

    float2* FT224F = (float2*)(ws + OFF_FT224F);
    float2* FT224I = (float2*)(ws + OFF_FT224I);
    float2* FT112F = (float2*)(ws + OFF_FT112F);
    float2* FT112I = (float2*)(ws + OFF_FT112I);
    float2* F56I  = (float2*)(ws + OFF_F56I);
    float* PSI0 = ws + OFF_PSI;
    float* PSI1 = ws + OFF_PSI + 8 * IMG224;
    float* PHI0 = ws + OFF_PHI0;
    float* PHI1 = ws + OFF_PHI1;
    unsigned* GK = (unsigned*)(ws + OFF_GK);
    float2* XH  = (float2*)(ws + OFF_XH);
    float* A0  = ws + OFF_POOL;          // 9633792 floats
    float* A1  = A0 + 9633792;           // 9633792
    float* A23 = A1 + 9633792;           // 9633792

    // tables
    k_fact<<<4, 256, 0, stream>>>(FT224F, 16, 14, -1.0, 1.0);
    k_fact<<<4, 256, 0, stream>>>(FT224I, 16, 14,  1.0, 1.0 / 224.0);
    k_fact<<<4, 256, 0, stream>>>(FT112F, 16, 7,  -1.0, 1.0);
    k_fact<<<4, 256, 0, stream>>>(FT112I, 16, 7,   1.0, 1.0 / 112.0);
    k_dft<<<(56*56 + 255) / 256, 256, 0, stream>>>(F56I, 56, 1.0, 1.0 / 56.0);
    k_psi<<<(16 * IMG224 + 255) / 256, 256, 0, stream>>>(ws + OFF_PSI);
    k_phi<<<(IMG224 + IMG112 + 255) / 256, 256, 0, stream>>>(PHI0, PHI1);
    k_zero<<<(3888 + 255) / 256, 256, 0, stream>>>(GK, 3888);

    // ---- fft2(x) -> XH ----
    rk<16, 14, 4, 1, 128, true, 2, 2><<<dim3(48, 56), 128, 0, stream>>>(x, 0, nullptr, 0, FT224F, (float2*)A0, 0, 0, 0);
    ck1<16, 14, 2, 64><<<dim3(96, 14), 64, 0, stream>>>((float2*)A0, FT224F, (float2*)A1);
    ck2<16, 14, 2, 0, 64><<<dim3(96, 16), 64, 0, stream>>>((float2*)A1, FT224F, XH, nullptr);

    // ---- s0 -> GK slot img*81+0 ----
    rowpass_c<56, 4, 8, 64><<<dim3(48, 7), 64, 0, stream>>>(XH, 0, PHI0, 0, F56I, (float2*)A1);
    colpass_max<56, 8, 64><<<dim3(48, 7), 64, 0, stream>>>((float2*)A1, F56I, GK, 0, 0, 0);

    // ---- pair-batched first order j1=0 (+ second order); g = img*2 + lc, l1 = 2c+lc ----
    for (int c = 0; c < 4; ++c) {
        // A: ifft rows of xh*psi0[l1] -> A0 (96 groups)
        rk<16, 14, 4, 1, 128, false, 2, 2><<<dim3(96, 56), 128, 0, stream>>>(
            XH, 1, PSI0 + (size_t)(2 * c) * IMG224, 1, FT224I, (float2*)A0, 0, 0, 0);
        // B: ifft cols + |.| -> A23 (real u1)
        ck1<16, 14, 2, 64><<<dim3(192, 14), 64, 0, stream>>>((float2*)A0, FT224I, (float2*)A1);
        ck2<16, 14, 2, 1, 64><<<dim3(192, 16), 64, 0, stream>>>((float2*)A1, FT224I, nullptr, A23);
        // C: fft rows of u1 (real) -> A0
        rk<16, 14, 4, 1, 128, true, 2, 2><<<dim3(96, 56), 128, 0, stream>>>(A23, 0, nullptr, 0, FT224F, (float2*)A0, 0, 0, 0);
        // D: fft cols -> V1 (A0)
        ck1<16, 14, 2, 64><<<dim3(192, 14), 64, 0, stream>>>((float2*)A0, FT224F, (float2*)A1);
        ck2<16, 14, 2, 0, 64><<<dim3(192, 16), 64, 0, stream>>>((float2*)A1, FT224F, (float2*)A0, nullptr);
        // E: s1 -> GK slot img*81 + 1 + 2c + lc
        rowpass_c<56, 4, 8, 64><<<dim3(96, 7), 64, 0, stream>>>((float2*)A0, 0, PHI0, 0, F56I, (float2*)A1);
        colpass_max<56, 8, 64><<<dim3(96, 7), 64, 0, stream>>>((float2*)A1, F56I, GK, 1 + 2 * c, 1, 1);
        // second order per l1 in pair (V1 stays live in A0)
        for (int lc = 0; lc < 2; ++lc) {
            int l1 = 2 * c + lc;
            // F: ifft112 rows of fold(V1*psi1[l2],2) [XCD swizzle] -> A1
            rk<16, 7, 8, 2, 128, false, 2, 1><<<dim3(384, 14), 128, 0, stream>>>(
                (float2*)A0, 0, PSI1, 7, FT112I, (float2*)A1, 48, 2, lc);
            // G: ifft112 cols + |.| : A1 -> A23 (stage1) -> A1 (real u2)
            ck1<16, 7, 1, 64><<<dim3(384, 7), 64, 0, stream>>>((float2*)A1, FT112I, (float2*)A23);
            ck2<16, 7, 1, 1, 64><<<dim3(384, 16), 64, 0, stream>>>((float2*)A23, FT112I, nullptr, A1);
            // H: fft112 rows of u2 (real) -> A23
            rk<16, 7, 8, 1, 128, true, 2, 1><<<dim3(384, 14), 128, 0, stream>>>(A1, 0, nullptr, 0, FT112F, (float2*)A23, 0, 0, 0);
            // I: fft112 cols: A23 -> A1 (stage1) -> A23 (u2h)
            ck1<16, 7, 1, 64><<<dim3(384, 7), 64, 0, stream>>>((float2*)A23, FT112F, (float2*)A1);
            ck2<16, 7, 1, 0, 64><<<dim3(384, 16), 64, 0, stream>>>((float2*)A1, FT112F, (float2*)A23, nullptr);
            // JK: s2 -> GK slot img*81 + 17 + 8*l1 + l2
            rowpass_c<56, 2, 8, 64><<<dim3(384, 7), 64, 0, stream>>>((float2*)A23, 0, PHI1, 0, F56I, (float2*)A1);
            colpass_max<56, 8, 64><<<dim3(384, 7), 64, 0, stream>>>((float2*)A1, F56I, GK, 17 + 8 * l1, 3, 7);
        }
    }

    // ---- first order j1=1 (8 orientations, g = img*8+l) ----
    rk<16, 7, 8, 2, 128, false, 2, 1><<<dim3(384, 14), 128, 0, stream>>>(XH, 0, PSI1, 7, FT112I, (float2*)A1, 48, 1, 0);
    ck1<16, 7, 1, 64><<<dim3(384, 7), 64, 0, stream>>>((float2*)A1, FT112I, (float2*)A23);
    ck2<16, 7, 1, 1, 64><<<dim3(384, 16), 64, 0, stream>>>((float2*)A23, FT112I, nullptr, A1);
    rk<16, 7, 8, 1, 128, true, 2, 1><<<dim3(384, 14), 128, 0, stream>>>(A1, 0, nullptr, 0, FT112F, (float2*)A23, 0, 0, 0);
    ck1<16, 7, 1, 64><<<dim3(384, 7), 64, 0, stream>>>((float2*)A23, FT112F, (float2*)A1);
    ck2<16, 7, 1, 0, 64><<<dim3(384, 16), 64, 0, stream>>>((float2*)A1, FT112F, (float2*)A23, nullptr);
    rowpass_c<56, 2, 8, 64><<<dim3(384, 7), 64, 0, stream>>>((float2*)A23, 0, PHI1, 0, F56I, (float2*)A1);
    colpass_max<56, 8, 64><<<dim3(384, 7), 64, 0, stream>>>((float2*)A1, F56I, GK, 9, 3, 7);

    // head
    k_linear<<<(16000 + 255) / 256, 256, 0, stream>>>(GK, Wl, bl, out);
}

// Round 13
// 2866.873 us; speedup vs baseline: 1.4609x; 1.1367x over previous
//
#include <hip/hip_runtime.h>
#include <math.h>

#define PI_D 3.14159265358979323846

// ---------------- workspace layout (float units) ----------------
#define IMG224 50176
#define IMG112 12544
// factorized DFT tables: per (N,dir): [W1:N1*N1 | W2:N2*N2 | TW:N2*N1] float2
static const size_t OFF_FT224F = 0;
static const size_t OFF_FT224I = 2048;
static const size_t OFF_FT112F = 4096;
static const size_t OFF_FT112I = 6144;
static const size_t OFF_F56I  = 250880;    // 6272 (dense 56 inverse)
static const size_t OFF_PSI   = 257152;    // 16*50176
static const size_t OFF_PHI0  = 1059968;
static const size_t OFF_PHI1  = 1110144;
static const size_t OFF_GK    = 1122688;   // 3888 keys
static const size_t OFF_XH    = 1126784;   // 4816896
static const size_t OFF_POOL  = 5943680;
// arena: A0, A1, A23 = 9633792 floats each -> ~139 MB total (< known-good 149 MB)

// ---------------- helpers ----------------
__device__ inline unsigned fkey(float v) {
    int b = __float_as_int(v);
    return (b >= 0) ? ((unsigned)b | 0x80000000u) : ~(unsigned)b;
}
__device__ inline float funkey(unsigned u) {
    int b = (u & 0x80000000u) ? (int)(u & 0x7fffffffu) : (int)~u;
    return __int_as_float(b);
}
__device__ inline void cmac(float2& a, float2 z, float2 w) {
    a.x += z.x * w.x - z.y * w.y;
    a.y += z.x * w.y + z.y * w.x;
}
__device__ inline float2 cmulc(float2 v, float c, float s) {
    return make_float2(v.x * c - v.y * s, v.x * s + v.y * c);
}

// 16-point DFT, radix-4 x radix-4, constant twiddles (zero table loads).
// Computes X[k] = sum_n x[n] e^{SGN*2*pi*i*n*k/16}, in natural order, in place.
// Verified algebra: n=4a+b, k=p+4q; n*k mod 16 = 4ap + bp + 4bq.
template<int SGN>
__device__ inline void fft16(float2* x) {
    const float C8  = 0.70710678118654752f;   // cos(pi/4)
    const float C16 = 0.92387953251128674f;   // cos(pi/8)
    const float S16 = 0.38268343236508977f;   // sin(pi/8)
    const float sg = (float)SGN;
    float2 g[16];
#pragma unroll
    for (int b = 0; b < 4; ++b) {             // g[b*4+p] = sum_a x[4a+b] w4^{SGN*a*p}
        float2 x0 = x[b], x1 = x[4 + b], x2 = x[8 + b], x3 = x[12 + b];
        float2 e0 = make_float2(x0.x + x2.x, x0.y + x2.y);
        float2 e1 = make_float2(x0.x - x2.x, x0.y - x2.y);
        float2 o0 = make_float2(x1.x + x3.x, x1.y + x3.y);
        float2 o1 = make_float2(x1.x - x3.x, x1.y - x3.y);
        float2 io1 = (SGN > 0) ? make_float2(-o1.y, o1.x) : make_float2(o1.y, -o1.x);
        g[b * 4 + 0] = make_float2(e0.x + o0.x, e0.y + o0.y);
        g[b * 4 + 2] = make_float2(e0.x - o0.x, e0.y - o0.y);
        g[b * 4 + 1] = make_float2(e1.x + io1.x, e1.y + io1.y);
        g[b * 4 + 3] = make_float2(e1.x - io1.x, e1.y - io1.y);
    }
    // inner twiddles g[b*4+p] *= e^{SGN*2*pi*i*b*p/16}; m=b*p in {1,2,3,4,6,9}
    g[5]  = cmulc(g[5],  C16,  sg * S16);     // m=1
    g[6]  = cmulc(g[6],  C8,   sg * C8);      // m=2
    g[7]  = cmulc(g[7],  S16,  sg * C16);     // m=3
    g[9]  = cmulc(g[9],  C8,   sg * C8);      // m=2
    g[10] = (SGN > 0) ? make_float2(-g[10].y, g[10].x)
                      : make_float2(g[10].y, -g[10].x);  // m=4 (= SGN*i)
    g[11] = cmulc(g[11], -C8,  sg * C8);      // m=6
    g[13] = cmulc(g[13], S16,  sg * C16);     // m=3
    g[14] = cmulc(g[14], -C8,  sg * C8);      // m=6
    g[15] = cmulc(g[15], -C16, -sg * S16);    // m=9
#pragma unroll
    for (int p = 0; p < 4; ++p) {             // x[p+4q] = sum_b g[b*4+p] w4^{SGN*b*q}
        float2 x0 = g[p], x1 = g[4 + p], x2 = g[8 + p], x3 = g[12 + p];
        float2 e0 = make_float2(x0.x + x2.x, x0.y + x2.y);
        float2 e1 = make_float2(x0.x - x2.x, x0.y - x2.y);
        float2 o0 = make_float2(x1.x + x3.x, x1.y + x3.y);
        float2 o1 = make_float2(x1.x - x3.x, x1.y - x3.y);
        float2 io1 = (SGN > 0) ? make_float2(-o1.y, o1.x) : make_float2(o1.y, -o1.x);
        x[p + 0]  = make_float2(e0.x + o0.x, e0.y + o0.y);
        x[p + 8]  = make_float2(e0.x - o0.x, e0.y - o0.y);
        x[p + 4]  = make_float2(e1.x + io1.x, e1.y + io1.y);
        x[p + 12] = make_float2(e1.x - io1.x, e1.y - io1.y);
    }
}

// ---------------- table builders ----------------
__global__ void k_dft(float2* out, int n, double sign, double scale) {
    int i = blockIdx.x * blockDim.x + threadIdx.x;
    if (i >= n * n) return;
    int c = i / n, k = i % n;
    int m = (c * k) % n;
    double ang = sign * 2.0 * PI_D * (double)m / (double)n;
    out[i] = make_float2((float)(scale * cos(ang)), (float)(scale * sin(ang)));
}

__global__ void k_fact(float2* o, int N1, int N2, double sign, double scale) {
    int total = N1 * N1 + N2 * N2 + N2 * N1;
    int N = N1 * N2;
    for (int i = blockIdx.x * blockDim.x + threadIdx.x; i < total; i += blockDim.x * gridDim.x) {
        double ang; double sc = 1.0;
        if (i < N1 * N1) {
            int n1 = i / N1, k1 = i % N1;
            ang = sign * 2.0 * PI_D * (double)((n1 * k1) % N1) / (double)N1;
        } else if (i < N1 * N1 + N2 * N2) {
            int j = i - N1 * N1; int n2 = j / N2, k2 = j % N2;
            ang = sign * 2.0 * PI_D * (double)((n2 * k2) % N2) / (double)N2;
            sc = scale;
        } else {
            int j = i - N1 * N1 - N2 * N2; int n2 = j / N1, k1 = j % N1;
            ang = sign * 2.0 * PI_D * (double)((n2 * k1) % N) / (double)N;
        }
        o[i] = make_float2((float)(sc * cos(ang)), (float)(sc * sin(ang)));
    }
}

__global__ void k_psi(float* out) {
    int i = blockIdx.x * blockDim.x + threadIdx.x;
    if (i >= 16 * IMG224) return;
    int jl = i / IMG224, p = i % IMG224;
    int r = p / 224, c = p % 224;
    int j = jl >> 3, l = jl & 7;
    double fr = (r < 112) ? (double)r : (double)(r - 224);
    double fc = (c < 112) ? (double)c : (double)(c - 224);
    double wx = 2.0 * PI_D * fr / 224.0;
    double wy = 2.0 * PI_D * fc / 224.0;
    double theta = (double)l * PI_D / 8.0;
    double xi = (3.0 * PI_D / 4.0) / (double)(1 << j);
    double sg = 0.8 * (double)(1 << j);
    double ct = cos(theta), st = sin(theta);
    double u = ct * wx + st * wy;
    double v = -st * wx + ct * wy;
    double vs = v / 0.5;
    double s2 = 0.5 * sg * sg;
    double gab = exp(-s2 * ((u - xi) * (u - xi) + vs * vs));
    double gau = exp(-s2 * (u * u + vs * vs));
    double kap = exp(-s2 * xi * xi);
    out[i] = (float)(gab - kap * gau);
}

__global__ void k_phi(float* phi0, float* phi1) {
    int i = blockIdx.x * blockDim.x + threadIdx.x;
    const double sp = 1.6;
    const double s2 = 0.5 * sp * sp;
    if (i < IMG224) {
        int r = i / 224, c = i % 224;
        double fr = (r < 112) ? (double)r : (double)(r - 224);
        double fc = (c < 112) ? (double)c : (double)(c - 224);
        double wx = 2.0 * PI_D * fr / 224.0;
        double wy = 2.0 * PI_D * fc / 224.0;
        phi0[i] = (float)exp(-s2 * (wx * wx + wy * wy));
    } else if (i < IMG224 + IMG112) {
        int p = i - IMG224, a = p / 112, b = p % 112;
        double sum = 0.0;
        for (int ii = 0; ii < 2; ++ii)
            for (int jj = 0; jj < 2; ++jj) {
                int r = a + 112 * ii, c = b + 112 * jj;
                double fr = (r < 112) ? (double)r : (double)(r - 224);
                double fc = (c < 112) ? (double)c : (double)(c - 224);
                double wx = 2.0 * PI_D * fr / 224.0;
                double wy = 2.0 * PI_D * fc / 224.0;
                sum += exp(-s2 * (wx * wx + wy * wy));
            }
        phi1[p] = (float)(0.25 * sum);
    }
}

__global__ void k_zero(unsigned* gk, int n) {
    int i = blockIdx.x * blockDim.x + threadIdx.x;
    if (i < n) gk[i] = 0u;
}

// ---------------- rk: row pass, two-stage (N=16*N2), fused in LDS ----------------
// R8-proven two-buffer structure (R9/R10: in-place variant -> VGPR=40 spill, retired).
// R13: pass-1 16-pt DFT now radix-4x4 fft16 with constant twiddles: eliminates all
// 128 W1 table loads/thread and cuts pass-1 FLOPs ~4x. h-split lanes (S=2) compute
// redundant fft16, write disjoint TW'd halves (lanes stay 112/128).
// swzImg>0: XCD swizzle (R6: FETCH 76->16MB on F-step).
template<int N1, int N2, int TA, int FOLD, int BS, bool REAL, int SGN, int S2>
__global__ __launch_bounds__(BS) void rk(
    const void* __restrict__ inBase, int inShift,
    const float* __restrict__ fltBase, int fltMask,
    const float2* __restrict__ FT, float2* __restrict__ out,
    int swzImg, int inStride, int inOff)
{
    constexpr int N = N1 * N2;
    constexpr int NIN = N * FOLD;
    constexpr int ZS = N + 2;
    constexpr int TS = N2 * (N1 + 1);
    constexpr int K2C = N2 / S2;
    __shared__ float2 Z[TA * ZS];
    __shared__ float2 T[TA * TS];
    const float2* W2 = FT + N1 * N1;
    const float2* TW = FT + N1 * N1 + N2 * N2;
    const int bx = blockIdx.x, a0 = blockIdx.y * TA, t = threadIdx.x;
    int gIn, gFlt, gOut;
    if (swzImg > 0) {
        int img = bx % swzImg, sub = bx / swzImg;
        gIn = img * inStride + inOff; gFlt = sub; gOut = img * (gridDim.x / swzImg) + sub;
    } else {
        gIn = bx >> inShift; gFlt = bx & fltMask; gOut = bx;
    }

    if (REAL) {
        const float* in = (const float*)inBase + (size_t)gIn * N * N;
        for (int r = 0; r < TA; ++r)
            for (int b = t; b < N; b += BS)
                Z[r * ZS + b] = make_float2(in[(size_t)(a0 + r) * N + b], 0.f);
    } else {
        const float2* in = (const float2*)inBase + (size_t)gIn * (NIN * NIN);
        const float* flt = fltBase + (size_t)gFlt * (NIN * NIN);
        const float s = 1.0f / (float)(FOLD * FOLD);
        for (int r = 0; r < TA; ++r) {
            int a = a0 + r;
            for (int b = t; b < N; b += BS) {
                float re = 0.f, im = 0.f;
#pragma unroll
                for (int i = 0; i < FOLD; ++i)
#pragma unroll
                    for (int j = 0; j < FOLD; ++j) {
                        int idx = (a + N * i) * NIN + (b + N * j);
                        float2 v = in[idx];
                        float f = flt[idx];
                        re += v.x * f; im += v.y * f;
                    }
                Z[r * ZS + b] = make_float2(re * s, im * s);
            }
        }
    }
    __syncthreads();
    // pass 1: fft16 per (r, n2); h in {0,1} redundant compute, disjoint writes.
    for (int idx = t; idx < TA * N2 * 2; idx += BS) {
        int r = idx / (N2 * 2);
        int rem = idx % (N2 * 2);
        int n2 = rem / 2, h = rem % 2;
        float2 xx[16];
#pragma unroll
        for (int n1 = 0; n1 < 16; ++n1) xx[n1] = Z[r * ZS + n1 * N2 + n2];
        fft16<SGN>(xx);
#pragma unroll
        for (int kk = 0; kk < 8; ++kk) {
            int k1 = h * 8 + kk;
            float2 tw = TW[n2 * N1 + k1];
            T[r * TS + n2 * (N1 + 1) + k1] = cmulc(xx[k1], tw.x, tw.y);
        }
    }
    __syncthreads();
    // pass 2: thread (r, k1, h) -> Z[r][k1 + N1*(h*K2C .. +K2C)]   (dense N2-pt)
    for (int idx = t; idx < TA * N1 * S2; idx += BS) {
        int r = idx / (N1 * S2);
        int rem = idx % (N1 * S2);
        int k1 = rem / S2, h = rem % S2;
        float2 acc[K2C];
#pragma unroll
        for (int kk = 0; kk < K2C; ++kk) acc[kk] = make_float2(0.f, 0.f);
        for (int n2 = 0; n2 < N2; ++n2) {
            float2 tv = T[r * TS + n2 * (N1 + 1) + k1];
#pragma unroll
            for (int kk = 0; kk < K2C; ++kk) cmac(acc[kk], tv, W2[n2 * N2 + h * K2C + kk]);
        }
#pragma unroll
        for (int kk = 0; kk < K2C; ++kk) Z[r * ZS + k1 + N1 * (h * K2C + kk)] = acc[kk];
    }
    __syncthreads();
    for (int r = 0; r < TA; ++r) {
        float2* o = out + ((size_t)gOut * N + (a0 + r)) * N;
        for (int b = t; b < N; b += BS) o[b] = Z[r * ZS + b];
    }
}

// ---------------- ck1: col pass stage 1 — fft16 columns (R13) ----------------
// Was dense 256-cmac + 256 W1 loads per column pair; now 2x fft16 + TW (zero W1 loads).
template<int N1, int N2, int SPLIT, int BS, int SGN>
__global__ __launch_bounds__(BS) void ck1(
    const float2* __restrict__ in, const float2* __restrict__ FT, float2* __restrict__ out)
{
    constexpr int N = N1 * N2;
    constexpr int NC = N / SPLIT;
    const float2* TW = FT + N1 * N1 + N2 * N2;
    const int g = blockIdx.x / SPLIT, half = blockIdx.x % SPLIT;
    const int n2 = blockIdx.y, t = threadIdx.x;
    if (2 * t >= NC) return;
    const int b0 = 2 * t + half * NC;
    const float2* I = in + (size_t)g * N * N;
    float2 a0[16], a1[16];
#pragma unroll
    for (int n1 = 0; n1 < 16; ++n1) {
        float4 v = *reinterpret_cast<const float4*>(&I[(size_t)(n1 * N2 + n2) * N + b0]);
        a0[n1] = make_float2(v.x, v.y);
        a1[n1] = make_float2(v.z, v.w);
    }
    fft16<SGN>(a0);
    fft16<SGN>(a1);
#pragma unroll
    for (int k1 = 0; k1 < 16; ++k1) {
        float2 tw = TW[n2 * N1 + k1];
        float2 r0 = cmulc(a0[k1], tw.x, tw.y);
        float2 r1 = cmulc(a1[k1], tw.x, tw.y);
        *reinterpret_cast<float4*>(&out[((size_t)g * N + (k1 * N2 + n2)) * N + b0]) =
            make_float4(r0.x, r0.y, r1.x, r1.y);
    }
}

// ---------------- ck2: col pass stage 2 + MODE (dense N2-pt; unchanged) ----------------
template<int N1, int N2, int SPLIT, int MODE, int BS>
__global__ __launch_bounds__(BS) void ck2(
    const float2* __restrict__ in, const float2* __restrict__ FT,
    float2* __restrict__ outc, float* __restrict__ outr)
{
    constexpr int N = N1 * N2;
    constexpr int NC = N / SPLIT;
    const float2* W2 = FT + N1 * N1;
    const int g = blockIdx.x / SPLIT, half = blockIdx.x % SPLIT;
    const int k1 = blockIdx.y, t = threadIdx.x;
    if (2 * t >= NC) return;
    const int b0 = 2 * t + half * NC;
    const float2* I = in + (size_t)g * N * N;
    float2 acc[N2][2];
#pragma unroll
    for (int k2 = 0; k2 < N2; ++k2) { acc[k2][0] = make_float2(0.f, 0.f); acc[k2][1] = make_float2(0.f, 0.f); }
    for (int n2 = 0; n2 < N2; ++n2) {
        float4 v = *reinterpret_cast<const float4*>(&I[(size_t)(k1 * N2 + n2) * N + b0]);
        float2 v0 = make_float2(v.x, v.y), v1 = make_float2(v.z, v.w);
#pragma unroll
        for (int k2 = 0; k2 < N2; ++k2) {
            float2 w = W2[n2 * N2 + k2];
            cmac(acc[k2][0], v0, w);
            cmac(acc[k2][1], v1, w);
        }
    }
    if (MODE == 0) {
#pragma unroll
        for (int k2 = 0; k2 < N2; ++k2)
            *reinterpret_cast<float4*>(&outc[((size_t)g * N + (k1 + N1 * k2)) * N + b0]) =
                make_float4(acc[k2][0].x, acc[k2][0].y, acc[k2][1].x, acc[k2][1].y);
    } else {
#pragma unroll
        for (int k2 = 0; k2 < N2; ++k2) {
            size_t o = ((size_t)g * N + (k1 + N1 * k2)) * N + b0;
            outr[o]     = sqrtf(acc[k2][0].x * acc[k2][0].x + acc[k2][0].y * acc[k2][0].y);
            outr[o + 1] = sqrtf(acc[k2][1].x * acc[k2][1].x + acc[k2][1].y * acc[k2][1].y);
        }
    }
}

// ---------------- 56-res dense kernels (R6-proven) ----------------
template<int NOUT, int FOLD, int TA, int BS>
__global__ __launch_bounds__(BS) void rowpass_c(
    const float2* __restrict__ inBase, int inShift,
    const float* __restrict__ fltBase, int fltMask,
    const float2* __restrict__ W, float2* __restrict__ out)
{
    constexpr int NIN = NOUT * FOLD;
    __shared__ float2 Z[TA * NOUT];
    const int g = blockIdx.x;
    const int a0 = blockIdx.y * TA;
    const float2* in = inBase + (size_t)(g >> inShift) * (NIN * NIN);
    const float* flt = fltBase + (size_t)(g & fltMask) * (NIN * NIN);
    const int t = threadIdx.x;
    const float s = 1.0f / (float)(FOLD * FOLD);
    for (int r = 0; r < TA; ++r) {
        const int a = a0 + r;
        for (int b = t; b < NOUT; b += BS) {
            float re = 0.f, im = 0.f;
#pragma unroll
            for (int i = 0; i < FOLD; ++i)
#pragma unroll
                for (int j = 0; j < FOLD; ++j) {
                    const int idx = (a + NOUT * i) * NIN + (b + NOUT * j);
                    float2 v = in[idx];
                    float f = flt[idx];
                    re += v.x * f; im += v.y * f;
                }
            Z[r * NOUT + b] = make_float2(re * s, im * s);
        }
    }
    __syncthreads();
    const int k0 = 2 * t;
    if (k0 < NOUT) {
        float2 acc[TA][2];
#pragma unroll
        for (int r = 0; r < TA; ++r) {
            acc[r][0] = make_float2(0.f, 0.f);
            acc[r][1] = make_float2(0.f, 0.f);
        }
        for (int b = 0; b < NOUT; ++b) {
            float4 w = *reinterpret_cast<const float4*>(&W[b * NOUT + k0]);
#pragma unroll
            for (int r = 0; r < TA; ++r) {
                float2 z = Z[r * NOUT + b];
                acc[r][0].x += z.x * w.x - z.y * w.y;
                acc[r][0].y += z.x * w.y + z.y * w.x;
                acc[r][1].x += z.x * w.z - z.y * w.w;
                acc[r][1].y += z.x * w.w + z.y * w.z;
            }
        }
        float2* o = out + ((size_t)g * NOUT + a0) * NOUT + k0;
#pragma unroll
        for (int r = 0; r < TA; ++r)
            *reinterpret_cast<float4*>(&o[(size_t)r * NOUT]) =
                make_float4(acc[r][0].x, acc[r][0].y, acc[r][1].x, acc[r][1].y);
    }
}

template<int N, int TK, int BS>
__global__ __launch_bounds__(BS) void colpass_max(
    const float2* __restrict__ in, const float2* __restrict__ W,
    unsigned* __restrict__ gk, int slotBase, int slotShift, int slotMask)
{
    __shared__ float2 Wl[N * TK];
    const int g = blockIdx.x;
    const int k0 = blockIdx.y * TK;
    const float2* I = in + (size_t)g * (N * N);
    const int t = threadIdx.x;
    for (int idx = t; idx < N * TK; idx += BS) {
        int a = idx / TK, kt = idx % TK;
        Wl[idx] = W[a * N + k0 + kt];
    }
    __syncthreads();
    const int b0 = 2 * t;
    float m = -INFINITY;
    if (b0 < N) {
        float2 acc[TK][2];
#pragma unroll
        for (int kt = 0; kt < TK; ++kt) {
            acc[kt][0] = make_float2(0.f, 0.f);
            acc[kt][1] = make_float2(0.f, 0.f);
        }
        for (int a = 0; a < N; ++a) {
            float4 v = *reinterpret_cast<const float4*>(&I[(size_t)a * N + b0]);
#pragma unroll
            for (int kt = 0; kt < TK; ++kt) {
                float2 w = Wl[a * TK + kt];
                acc[kt][0].x += w.x * v.x - w.y * v.y;
                acc[kt][1].x += w.x * v.z - w.y * v.w;
            }
        }
#pragma unroll
        for (int kt = 0; kt < TK; ++kt)
            m = fmaxf(m, fmaxf(acc[kt][0].x, acc[kt][1].x));
    }
    for (int off = 32; off > 0; off >>= 1)
        m = fmaxf(m, __shfl_down(m, off, 64));
    if (t == 0) {
        int slot = slotBase + ((g >> slotShift) * 81) + (g & slotMask);
        atomicMax(&gk[slot], fkey(m));
    }
}

// ---------------- classifier head ----------------
__global__ void k_linear(const unsigned* __restrict__ gk, const float* __restrict__ Wl,
                         const float* __restrict__ bl, float* __restrict__ out)
{
    int i = blockIdx.x * blockDim.x + threadIdx.x;
    if (i >= 16 * 1000) return;
    int b = i / 1000, o = i % 1000;
    float s = bl[o];
    for (int f = 0; f < 243; ++f)
        s += funkey(gk[b * 243 + f]) * Wl[o * 243 + f];
    out[i] = s;
}

// ---------------- launch ----------------
extern "C" void kernel_launch(void* const* d_in, const int* in_sizes, int n_in,
                              void* d_out, int out_size, void* d_ws, size_t ws_size,
                              hipStream_t stream)
{
    const float* x  = (const float*)d_in[0];
    const float* Wl = (const float*)d_in[1];
    const float* bl = (const float*)d_in[2];
    float* out = (float*)d_out;
    float* ws = (float*)d_ws;

    float2* FT224F = (float2*)(ws + OFF_FT224F);
    float2* FT224I = (float2*)(ws + OFF_FT224I);
    float2* FT112F = (float2*)(ws + OFF_FT112F);
    float2* FT112I = (float2*)(ws + OFF_FT112I);
    float2* F56I  = (float2*)(ws + OFF_F56I);
    float* PSI0 = ws + OFF_PSI;
    float* PSI1 = ws + OFF_PSI + 8 * IMG224;
    float* PHI0 = ws + OFF_PHI0;
    float* PHI1 = ws + OFF_PHI1;
    unsigned* GK = (unsigned*)(ws + OFF_GK);
    float2* XH  = (float2*)(ws + OFF_XH);
    float* A0  = ws + OFF_POOL;          // 9633792 floats
    float* A1  = A0 + 9633792;           // 9633792
    float* A23 = A1 + 9633792;           // 9633792

    // tables
    k_fact<<<4, 256, 0, stream>>>(FT224F, 16, 14, -1.0, 1.0);
    k_fact<<<4, 256, 0, stream>>>(FT224I, 16, 14,  1.0, 1.0 / 224.0);
    k_fact<<<4, 256, 0, stream>>>(FT112F, 16, 7,  -1.0, 1.0);
    k_fact<<<4, 256, 0, stream>>>(FT112I, 16, 7,   1.0, 1.0 / 112.0);
    k_dft<<<(56*56 + 255) / 256, 256, 0, stream>>>(F56I, 56, 1.0, 1.0 / 56.0);
    k_psi<<<(16 * IMG224 + 255) / 256, 256, 0, stream>>>(ws + OFF_PSI);
    k_phi<<<(IMG224 + IMG112 + 255) / 256, 256, 0, stream>>>(PHI0, PHI1);
    k_zero<<<(3888 + 255) / 256, 256, 0, stream>>>(GK, 3888);

    // ---- fft2(x) -> XH ----
    rk<16, 14, 4, 1, 128, true, -1, 2><<<dim3(48, 56), 128, 0, stream>>>(x, 0, nullptr, 0, FT224F, (float2*)A0, 0, 0, 0);
    ck1<16, 14, 2, 64, -1><<<dim3(96, 14), 64, 0, stream>>>((float2*)A0, FT224F, (float2*)A1);
    ck2<16, 14, 2, 0, 64><<<dim3(96, 16), 64, 0, stream>>>((float2*)A1, FT224F, XH, nullptr);

    // ---- s0 -> GK slot img*81+0 ----
    rowpass_c<56, 4, 8, 64><<<dim3(48, 7), 64, 0, stream>>>(XH, 0, PHI0, 0, F56I, (float2*)A1);
    colpass_max<56, 8, 64><<<dim3(48, 7), 64, 0, stream>>>((float2*)A1, F56I, GK, 0, 0, 0);

    // ---- pair-batched first order j1=0 (+ second order); g = img*2 + lc, l1 = 2c+lc ----
    for (int c = 0; c < 4; ++c) {
        // A: ifft rows of xh*psi0[l1] -> A0 (96 groups)
        rk<16, 14, 4, 1, 128, false, 1, 2><<<dim3(96, 56), 128, 0, stream>>>(
            XH, 1, PSI0 + (size_t)(2 * c) * IMG224, 1, FT224I, (float2*)A0, 0, 0, 0);
        // B: ifft cols + |.| -> A23 (real u1)
        ck1<16, 14, 2, 64, 1><<<dim3(192, 14), 64, 0, stream>>>((float2*)A0, FT224I, (float2*)A1);
        ck2<16, 14, 2, 1, 64><<<dim3(192, 16), 64, 0, stream>>>((float2*)A1, FT224I, nullptr, A23);
        // C: fft rows of u1 (real) -> A0
        rk<16, 14, 4, 1, 128, true, -1, 2><<<dim3(96, 56), 128, 0, stream>>>(A23, 0, nullptr, 0, FT224F, (float2*)A0, 0, 0, 0);
        // D: fft cols -> V1 (A0)
        ck1<16, 14, 2, 64, -1><<<dim3(192, 14), 64, 0, stream>>>((float2*)A0, FT224F, (float2*)A1);
        ck2<16, 14, 2, 0, 64><<<dim3(192, 16), 64, 0, stream>>>((float2*)A1, FT224F, (float2*)A0, nullptr);
        // E: s1 -> GK slot img*81 + 1 + 2c + lc
        rowpass_c<56, 4, 8, 64><<<dim3(96, 7), 64, 0, stream>>>((float2*)A0, 0, PHI0, 0, F56I, (float2*)A1);
        colpass_max<56, 8, 64><<<dim3(96, 7), 64, 0, stream>>>((float2*)A1, F56I, GK, 1 + 2 * c, 1, 1);
        // second order per l1 in pair (V1 stays live in A0)
        for (int lc = 0; lc < 2; ++lc) {
            int l1 = 2 * c + lc;
            // F: ifft112 rows of fold(V1*psi1[l2],2) [XCD swizzle] -> A1
            rk<16, 7, 8, 2, 128, false, 1, 1><<<dim3(384, 14), 128, 0, stream>>>(
                (float2*)A0, 0, PSI1, 7, FT112I, (float2*)A1, 48, 2, lc);
            // G: ifft112 cols + |.| : A1 -> A23 (stage1) -> A1 (real u2)
            ck1<16, 7, 1, 64, 1><<<dim3(384, 7), 64, 0, stream>>>((float2*)A1, FT112I, (float2*)A23);
            ck2<16, 7, 1, 1, 64><<<dim3(384, 16), 64, 0, stream>>>((float2*)A23, FT112I, nullptr, A1);
            // H: fft112 rows of u2 (real) -> A23
            rk<16, 7, 8, 1, 128, true, -1, 1><<<dim3(384, 14), 128, 0, stream>>>(A1, 0, nullptr, 0, FT112F, (float2*)A23, 0, 0, 0);
            // I: fft112 cols: A23 -> A1 (stage1) -> A23 (u2h)
            ck1<16, 7, 1, 64, -1><<<dim3(384, 7), 64, 0, stream>>>((float2*)A23, FT112F, (float2*)A1);
            ck2<16, 7, 1, 0, 64><<<dim3(384, 16), 64, 0, stream>>>((float2*)A1, FT112F, (float2*)A23, nullptr);
            // JK: s2 -> GK slot img*81 + 17 + 8*l1 + l2
            rowpass_c<56, 2, 8, 64><<<dim3(384, 7), 64, 0, stream>>>((float2*)A23, 0, PHI1, 0, F56I, (float2*)A1);
            colpass_max<56, 8, 64><<<dim3(384, 7), 64, 0, stream>>>((float2*)A1, F56I, GK, 17 + 8 * l1, 3, 7);
        }
    }

    // ---- first order j1=1 (8 orientations, g = img*8+l) ----
    rk<16, 7, 8, 2, 128, false, 1, 1><<<dim3(384, 14), 128, 0, stream>>>(XH, 0, PSI1, 7, FT112I, (float2*)A1, 48, 1, 0);
    ck1<16, 7, 1, 64, 1><<<dim3(384, 7), 64, 0, stream>>>((float2*)A1, FT112I, (float2*)A23);
    ck2<16, 7, 1, 1, 64><<<dim3(384, 16), 64, 0, stream>>>((float2*)A23, FT112I, nullptr, A1);
    rk<16, 7, 8, 1, 128, true, -1, 1><<<dim3(384, 14), 128, 0, stream>>>(A1, 0, nullptr, 0, FT112F, (float2*)A23, 0, 0, 0);
    ck1<16, 7, 1, 64, -1><<<dim3(384, 7), 64, 0, stream>>>((float2*)A23, FT112F, (float2*)A1);
    ck2<16, 7, 1, 0, 64><<<dim3(384, 16), 64, 0, stream>>>((float2*)A1, FT112F, (float2*)A23, nullptr);
    rowpass_c<56, 2, 8, 64><<<dim3(384, 7), 64, 0, stream>>>((float2*)A23, 0, PHI1, 0, F56I, (float2*)A1);
    colpass_max<56, 8, 64><<<dim3(384, 7), 64, 0, stream>>>((float2*)A1, F56I, GK, 9, 3, 7);

    // head
    k_linear<<<(16000 + 255) / 256, 256, 0, stream>>>(GK, Wl, bl, out);
}

// Round 14
// 2600.077 us; speedup vs baseline: 1.6108x; 1.1026x over previous
//
#include <hip/hip_runtime.h>
#include <math.h>

#define PI_D 3.14159265358979323846

// ---------------- workspace layout (float units) ----------------
#define IMG224 50176
#define IMG112 12544
// factorized DFT tables per (N,dir): [W1:N1*N1 | W2:N2*N2 | TW:N2*N1 | (r2: W7:49 | T14:14)]
static const size_t OFF_FT224F = 0;        // 739 float2 used, 1024 reserved
static const size_t OFF_FT224I = 2048;
static const size_t OFF_FT112F = 4096;
static const size_t OFF_FT112I = 6144;
static const size_t OFF_F56I  = 250880;    // 6272 (dense 56 inverse)
static const size_t OFF_PSI   = 257152;    // 16*50176
static const size_t OFF_PHI0  = 1059968;
static const size_t OFF_PHI1  = 1110144;
static const size_t OFF_GK    = 1122688;   // 3888 keys
static const size_t OFF_XH    = 1126784;   // 4816896
static const size_t OFF_POOL  = 5943680;
// arena: A0, A1, A23 = 9633792 floats each -> ~139 MB total (< known-good 149 MB)

// ---------------- helpers ----------------
__device__ inline unsigned fkey(float v) {
    int b = __float_as_int(v);
    return (b >= 0) ? ((unsigned)b | 0x80000000u) : ~(unsigned)b;
}
__device__ inline float funkey(unsigned u) {
    int b = (u & 0x80000000u) ? (int)(u & 0x7fffffffu) : (int)~u;
    return __int_as_float(b);
}
__device__ inline void cmac(float2& a, float2 z, float2 w) {
    a.x += z.x * w.x - z.y * w.y;
    a.y += z.x * w.y + z.y * w.x;
}
__device__ inline float2 cmulc(float2 v, float c, float s) {
    return make_float2(v.x * c - v.y * s, v.x * s + v.y * c);
}

// 16-point DFT, radix-4 x radix-4, constant twiddles (zero table loads). R13-proven.
template<int SGN>
__device__ inline void fft16(float2* x) {
    const float C8  = 0.70710678118654752f;
    const float C16 = 0.92387953251128674f;
    const float S16 = 0.38268343236508977f;
    const float sg = (float)SGN;
    float2 g[16];
#pragma unroll
    for (int b = 0; b < 4; ++b) {
        float2 x0 = x[b], x1 = x[4 + b], x2 = x[8 + b], x3 = x[12 + b];
        float2 e0 = make_float2(x0.x + x2.x, x0.y + x2.y);
        float2 e1 = make_float2(x0.x - x2.x, x0.y - x2.y);
        float2 o0 = make_float2(x1.x + x3.x, x1.y + x3.y);
        float2 o1 = make_float2(x1.x - x3.x, x1.y - x3.y);
        float2 io1 = (SGN > 0) ? make_float2(-o1.y, o1.x) : make_float2(o1.y, -o1.x);
        g[b * 4 + 0] = make_float2(e0.x + o0.x, e0.y + o0.y);
        g[b * 4 + 2] = make_float2(e0.x - o0.x, e0.y - o0.y);
        g[b * 4 + 1] = make_float2(e1.x + io1.x, e1.y + io1.y);
        g[b * 4 + 3] = make_float2(e1.x - io1.x, e1.y - io1.y);
    }
    g[5]  = cmulc(g[5],  C16,  sg * S16);
    g[6]  = cmulc(g[6],  C8,   sg * C8);
    g[7]  = cmulc(g[7],  S16,  sg * C16);
    g[9]  = cmulc(g[9],  C8,   sg * C8);
    g[10] = (SGN > 0) ? make_float2(-g[10].y, g[10].x)
                      : make_float2(g[10].y, -g[10].x);
    g[11] = cmulc(g[11], -C8,  sg * C8);
    g[13] = cmulc(g[13], S16,  sg * C16);
    g[14] = cmulc(g[14], -C8,  sg * C8);
    g[15] = cmulc(g[15], -C16, -sg * S16);
#pragma unroll
    for (int p = 0; p < 4; ++p) {
        float2 x0 = g[p], x1 = g[4 + p], x2 = g[8 + p], x3 = g[12 + p];
        float2 e0 = make_float2(x0.x + x2.x, x0.y + x2.y);
        float2 e1 = make_float2(x0.x - x2.x, x0.y - x2.y);
        float2 o0 = make_float2(x1.x + x3.x, x1.y + x3.y);
        float2 o1 = make_float2(x1.x - x3.x, x1.y - x3.y);
        float2 io1 = (SGN > 0) ? make_float2(-o1.y, o1.x) : make_float2(o1.y, -o1.x);
        x[p + 0]  = make_float2(e0.x + o0.x, e0.y + o0.y);
        x[p + 8]  = make_float2(e0.x - o0.x, e0.y - o0.y);
        x[p + 4]  = make_float2(e1.x + io1.x, e1.y + io1.y);
        x[p + 12] = make_float2(e1.x - io1.x, e1.y - io1.y);
    }
}

// ---------------- table builders ----------------
__global__ void k_dft(float2* out, int n, double sign, double scale) {
    int i = blockIdx.x * blockDim.x + threadIdx.x;
    if (i >= n * n) return;
    int c = i / n, k = i % n;
    int m = (c * k) % n;
    double ang = sign * 2.0 * PI_D * (double)m / (double)n;
    out[i] = make_float2((float)(scale * cos(ang)), (float)(scale * sin(ang)));
}

// r2: also emit [W7: scale*e^{s*2pi*i*nk/7} (49) | T14: e^{s*2pi*i*k/14} (14)]
__global__ void k_fact(float2* o, int N1, int N2, double sign, double scale, int r2) {
    int base3 = N1 * N1 + N2 * N2 + N2 * N1;
    int total = base3 + (r2 ? 63 : 0);
    int N = N1 * N2;
    for (int i = blockIdx.x * blockDim.x + threadIdx.x; i < total; i += blockDim.x * gridDim.x) {
        double ang; double sc = 1.0;
        if (i < N1 * N1) {
            int n1 = i / N1, k1 = i % N1;
            ang = sign * 2.0 * PI_D * (double)((n1 * k1) % N1) / (double)N1;
        } else if (i < N1 * N1 + N2 * N2) {
            int j = i - N1 * N1; int n2 = j / N2, k2 = j % N2;
            ang = sign * 2.0 * PI_D * (double)((n2 * k2) % N2) / (double)N2;
            sc = scale;
        } else if (i < base3) {
            int j = i - N1 * N1 - N2 * N2; int n2 = j / N1, k1 = j % N1;
            ang = sign * 2.0 * PI_D * (double)((n2 * k1) % N) / (double)N;
        } else if (i < base3 + 49) {
            int j = i - base3; int n = j / 7, k = j % 7;
            ang = sign * 2.0 * PI_D * (double)((n * k) % 7) / 7.0;
            sc = scale;
        } else {
            int k = i - base3 - 49;
            ang = sign * 2.0 * PI_D * (double)k / 14.0;
        }
        o[i] = make_float2((float)(sc * cos(ang)), (float)(sc * sin(ang)));
    }
}

__global__ void k_psi(float* out) {
    int i = blockIdx.x * blockDim.x + threadIdx.x;
    if (i >= 16 * IMG224) return;
    int jl = i / IMG224, p = i % IMG224;
    int r = p / 224, c = p % 224;
    int j = jl >> 3, l = jl & 7;
    double fr = (r < 112) ? (double)r : (double)(r - 224);
    double fc = (c < 112) ? (double)c : (double)(c - 224);
    double wx = 2.0 * PI_D * fr / 224.0;
    double wy = 2.0 * PI_D * fc / 224.0;
    double theta = (double)l * PI_D / 8.0;
    double xi = (3.0 * PI_D / 4.0) / (double)(1 << j);
    double sg = 0.8 * (double)(1 << j);
    double ct = cos(theta), st = sin(theta);
    double u = ct * wx + st * wy;
    double v = -st * wx + ct * wy;
    double vs = v / 0.5;
    double s2 = 0.5 * sg * sg;
    double gab = exp(-s2 * ((u - xi) * (u - xi) + vs * vs));
    double gau = exp(-s2 * (u * u + vs * vs));
    double kap = exp(-s2 * xi * xi);
    out[i] = (float)(gab - kap * gau);
}

__global__ void k_phi(float* phi0, float* phi1) {
    int i = blockIdx.x * blockDim.x + threadIdx.x;
    const double sp = 1.6;
    const double s2 = 0.5 * sp * sp;
    if (i < IMG224) {
        int r = i / 224, c = i % 224;
        double fr = (r < 112) ? (double)r : (double)(r - 224);
        double fc = (c < 112) ? (double)c : (double)(c - 224);
        double wx = 2.0 * PI_D * fr / 224.0;
        double wy = 2.0 * PI_D * fc / 224.0;
        phi0[i] = (float)exp(-s2 * (wx * wx + wy * wy));
    } else if (i < IMG224 + IMG112) {
        int p = i - IMG224, a = p / 112, b = p % 112;
        double sum = 0.0;
        for (int ii = 0; ii < 2; ++ii)
            for (int jj = 0; jj < 2; ++jj) {
                int r = a + 112 * ii, c = b + 112 * jj;
                double fr = (r < 112) ? (double)r : (double)(r - 224);
                double fc = (c < 112) ? (double)c : (double)(c - 224);
                double wx = 2.0 * PI_D * fr / 224.0;
                double wy = 2.0 * PI_D * fc / 224.0;
                sum += exp(-s2 * (wx * wx + wy * wy));
            }
        phi1[p] = (float)(0.25 * sum);
    }
}

__global__ void k_zero(unsigned* gk, int n) {
    int i = blockIdx.x * blockDim.x + threadIdx.x;
    if (i < n) gk[i] = 0u;
}

// ---------------- rk: row pass, two-stage (N=16*N2), fused in LDS ----------------
// R8-proven two-buffer structure. R13: pass-1 = constant-twiddle fft16 (no W1 loads).
// R14: pass-2 for N2=14 uses DIT 14=2x7: X[k]=E[k%7]+T14[k]*O[k%7] (2x49 cmacs+14
// cmuls vs 196 cmacs, half the table loads). N2=7 keeps dense 7-pt.
// swzImg>0: XCD swizzle (R6: FETCH 76->16MB on F-step).
template<int N1, int N2, int TA, int FOLD, int BS, bool REAL, int SGN>
__global__ __launch_bounds__(BS) void rk(
    const void* __restrict__ inBase, int inShift,
    const float* __restrict__ fltBase, int fltMask,
    const float2* __restrict__ FT, float2* __restrict__ out,
    int swzImg, int inStride, int inOff)
{
    constexpr int N = N1 * N2;
    constexpr int NIN = N * FOLD;
    constexpr int ZS = N + 2;
    constexpr int TS = N2 * (N1 + 1);
    __shared__ float2 Z[TA * ZS];
    __shared__ float2 T[TA * TS];
    const float2* W2 = FT + N1 * N1;
    const float2* TW = FT + N1 * N1 + N2 * N2;
    const int bx = blockIdx.x, a0 = blockIdx.y * TA, t = threadIdx.x;
    int gIn, gFlt, gOut;
    if (swzImg > 0) {
        int img = bx % swzImg, sub = bx / swzImg;
        gIn = img * inStride + inOff; gFlt = sub; gOut = img * (gridDim.x / swzImg) + sub;
    } else {
        gIn = bx >> inShift; gFlt = bx & fltMask; gOut = bx;
    }

    if (REAL) {
        const float* in = (const float*)inBase + (size_t)gIn * N * N;
        for (int r = 0; r < TA; ++r)
            for (int b = t; b < N; b += BS)
                Z[r * ZS + b] = make_float2(in[(size_t)(a0 + r) * N + b], 0.f);
    } else {
        const float2* in = (const float2*)inBase + (size_t)gIn * (NIN * NIN);
        const float* flt = fltBase + (size_t)gFlt * (NIN * NIN);
        const float s = 1.0f / (float)(FOLD * FOLD);
        for (int r = 0; r < TA; ++r) {
            int a = a0 + r;
            for (int b = t; b < N; b += BS) {
                float re = 0.f, im = 0.f;
#pragma unroll
                for (int i = 0; i < FOLD; ++i)
#pragma unroll
                    for (int j = 0; j < FOLD; ++j) {
                        int idx = (a + N * i) * NIN + (b + N * j);
                        float2 v = in[idx];
                        float f = flt[idx];
                        re += v.x * f; im += v.y * f;
                    }
                Z[r * ZS + b] = make_float2(re * s, im * s);
            }
        }
    }
    __syncthreads();
    // pass 1: fft16 per (r, n2); h in {0,1} redundant compute, disjoint writes.
    for (int idx = t; idx < TA * N2 * 2; idx += BS) {
        int r = idx / (N2 * 2);
        int rem = idx % (N2 * 2);
        int n2 = rem / 2, h = rem % 2;
        float2 xx[16];
#pragma unroll
        for (int n1 = 0; n1 < 16; ++n1) xx[n1] = Z[r * ZS + n1 * N2 + n2];
        fft16<SGN>(xx);
#pragma unroll
        for (int kk = 0; kk < 8; ++kk) {
            int k1 = h * 8 + kk;
            float2 tw = TW[n2 * N1 + k1];
            T[r * TS + n2 * (N1 + 1) + k1] = cmulc(xx[k1], tw.x, tw.y);
        }
    }
    __syncthreads();
    // pass 2
    if constexpr (N2 == 14) {
        const float2* W7  = FT + N1 * N1 + N2 * N2 + N2 * N1;
        const float2* T14 = W7 + 49;
        for (int idx = t; idx < TA * N1; idx += BS) {
            int r = idx / N1, k1 = idx % N1;
            float2 E[7], O[7];
#pragma unroll
            for (int k = 0; k < 7; ++k) { E[k] = make_float2(0.f, 0.f); O[k] = make_float2(0.f, 0.f); }
            for (int m = 0; m < 7; ++m) {
                float2 te = T[r * TS + (2 * m) * (N1 + 1) + k1];
                float2 to = T[r * TS + (2 * m + 1) * (N1 + 1) + k1];
#pragma unroll
                for (int k = 0; k < 7; ++k) {
                    float2 w = W7[m * 7 + k];
                    cmac(E[k], te, w);
                    cmac(O[k], to, w);
                }
            }
#pragma unroll
            for (int k = 0; k < 14; ++k) {
                float2 tw = T14[k];
                float2 o_ = O[k % 7];
                float2 X = E[k % 7];
                X.x += o_.x * tw.x - o_.y * tw.y;
                X.y += o_.x * tw.y + o_.y * tw.x;
                Z[r * ZS + k1 + N1 * k] = X;
            }
        }
    } else {
        for (int idx = t; idx < TA * N1; idx += BS) {
            int r = idx / N1, k1 = idx % N1;
            float2 acc[N2];
#pragma unroll
            for (int kk = 0; kk < N2; ++kk) acc[kk] = make_float2(0.f, 0.f);
            for (int n2 = 0; n2 < N2; ++n2) {
                float2 tv = T[r * TS + n2 * (N1 + 1) + k1];
#pragma unroll
                for (int kk = 0; kk < N2; ++kk) cmac(acc[kk], tv, W2[n2 * N2 + kk]);
            }
#pragma unroll
            for (int kk = 0; kk < N2; ++kk) Z[r * ZS + k1 + N1 * kk] = acc[kk];
        }
    }
    __syncthreads();
    for (int r = 0; r < TA; ++r) {
        float2* o = out + ((size_t)gOut * N + (a0 + r)) * N;
        for (int b = t; b < N; b += BS) o[b] = Z[r * ZS + b];
    }
}

// ---------------- ck1: col pass stage 1 — fft16 columns (R13-proven) ----------------
template<int N1, int N2, int SPLIT, int BS, int SGN>
__global__ __launch_bounds__(BS) void ck1(
    const float2* __restrict__ in, const float2* __restrict__ FT, float2* __restrict__ out)
{
    constexpr int N = N1 * N2;
    constexpr int NC = N / SPLIT;
    const float2* TW = FT + N1 * N1 + N2 * N2;
    const int g = blockIdx.x / SPLIT, half = blockIdx.x % SPLIT;
    const int n2 = blockIdx.y, t = threadIdx.x;
    if (2 * t >= NC) return;
    const int b0 = 2 * t + half * NC;
    const float2* I = in + (size_t)g * N * N;
    float2 a0[16], a1[16];
#pragma unroll
    for (int n1 = 0; n1 < 16; ++n1) {
        float4 v = *reinterpret_cast<const float4*>(&I[(size_t)(n1 * N2 + n2) * N + b0]);
        a0[n1] = make_float2(v.x, v.y);
        a1[n1] = make_float2(v.z, v.w);
    }
    fft16<SGN>(a0);
    fft16<SGN>(a1);
#pragma unroll
    for (int k1 = 0; k1 < 16; ++k1) {
        float2 tw = TW[n2 * N1 + k1];
        float2 r0 = cmulc(a0[k1], tw.x, tw.y);
        float2 r1 = cmulc(a1[k1], tw.x, tw.y);
        *reinterpret_cast<float4*>(&out[((size_t)g * N + (k1 * N2 + n2)) * N + b0]) =
            make_float4(r0.x, r0.y, r1.x, r1.y);
    }
}

// ---------------- ck2: col pass stage 2 + MODE ----------------
// R14: N2=14 path uses DIT 14=2x7 (E/O 7-pt DFTs + T14 twiddles); N2=7 dense.
template<int N1, int N2, int SPLIT, int MODE, int BS>
__global__ __launch_bounds__(BS) void ck2(
    const float2* __restrict__ in, const float2* __restrict__ FT,
    float2* __restrict__ outc, float* __restrict__ outr)
{
    constexpr int N = N1 * N2;
    constexpr int NC = N / SPLIT;
    const float2* W2 = FT + N1 * N1;
    const int g = blockIdx.x / SPLIT, half = blockIdx.x % SPLIT;
    const int k1 = blockIdx.y, t = threadIdx.x;
    if (2 * t >= NC) return;
    const int b0 = 2 * t + half * NC;
    const float2* I = in + (size_t)g * N * N;
    if constexpr (N2 == 14) {
        const float2* W7  = FT + N1 * N1 + N2 * N2 + N2 * N1;
        const float2* T14 = W7 + 49;
        float2 E0[7], E1[7], O0[7], O1[7];
#pragma unroll
        for (int k = 0; k < 7; ++k) {
            E0[k] = make_float2(0.f, 0.f); E1[k] = make_float2(0.f, 0.f);
            O0[k] = make_float2(0.f, 0.f); O1[k] = make_float2(0.f, 0.f);
        }
        for (int m = 0; m < 7; ++m) {
            float4 ve = *reinterpret_cast<const float4*>(&I[(size_t)(k1 * 14 + 2 * m) * N + b0]);
            float4 vo = *reinterpret_cast<const float4*>(&I[(size_t)(k1 * 14 + 2 * m + 1) * N + b0]);
            float2 ve0 = make_float2(ve.x, ve.y), ve1 = make_float2(ve.z, ve.w);
            float2 vo0 = make_float2(vo.x, vo.y), vo1 = make_float2(vo.z, vo.w);
#pragma unroll
            for (int k = 0; k < 7; ++k) {
                float2 w = W7[m * 7 + k];
                cmac(E0[k], ve0, w); cmac(E1[k], ve1, w);
                cmac(O0[k], vo0, w); cmac(O1[k], vo1, w);
            }
        }
#pragma unroll
        for (int k = 0; k < 14; ++k) {
            float2 tw = T14[k];
            float2 r0 = E0[k % 7], r1 = E1[k % 7];
            float2 o0 = O0[k % 7], o1 = O1[k % 7];
            r0.x += o0.x * tw.x - o0.y * tw.y;
            r0.y += o0.x * tw.y + o0.y * tw.x;
            r1.x += o1.x * tw.x - o1.y * tw.y;
            r1.y += o1.x * tw.y + o1.y * tw.x;
            if (MODE == 0) {
                *reinterpret_cast<float4*>(&outc[((size_t)g * N + (k1 + N1 * k)) * N + b0]) =
                    make_float4(r0.x, r0.y, r1.x, r1.y);
            } else {
                size_t o = ((size_t)g * N + (k1 + N1 * k)) * N + b0;
                outr[o]     = sqrtf(r0.x * r0.x + r0.y * r0.y);
                outr[o + 1] = sqrtf(r1.x * r1.x + r1.y * r1.y);
            }
        }
    } else {
        float2 acc[N2][2];
#pragma unroll
        for (int k2 = 0; k2 < N2; ++k2) { acc[k2][0] = make_float2(0.f, 0.f); acc[k2][1] = make_float2(0.f, 0.f); }
        for (int n2 = 0; n2 < N2; ++n2) {
            float4 v = *reinterpret_cast<const float4*>(&I[(size_t)(k1 * N2 + n2) * N + b0]);
            float2 v0 = make_float2(v.x, v.y), v1 = make_float2(v.z, v.w);
#pragma unroll
            for (int k2 = 0; k2 < N2; ++k2) {
                float2 w = W2[n2 * N2 + k2];
                cmac(acc[k2][0], v0, w);
                cmac(acc[k2][1], v1, w);
            }
        }
        if (MODE == 0) {
#pragma unroll
            for (int k2 = 0; k2 < N2; ++k2)
                *reinterpret_cast<float4*>(&outc[((size_t)g * N + (k1 + N1 * k2)) * N + b0]) =
                    make_float4(acc[k2][0].x, acc[k2][0].y, acc[k2][1].x, acc[k2][1].y);
        } else {
#pragma unroll
            for (int k2 = 0; k2 < N2; ++k2) {
                size_t o = ((size_t)g * N + (k1 + N1 * k2)) * N + b0;
                outr[o]     = sqrtf(acc[k2][0].x * acc[k2][0].x + acc[k2][0].y * acc[k2][0].y);
                outr[o + 1] = sqrtf(acc[k2][1].x * acc[k2][1].x + acc[k2][1].y * acc[k2][1].y);
            }
        }
    }
}

// ---------------- 56-res dense kernels (R6-proven) ----------------
template<int NOUT, int FOLD, int TA, int BS>
__global__ __launch_bounds__(BS) void rowpass_c(
    const float2* __restrict__ inBase, int inShift,
    const float* __restrict__ fltBase, int fltMask,
    const float2* __restrict__ W, float2* __restrict__ out)
{
    constexpr int NIN = NOUT * FOLD;
    __shared__ float2 Z[TA * NOUT];
    const int g = blockIdx.x;
    const int a0 = blockIdx.y * TA;
    const float2* in = inBase + (size_t)(g >> inShift) * (NIN * NIN);
    const float* flt = fltBase + (size_t)(g & fltMask) * (NIN * NIN);
    const int t = threadIdx.x;
    const float s = 1.0f / (float)(FOLD * FOLD);
    for (int r = 0; r < TA; ++r) {
        const int a = a0 + r;
        for (int b = t; b < NOUT; b += BS) {
            float re = 0.f, im = 0.f;
#pragma unroll
            for (int i = 0; i < FOLD; ++i)
#pragma unroll
                for (int j = 0; j < FOLD; ++j) {
                    const int idx = (a + NOUT * i) * NIN + (b + NOUT * j);
                    float2 v = in[idx];
                    float f = flt[idx];
                    re += v.x * f; im += v.y * f;
                }
            Z[r * NOUT + b] = make_float2(re * s, im * s);
        }
    }
    __syncthreads();
    const int k0 = 2 * t;
    if (k0 < NOUT) {
        float2 acc[TA][2];
#pragma unroll
        for (int r = 0; r < TA; ++r) {
            acc[r][0] = make_float2(0.f, 0.f);
            acc[r][1] = make_float2(0.f, 0.f);
        }
        for (int b = 0; b < NOUT; ++b) {
            float4 w = *reinterpret_cast<const float4*>(&W[b * NOUT + k0]);
#pragma unroll
            for (int r = 0; r < TA; ++r) {
                float2 z = Z[r * NOUT + b];
                acc[r][0].x += z.x * w.x - z.y * w.y;
                acc[r][0].y += z.x * w.y + z.y * w.x;
                acc[r][1].x += z.x * w.z - z.y * w.w;
                acc[r][1].y += z.x * w.w + z.y * w.z;
            }
        }
        float2* o = out + ((size_t)g * NOUT + a0) * NOUT + k0;
#pragma unroll
        for (int r = 0; r < TA; ++r)
            *reinterpret_cast<float4*>(&o[(size_t)r * NOUT]) =
                make_float4(acc[r][0].x, acc[r][0].y, acc[r][1].x, acc[r][1].y);
    }
}

template<int N, int TK, int BS>
__global__ __launch_bounds__(BS) void colpass_max(
    const float2* __restrict__ in, const float2* __restrict__ W,
    unsigned* __restrict__ gk, int slotBase, int slotShift, int slotMask)
{
    __shared__ float2 Wl[N * TK];
    const int g = blockIdx.x;
    const int k0 = blockIdx.y * TK;
    const float2* I = in + (size_t)g * (N * N);
    const int t = threadIdx.x;
    for (int idx = t; idx < N * TK; idx += BS) {
        int a = idx / TK, kt = idx % TK;
        Wl[idx] = W[a * N + k0 + kt];
    }
    __syncthreads();
    const int b0 = 2 * t;
    float m = -INFINITY;
    if (b0 < N) {
        float2 acc[TK][2];
#pragma unroll
        for (int kt = 0; kt < TK; ++kt) {
            acc[kt][0] = make_float2(0.f, 0.f);
            acc[kt][1] = make_float2(0.f, 0.f);
        }
        for (int a = 0; a < N; ++a) {
            float4 v = *reinterpret_cast<const float4*>(&I[(size_t)a * N + b0]);
#pragma unroll
            for (int kt = 0; kt < TK; ++kt) {
                float2 w = Wl[a * TK + kt];
                acc[kt][0].x += w.x * v.x - w.y * v.y;
                acc[kt][1].x += w.x * v.z - w.y * v.w;
            }
        }
#pragma unroll
        for (int kt = 0; kt < TK; ++kt)
            m = fmaxf(m, fmaxf(acc[kt][0].x, acc[kt][1].x));
    }
    for (int off = 32; off > 0; off >>= 1)
        m = fmaxf(m, __shfl_down(m, off, 64));
    if (t == 0) {
        int slot = slotBase + ((g >> slotShift) * 81) + (g & slotMask);
        atomicMax(&gk[slot], fkey(m));
    }
}

// ---------------- classifier head ----------------
__global__ void k_linear(const unsigned* __restrict__ gk, const float* __restrict__ Wl,
                         const float* __restrict__ bl, float* __restrict__ out)
{
    int i = blockIdx.x * blockDim.x + threadIdx.x;
    if (i >= 16 * 1000) return;
    int b = i / 1000, o = i % 1000;
    float s = bl[o];
    for (int f = 0; f < 243; ++f)
        s += funkey(gk[b * 243 + f]) * Wl[o * 243 + f];
    out[i] = s;
}

// ---------------- launch ----------------
extern "C" void kernel_launch(void* const* d_in, const int* in_sizes, int n_in,
                              void* d_out, int out_size, void* d_ws, size_t ws_size,
                              hipStream_t stream)
{
    const float* x  = (const float*)d_in[0];
    const float* Wl = (const float*)d_in[1];
    const float* bl = (const float*)d_in[2];
    float* out = (float*)d_out;
    float* ws = (float*)d_ws;

    float2* FT224F = (float2*)(ws + OFF_FT224F);
    float2* FT224I = (float2*)(ws + OFF_FT224I);
    float2* FT112F = (float2*)(ws + OFF_FT112F);
    float2* FT112I = (float2*)(ws + OFF_FT112I);
    float2* F56I  = (float2*)(ws + OFF_F56I);
    float* PSI0 = ws + OFF_PSI;
    float* PSI1 = ws + OFF_PSI + 8 * IMG224;
    float* PHI0 = ws + OFF_PHI0;
    float* PHI1 = ws + OFF_PHI1;
    unsigned* GK = (unsigned*)(ws + OFF_GK);
    float2* XH  = (float2*)(ws + OFF_XH);
    float* A0  = ws + OFF_POOL;          // 9633792 floats
    float* A1  = A0 + 9633792;           // 9633792
    float* A23 = A1 + 9633792;           // 9633792

    // tables (224 tables get the r2 = 2x7 sections)
    k_fact<<<4, 256, 0, stream>>>(FT224F, 16, 14, -1.0, 1.0, 1);
    k_fact<<<4, 256, 0, stream>>>(FT224I, 16, 14,  1.0, 1.0 / 224.0, 1);
    k_fact<<<4, 256, 0, stream>>>(FT112F, 16, 7,  -1.0, 1.0, 0);
    k_fact<<<4, 256, 0, stream>>>(FT112I, 16, 7,   1.0, 1.0 / 112.0, 0);
    k_dft<<<(56*56 + 255) / 256, 256, 0, stream>>>(F56I, 56, 1.0, 1.0 / 56.0);
    k_psi<<<(16 * IMG224 + 255) / 256, 256, 0, stream>>>(ws + OFF_PSI);
    k_phi<<<(IMG224 + IMG112 + 255) / 256, 256, 0, stream>>>(PHI0, PHI1);
    k_zero<<<(3888 + 255) / 256, 256, 0, stream>>>(GK, 3888);

    // ---- fft2(x) -> XH ----
    rk<16, 14, 4, 1, 128, true, -1><<<dim3(48, 56), 128, 0, stream>>>(x, 0, nullptr, 0, FT224F, (float2*)A0, 0, 0, 0);
    ck1<16, 14, 2, 64, -1><<<dim3(96, 14), 64, 0, stream>>>((float2*)A0, FT224F, (float2*)A1);
    ck2<16, 14, 2, 0, 64><<<dim3(96, 16), 64, 0, stream>>>((float2*)A1, FT224F, XH, nullptr);

    // ---- s0 -> GK slot img*81+0 ----
    rowpass_c<56, 4, 8, 64><<<dim3(48, 7), 64, 0, stream>>>(XH, 0, PHI0, 0, F56I, (float2*)A1);
    colpass_max<56, 8, 64><<<dim3(48, 7), 64, 0, stream>>>((float2*)A1, F56I, GK, 0, 0, 0);

    // ---- pair-batched first order j1=0 (+ second order); g = img*2 + lc, l1 = 2c+lc ----
    for (int c = 0; c < 4; ++c) {
        // A: ifft rows of xh*psi0[l1] -> A0 (96 groups)
        rk<16, 14, 4, 1, 128, false, 1><<<dim3(96, 56), 128, 0, stream>>>(
            XH, 1, PSI0 + (size_t)(2 * c) * IMG224, 1, FT224I, (float2*)A0, 0, 0, 0);
        // B: ifft cols + |.| -> A23 (real u1)
        ck1<16, 14, 2, 64, 1><<<dim3(192, 14), 64, 0, stream>>>((float2*)A0, FT224I, (float2*)A1);
        ck2<16, 14, 2, 1, 64><<<dim3(192, 16), 64, 0, stream>>>((float2*)A1, FT224I, nullptr, A23);
        // C: fft rows of u1 (real) -> A0
        rk<16, 14, 4, 1, 128, true, -1><<<dim3(96, 56), 128, 0, stream>>>(A23, 0, nullptr, 0, FT224F, (float2*)A0, 0, 0, 0);
        // D: fft cols -> V1 (A0)
        ck1<16, 14, 2, 64, -1><<<dim3(192, 14), 64, 0, stream>>>((float2*)A0, FT224F, (float2*)A1);
        ck2<16, 14, 2, 0, 64><<<dim3(192, 16), 64, 0, stream>>>((float2*)A1, FT224F, (float2*)A0, nullptr);
        // E: s1 -> GK slot img*81 + 1 + 2c + lc
        rowpass_c<56, 4, 8, 64><<<dim3(96, 7), 64, 0, stream>>>((float2*)A0, 0, PHI0, 0, F56I, (float2*)A1);
        colpass_max<56, 8, 64><<<dim3(96, 7), 64, 0, stream>>>((float2*)A1, F56I, GK, 1 + 2 * c, 1, 1);
        // second order per l1 in pair (V1 stays live in A0)
        for (int lc = 0; lc < 2; ++lc) {
            int l1 = 2 * c + lc;
            // F: ifft112 rows of fold(V1*psi1[l2],2) [XCD swizzle] -> A1
            rk<16, 7, 8, 2, 128, false, 1><<<dim3(384, 14), 128, 0, stream>>>(
                (float2*)A0, 0, PSI1, 7, FT112I, (float2*)A1, 48, 2, lc);
            // G: ifft112 cols + |.| : A1 -> A23 (stage1) -> A1 (real u2)
            ck1<16, 7, 1, 64, 1><<<dim3(384, 7), 64, 0, stream>>>((float2*)A1, FT112I, (float2*)A23);
            ck2<16, 7, 1, 1, 64><<<dim3(384, 16), 64, 0, stream>>>((float2*)A23, FT112I, nullptr, A1);
            // H: fft112 rows of u2 (real) -> A23
            rk<16, 7, 8, 1, 128, true, -1><<<dim3(384, 14), 128, 0, stream>>>(A1, 0, nullptr, 0, FT112F, (float2*)A23, 0, 0, 0);
            // I: fft112 cols: A23 -> A1 (stage1) -> A23 (u2h)
            ck1<16, 7, 1, 64, -1><<<dim3(384, 7), 64, 0, stream>>>((float2*)A23, FT112F, (float2*)A1);
            ck2<16, 7, 1, 0, 64><<<dim3(384, 16), 64, 0, stream>>>((float2*)A1, FT112F, (float2*)A23, nullptr);
            // JK: s2 -> GK slot img*81 + 17 + 8*l1 + l2
            rowpass_c<56, 2, 8, 64><<<dim3(384, 7), 64, 0, stream>>>((float2*)A23, 0, PHI1, 0, F56I, (float2*)A1);
            colpass_max<56, 8, 64><<<dim3(384, 7), 64, 0, stream>>>((float2*)A1, F56I, GK, 17 + 8 * l1, 3, 7);
        }
    }

    // ---- first order j1=1 (8 orientations, g = img*8+l) ----
    rk<16, 7, 8, 2, 128, false, 1><<<dim3(384, 14), 128, 0, stream>>>(XH, 0, PSI1, 7, FT112I, (float2*)A1, 48, 1, 0);
    ck1<16, 7, 1, 64, 1><<<dim3(384, 7), 64, 0, stream>>>((float2*)A1, FT112I, (float2*)A23);
    ck2<16, 7, 1, 1, 64><<<dim3(384, 16), 64, 0, stream>>>((float2*)A23, FT112I, nullptr, A1);
    rk<16, 7, 8, 1, 128, true, -1><<<dim3(384, 14), 128, 0, stream>>>(A1, 0, nullptr, 0, FT112F, (float2*)A23, 0, 0, 0);
    ck1<16, 7, 1, 64, -1><<<dim3(384, 7), 64, 0, stream>>>((float2*)A23, FT112F, (float2*)A1);
    ck2<16, 7, 1, 0, 64><<<dim3(384, 16), 64, 0, stream>>>((float2*)A1, FT112F, (float2*)A23, nullptr);
    rowpass_c<56, 2, 8, 64><<<dim3(384, 7), 64, 0, stream>>>((float2*)A23, 0, PHI1, 0, F56I, (float2*)A1);
    colpass_max<56, 8, 64><<<dim3(384, 7), 64, 0, stream>>>((float2*)A1, F56I, GK, 9, 3, 7);

    // head
    k_linear<<<(16000 + 255) / 256, 256, 0, stream>>>(GK, Wl, bl, out);
}

// Round 15
// 2258.723 us; speedup vs baseline: 1.8542x; 1.1511x over previous
//
#include <hip/hip_runtime.h>
#include <math.h>

#define PI_D 3.14159265358979323846

// ---------------- workspace layout (float units) ----------------
#define IMG224 50176
#define IMG112 12544
// factorized DFT tables per (N,dir): [W1:N1*N1 | W2:N2*N2 | TW:N2*N1 | (r2: W7:49 | T14:14)]
static const size_t OFF_FT224F = 0;        // 739 float2 used, 1024 reserved
static const size_t OFF_FT224I = 2048;
static const size_t OFF_FT112F = 4096;
static const size_t OFF_FT112I = 6144;
static const size_t OFF_FT56I  = 8192;     // [W1:64|W2:49|TW:56] = 169 float2
static const size_t OFF_F56I  = 250880;    // 6272 (dense 56 inverse, for colpass_max)
static const size_t OFF_PSI   = 257152;    // 16*50176
static const size_t OFF_PHI0  = 1059968;
static const size_t OFF_PHI1  = 1110144;
static const size_t OFF_GK    = 1122688;   // 3888 keys
static const size_t OFF_XH    = 1126784;   // 4816896
static const size_t OFF_POOL  = 5943680;
// arena: A0, A1, A23 = 9633792 floats each -> ~139 MB total (< known-good 149 MB)

// ---------------- helpers ----------------
__device__ inline unsigned fkey(float v) {
    int b = __float_as_int(v);
    return (b >= 0) ? ((unsigned)b | 0x80000000u) : ~(unsigned)b;
}
__device__ inline float funkey(unsigned u) {
    int b = (u & 0x80000000u) ? (int)(u & 0x7fffffffu) : (int)~u;
    return __int_as_float(b);
}
__device__ inline void cmac(float2& a, float2 z, float2 w) {
    a.x += z.x * w.x - z.y * w.y;
    a.y += z.x * w.y + z.y * w.x;
}
__device__ inline float2 cmulc(float2 v, float c, float s) {
    return make_float2(v.x * c - v.y * s, v.x * s + v.y * c);
}

// 16-point DFT, radix-4 x radix-4, constant twiddles (zero table loads). R13-proven.
template<int SGN>
__device__ inline void fft16(float2* x) {
    const float C8  = 0.70710678118654752f;
    const float C16 = 0.92387953251128674f;
    const float S16 = 0.38268343236508977f;
    const float sg = (float)SGN;
    float2 g[16];
#pragma unroll
    for (int b = 0; b < 4; ++b) {
        float2 x0 = x[b], x1 = x[4 + b], x2 = x[8 + b], x3 = x[12 + b];
        float2 e0 = make_float2(x0.x + x2.x, x0.y + x2.y);
        float2 e1 = make_float2(x0.x - x2.x, x0.y - x2.y);
        float2 o0 = make_float2(x1.x + x3.x, x1.y + x3.y);
        float2 o1 = make_float2(x1.x - x3.x, x1.y - x3.y);
        float2 io1 = (SGN > 0) ? make_float2(-o1.y, o1.x) : make_float2(o1.y, -o1.x);
        g[b * 4 + 0] = make_float2(e0.x + o0.x, e0.y + o0.y);
        g[b * 4 + 2] = make_float2(e0.x - o0.x, e0.y - o0.y);
        g[b * 4 + 1] = make_float2(e1.x + io1.x, e1.y + io1.y);
        g[b * 4 + 3] = make_float2(e1.x - io1.x, e1.y - io1.y);
    }
    g[5]  = cmulc(g[5],  C16,  sg * S16);
    g[6]  = cmulc(g[6],  C8,   sg * C8);
    g[7]  = cmulc(g[7],  S16,  sg * C16);
    g[9]  = cmulc(g[9],  C8,   sg * C8);
    g[10] = (SGN > 0) ? make_float2(-g[10].y, g[10].x)
                      : make_float2(g[10].y, -g[10].x);
    g[11] = cmulc(g[11], -C8,  sg * C8);
    g[13] = cmulc(g[13], S16,  sg * C16);
    g[14] = cmulc(g[14], -C8,  sg * C8);
    g[15] = cmulc(g[15], -C16, -sg * S16);
#pragma unroll
    for (int p = 0; p < 4; ++p) {
        float2 x0 = g[p], x1 = g[4 + p], x2 = g[8 + p], x3 = g[12 + p];
        float2 e0 = make_float2(x0.x + x2.x, x0.y + x2.y);
        float2 e1 = make_float2(x0.x - x2.x, x0.y - x2.y);
        float2 o0 = make_float2(x1.x + x3.x, x1.y + x3.y);
        float2 o1 = make_float2(x1.x - x3.x, x1.y - x3.y);
        float2 io1 = (SGN > 0) ? make_float2(-o1.y, o1.x) : make_float2(o1.y, -o1.x);
        x[p + 0]  = make_float2(e0.x + o0.x, e0.y + o0.y);
        x[p + 8]  = make_float2(e0.x - o0.x, e0.y - o0.y);
        x[p + 4]  = make_float2(e1.x + io1.x, e1.y + io1.y);
        x[p + 12] = make_float2(e1.x - io1.x, e1.y - io1.y);
    }
}

// 8-point DFT, DIT 2x fft4 + constant w8 twiddles. Same sign convention as fft16.
template<int SGN>
__device__ inline void fft8(float2* x) {
    const float C8 = 0.70710678118654752f;
    const float sg = (float)SGN;
    float2 E[4], O[4];
    {   // fft4 of evens (x0,x2,x4,x6)
        float2 e0 = make_float2(x[0].x + x[4].x, x[0].y + x[4].y);
        float2 e1 = make_float2(x[0].x - x[4].x, x[0].y - x[4].y);
        float2 o0 = make_float2(x[2].x + x[6].x, x[2].y + x[6].y);
        float2 o1 = make_float2(x[2].x - x[6].x, x[2].y - x[6].y);
        float2 io1 = (SGN > 0) ? make_float2(-o1.y, o1.x) : make_float2(o1.y, -o1.x);
        E[0] = make_float2(e0.x + o0.x, e0.y + o0.y);
        E[2] = make_float2(e0.x - o0.x, e0.y - o0.y);
        E[1] = make_float2(e1.x + io1.x, e1.y + io1.y);
        E[3] = make_float2(e1.x - io1.x, e1.y - io1.y);
    }
    {   // fft4 of odds (x1,x3,x5,x7)
        float2 e0 = make_float2(x[1].x + x[5].x, x[1].y + x[5].y);
        float2 e1 = make_float2(x[1].x - x[5].x, x[1].y - x[5].y);
        float2 o0 = make_float2(x[3].x + x[7].x, x[3].y + x[7].y);
        float2 o1 = make_float2(x[3].x - x[7].x, x[3].y - x[7].y);
        float2 io1 = (SGN > 0) ? make_float2(-o1.y, o1.x) : make_float2(o1.y, -o1.x);
        O[0] = make_float2(e0.x + o0.x, e0.y + o0.y);
        O[2] = make_float2(e0.x - o0.x, e0.y - o0.y);
        O[1] = make_float2(e1.x + io1.x, e1.y + io1.y);
        O[3] = make_float2(e1.x - io1.x, e1.y - io1.y);
    }
    // w8^k O[k]: k=0:1, k=1:(C8,sg*C8), k=2:sg*i, k=3:(-C8,sg*C8)
    float2 t0 = O[0];
    float2 t1 = cmulc(O[1], C8, sg * C8);
    float2 t2 = (SGN > 0) ? make_float2(-O[2].y, O[2].x) : make_float2(O[2].y, -O[2].x);
    float2 t3 = cmulc(O[3], -C8, sg * C8);
    x[0] = make_float2(E[0].x + t0.x, E[0].y + t0.y);
    x[4] = make_float2(E[0].x - t0.x, E[0].y - t0.y);
    x[1] = make_float2(E[1].x + t1.x, E[1].y + t1.y);
    x[5] = make_float2(E[1].x - t1.x, E[1].y - t1.y);
    x[2] = make_float2(E[2].x + t2.x, E[2].y + t2.y);
    x[6] = make_float2(E[2].x - t2.x, E[2].y - t2.y);
    x[3] = make_float2(E[3].x + t3.x, E[3].y + t3.y);
    x[7] = make_float2(E[3].x - t3.x, E[3].y - t3.y);
}

// ---------------- table builders ----------------
__global__ void k_dft(float2* out, int n, double sign, double scale) {
    int i = blockIdx.x * blockDim.x + threadIdx.x;
    if (i >= n * n) return;
    int c = i / n, k = i % n;
    int m = (c * k) % n;
    double ang = sign * 2.0 * PI_D * (double)m / (double)n;
    out[i] = make_float2((float)(scale * cos(ang)), (float)(scale * sin(ang)));
}

// r2: also emit [W7: scale*e^{s*2pi*i*nk/7} (49) | T14: e^{s*2pi*i*k/14} (14)]
__global__ void k_fact(float2* o, int N1, int N2, double sign, double scale, int r2) {
    int base3 = N1 * N1 + N2 * N2 + N2 * N1;
    int total = base3 + (r2 ? 63 : 0);
    int N = N1 * N2;
    for (int i = blockIdx.x * blockDim.x + threadIdx.x; i < total; i += blockDim.x * gridDim.x) {
        double ang; double sc = 1.0;
        if (i < N1 * N1) {
            int n1 = i / N1, k1 = i % N1;
            ang = sign * 2.0 * PI_D * (double)((n1 * k1) % N1) / (double)N1;
        } else if (i < N1 * N1 + N2 * N2) {
            int j = i - N1 * N1; int n2 = j / N2, k2 = j % N2;
            ang = sign * 2.0 * PI_D * (double)((n2 * k2) % N2) / (double)N2;
            sc = scale;
        } else if (i < base3) {
            int j = i - N1 * N1 - N2 * N2; int n2 = j / N1, k1 = j % N1;
            ang = sign * 2.0 * PI_D * (double)((n2 * k1) % N) / (double)N;
        } else if (i < base3 + 49) {
            int j = i - base3; int n = j / 7, k = j % 7;
            ang = sign * 2.0 * PI_D * (double)((n * k) % 7) / 7.0;
            sc = scale;
        } else {
            int k = i - base3 - 49;
            ang = sign * 2.0 * PI_D * (double)k / 14.0;
        }
        o[i] = make_float2((float)(sc * cos(ang)), (float)(sc * sin(ang)));
    }
}

__global__ void k_psi(float* out) {
    int i = blockIdx.x * blockDim.x + threadIdx.x;
    if (i >= 16 * IMG224) return;
    int jl = i / IMG224, p = i % IMG224;
    int r = p / 224, c = p % 224;
    int j = jl >> 3, l = jl & 7;
    double fr = (r < 112) ? (double)r : (double)(r - 224);
    double fc = (c < 112) ? (double)c : (double)(c - 224);
    double wx = 2.0 * PI_D * fr / 224.0;
    double wy = 2.0 * PI_D * fc / 224.0;
    double theta = (double)l * PI_D / 8.0;
    double xi = (3.0 * PI_D / 4.0) / (double)(1 << j);
    double sg = 0.8 * (double)(1 << j);
    double ct = cos(theta), st = sin(theta);
    double u = ct * wx + st * wy;
    double v = -st * wx + ct * wy;
    double vs = v / 0.5;
    double s2 = 0.5 * sg * sg;
    double gab = exp(-s2 * ((u - xi) * (u - xi) + vs * vs));
    double gau = exp(-s2 * (u * u + vs * vs));
    double kap = exp(-s2 * xi * xi);
    out[i] = (float)(gab - kap * gau);
}

__global__ void k_phi(float* phi0, float* phi1) {
    int i = blockIdx.x * blockDim.x + threadIdx.x;
    const double sp = 1.6;
    const double s2 = 0.5 * sp * sp;
    if (i < IMG224) {
        int r = i / 224, c = i % 224;
        double fr = (r < 112) ? (double)r : (double)(r - 224);
        double fc = (c < 112) ? (double)c : (double)(c - 224);
        double wx = 2.0 * PI_D * fr / 224.0;
        double wy = 2.0 * PI_D * fc / 224.0;
        phi0[i] = (float)exp(-s2 * (wx * wx + wy * wy));
    } else if (i < IMG224 + IMG112) {
        int p = i - IMG224, a = p / 112, b = p % 112;
        double sum = 0.0;
        for (int ii = 0; ii < 2; ++ii)
            for (int jj = 0; jj < 2; ++jj) {
                int r = a + 112 * ii, c = b + 112 * jj;
                double fr = (r < 112) ? (double)r : (double)(r - 224);
                double fc = (c < 112) ? (double)c : (double)(c - 224);
                double wx = 2.0 * PI_D * fr / 224.0;
                double wy = 2.0 * PI_D * fc / 224.0;
                sum += exp(-s2 * (wx * wx + wy * wy));
            }
        phi1[p] = (float)(0.25 * sum);
    }
}

__global__ void k_zero(unsigned* gk, int n) {
    int i = blockIdx.x * blockDim.x + threadIdx.x;
    if (i < n) gk[i] = 0u;
}

// ---------------- rk: row pass, two-stage (N=N1*N2), fused in LDS ----------------
// R8-proven two-buffer structure. Pass-1: constant-twiddle fftN1 (N1 in {8,16}),
// h-split (each h writes N1/2 TW'd outputs). Pass-2: N2=14 -> DIT 2x7 (R14);
// else dense N2-pt. R15: N1=8 path added so the 56-res row pass (s0/s1/s2) reuses
// this machinery (6x fewer ops than the dense rowpass it replaces).
// swzImg>0: XCD swizzle (R6: FETCH 76->16MB on F-step).
template<int N1, int N2, int TA, int FOLD, int BS, bool REAL, int SGN>
__global__ __launch_bounds__(BS) void rk(
    const void* __restrict__ inBase, int inShift,
    const float* __restrict__ fltBase, int fltMask,
    const float2* __restrict__ FT, float2* __restrict__ out,
    int swzImg, int inStride, int inOff)
{
    constexpr int N = N1 * N2;
    constexpr int NIN = N * FOLD;
    constexpr int ZS = N + 2;
    constexpr int TS = N2 * (N1 + 1);
    constexpr int K1H = N1 / 2;
    __shared__ float2 Z[TA * ZS];
    __shared__ float2 T[TA * TS];
    const float2* W2 = FT + N1 * N1;
    const float2* TW = FT + N1 * N1 + N2 * N2;
    const int bx = blockIdx.x, a0 = blockIdx.y * TA, t = threadIdx.x;
    int gIn, gFlt, gOut;
    if (swzImg > 0) {
        int img = bx % swzImg, sub = bx / swzImg;
        gIn = img * inStride + inOff; gFlt = sub; gOut = img * (gridDim.x / swzImg) + sub;
    } else {
        gIn = bx >> inShift; gFlt = bx & fltMask; gOut = bx;
    }

    if (REAL) {
        const float* in = (const float*)inBase + (size_t)gIn * N * N;
        for (int r = 0; r < TA; ++r)
            for (int b = t; b < N; b += BS)
                Z[r * ZS + b] = make_float2(in[(size_t)(a0 + r) * N + b], 0.f);
    } else {
        const float2* in = (const float2*)inBase + (size_t)gIn * (NIN * NIN);
        const float* flt = fltBase + (size_t)gFlt * (NIN * NIN);
        const float s = 1.0f / (float)(FOLD * FOLD);
        for (int r = 0; r < TA; ++r) {
            int a = a0 + r;
            for (int b = t; b < N; b += BS) {
                float re = 0.f, im = 0.f;
#pragma unroll
                for (int i = 0; i < FOLD; ++i)
#pragma unroll
                    for (int j = 0; j < FOLD; ++j) {
                        int idx = (a + N * i) * NIN + (b + N * j);
                        float2 v = in[idx];
                        float f = flt[idx];
                        re += v.x * f; im += v.y * f;
                    }
                Z[r * ZS + b] = make_float2(re * s, im * s);
            }
        }
    }
    __syncthreads();
    // pass 1: fftN1 per (r, n2); h in {0,1} redundant compute, disjoint TW'd writes.
    for (int idx = t; idx < TA * N2 * 2; idx += BS) {
        int r = idx / (N2 * 2);
        int rem = idx % (N2 * 2);
        int n2 = rem / 2, h = rem % 2;
        float2 xx[N1];
#pragma unroll
        for (int n1 = 0; n1 < N1; ++n1) xx[n1] = Z[r * ZS + n1 * N2 + n2];
        if constexpr (N1 == 16) fft16<SGN>(xx); else fft8<SGN>(xx);
#pragma unroll
        for (int kk = 0; kk < K1H; ++kk) {
            int k1 = h * K1H + kk;
            float2 tw = TW[n2 * N1 + k1];
            T[r * TS + n2 * (N1 + 1) + k1] = cmulc(xx[k1], tw.x, tw.y);
        }
    }
    __syncthreads();
    // pass 2
    if constexpr (N2 == 14) {
        const float2* W7  = FT + N1 * N1 + N2 * N2 + N2 * N1;
        const float2* T14 = W7 + 49;
        for (int idx = t; idx < TA * N1; idx += BS) {
            int r = idx / N1, k1 = idx % N1;
            float2 E[7], O[7];
#pragma unroll
            for (int k = 0; k < 7; ++k) { E[k] = make_float2(0.f, 0.f); O[k] = make_float2(0.f, 0.f); }
            for (int m = 0; m < 7; ++m) {
                float2 te = T[r * TS + (2 * m) * (N1 + 1) + k1];
                float2 to = T[r * TS + (2 * m + 1) * (N1 + 1) + k1];
#pragma unroll
                for (int k = 0; k < 7; ++k) {
                    float2 w = W7[m * 7 + k];
                    cmac(E[k], te, w);
                    cmac(O[k], to, w);
                }
            }
#pragma unroll
            for (int k = 0; k < 14; ++k) {
                float2 tw = T14[k];
                float2 o_ = O[k % 7];
                float2 X = E[k % 7];
                X.x += o_.x * tw.x - o_.y * tw.y;
                X.y += o_.x * tw.y + o_.y * tw.x;
                Z[r * ZS + k1 + N1 * k] = X;
            }
        }
    } else {
        for (int idx = t; idx < TA * N1; idx += BS) {
            int r = idx / N1, k1 = idx % N1;
            float2 acc[N2];
#pragma unroll
            for (int kk = 0; kk < N2; ++kk) acc[kk] = make_float2(0.f, 0.f);
            for (int n2 = 0; n2 < N2; ++n2) {
                float2 tv = T[r * TS + n2 * (N1 + 1) + k1];
#pragma unroll
                for (int kk = 0; kk < N2; ++kk) cmac(acc[kk], tv, W2[n2 * N2 + kk]);
            }
#pragma unroll
            for (int kk = 0; kk < N2; ++kk) Z[r * ZS + k1 + N1 * kk] = acc[kk];
        }
    }
    __syncthreads();
    for (int r = 0; r < TA; ++r) {
        float2* o = out + ((size_t)gOut * N + (a0 + r)) * N;
        for (int b = t; b < N; b += BS) o[b] = Z[r * ZS + b];
    }
}

// ---------------- ck1: col pass stage 1 — fft16 columns (R13-proven) ----------------
template<int N1, int N2, int SPLIT, int BS, int SGN>
__global__ __launch_bounds__(BS) void ck1(
    const float2* __restrict__ in, const float2* __restrict__ FT, float2* __restrict__ out)
{
    constexpr int N = N1 * N2;
    constexpr int NC = N / SPLIT;
    const float2* TW = FT + N1 * N1 + N2 * N2;
    const int g = blockIdx.x / SPLIT, half = blockIdx.x % SPLIT;
    const int n2 = blockIdx.y, t = threadIdx.x;
    if (2 * t >= NC) return;
    const int b0 = 2 * t + half * NC;
    const float2* I = in + (size_t)g * N * N;
    float2 a0[16], a1[16];
#pragma unroll
    for (int n1 = 0; n1 < 16; ++n1) {
        float4 v = *reinterpret_cast<const float4*>(&I[(size_t)(n1 * N2 + n2) * N + b0]);
        a0[n1] = make_float2(v.x, v.y);
        a1[n1] = make_float2(v.z, v.w);
    }
    fft16<SGN>(a0);
    fft16<SGN>(a1);
#pragma unroll
    for (int k1 = 0; k1 < 16; ++k1) {
        float2 tw = TW[n2 * N1 + k1];
        float2 r0 = cmulc(a0[k1], tw.x, tw.y);
        float2 r1 = cmulc(a1[k1], tw.x, tw.y);
        *reinterpret_cast<float4*>(&out[((size_t)g * N + (k1 * N2 + n2)) * N + b0]) =
            make_float4(r0.x, r0.y, r1.x, r1.y);
    }
}

// ---------------- ck2: col pass stage 2 + MODE (R14: N2=14 DIT; N2=7 dense) ----------------
template<int N1, int N2, int SPLIT, int MODE, int BS>
__global__ __launch_bounds__(BS) void ck2(
    const float2* __restrict__ in, const float2* __restrict__ FT,
    float2* __restrict__ outc, float* __restrict__ outr)
{
    constexpr int N = N1 * N2;
    constexpr int NC = N / SPLIT;
    const float2* W2 = FT + N1 * N1;
    const int g = blockIdx.x / SPLIT, half = blockIdx.x % SPLIT;
    const int k1 = blockIdx.y, t = threadIdx.x;
    if (2 * t >= NC) return;
    const int b0 = 2 * t + half * NC;
    const float2* I = in + (size_t)g * N * N;
    if constexpr (N2 == 14) {
        const float2* W7  = FT + N1 * N1 + N2 * N2 + N2 * N1;
        const float2* T14 = W7 + 49;
        float2 E0[7], E1[7], O0[7], O1[7];
#pragma unroll
        for (int k = 0; k < 7; ++k) {
            E0[k] = make_float2(0.f, 0.f); E1[k] = make_float2(0.f, 0.f);
            O0[k] = make_float2(0.f, 0.f); O1[k] = make_float2(0.f, 0.f);
        }
        for (int m = 0; m < 7; ++m) {
            float4 ve = *reinterpret_cast<const float4*>(&I[(size_t)(k1 * 14 + 2 * m) * N + b0]);
            float4 vo = *reinterpret_cast<const float4*>(&I[(size_t)(k1 * 14 + 2 * m + 1) * N + b0]);
            float2 ve0 = make_float2(ve.x, ve.y), ve1 = make_float2(ve.z, ve.w);
            float2 vo0 = make_float2(vo.x, vo.y), vo1 = make_float2(vo.z, vo.w);
#pragma unroll
            for (int k = 0; k < 7; ++k) {
                float2 w = W7[m * 7 + k];
                cmac(E0[k], ve0, w); cmac(E1[k], ve1, w);
                cmac(O0[k], vo0, w); cmac(O1[k], vo1, w);
            }
        }
#pragma unroll
        for (int k = 0; k < 14; ++k) {
            float2 tw = T14[k];
            float2 r0 = E0[k % 7], r1 = E1[k % 7];
            float2 o0 = O0[k % 7], o1 = O1[k % 7];
            r0.x += o0.x * tw.x - o0.y * tw.y;
            r0.y += o0.x * tw.y + o0.y * tw.x;
            r1.x += o1.x * tw.x - o1.y * tw.y;
            r1.y += o1.x * tw.y + o1.y * tw.x;
            if (MODE == 0) {
                *reinterpret_cast<float4*>(&outc[((size_t)g * N + (k1 + N1 * k)) * N + b0]) =
                    make_float4(r0.x, r0.y, r1.x, r1.y);
            } else {
                size_t o = ((size_t)g * N + (k1 + N1 * k)) * N + b0;
                outr[o]     = sqrtf(r0.x * r0.x + r0.y * r0.y);
                outr[o + 1] = sqrtf(r1.x * r1.x + r1.y * r1.y);
            }
        }
    } else {
        float2 acc[N2][2];
#pragma unroll
        for (int k2 = 0; k2 < N2; ++k2) { acc[k2][0] = make_float2(0.f, 0.f); acc[k2][1] = make_float2(0.f, 0.f); }
        for (int n2 = 0; n2 < N2; ++n2) {
            float4 v = *reinterpret_cast<const float4*>(&I[(size_t)(k1 * N2 + n2) * N + b0]);
            float2 v0 = make_float2(v.x, v.y), v1 = make_float2(v.z, v.w);
#pragma unroll
            for (int k2 = 0; k2 < N2; ++k2) {
                float2 w = W2[n2 * N2 + k2];
                cmac(acc[k2][0], v0, w);
                cmac(acc[k2][1], v1, w);
            }
        }
        if (MODE == 0) {
#pragma unroll
            for (int k2 = 0; k2 < N2; ++k2)
                *reinterpret_cast<float4*>(&outc[((size_t)g * N + (k1 + N1 * k2)) * N + b0]) =
                    make_float4(acc[k2][0].x, acc[k2][0].y, acc[k2][1].x, acc[k2][1].y);
        } else {
#pragma unroll
            for (int k2 = 0; k2 < N2; ++k2) {
                size_t o = ((size_t)g * N + (k1 + N1 * k2)) * N + b0;
                outr[o]     = sqrtf(acc[k2][0].x * acc[k2][0].x + acc[k2][0].y * acc[k2][0].y);
                outr[o + 1] = sqrtf(acc[k2][1].x * acc[k2][1].x + acc[k2][1].y * acc[k2][1].y);
            }
        }
    }
}

// ---------------- colpass_max: dense 56-col pass + real + max (R6-proven) ----------------
template<int N, int TK, int BS>
__global__ __launch_bounds__(BS) void colpass_max(
    const float2* __restrict__ in, const float2* __restrict__ W,
    unsigned* __restrict__ gk, int slotBase, int slotShift, int slotMask)
{
    __shared__ float2 Wl[N * TK];
    const int g = blockIdx.x;
    const int k0 = blockIdx.y * TK;
    const float2* I = in + (size_t)g * (N * N);
    const int t = threadIdx.x;
    for (int idx = t; idx < N * TK; idx += BS) {
        int a = idx / TK, kt = idx % TK;
        Wl[idx] = W[a * N + k0 + kt];
    }
    __syncthreads();
    const int b0 = 2 * t;
    float m = -INFINITY;
    if (b0 < N) {
        float2 acc[TK][2];
#pragma unroll
        for (int kt = 0; kt < TK; ++kt) {
            acc[kt][0] = make_float2(0.f, 0.f);
            acc[kt][1] = make_float2(0.f, 0.f);
        }
        for (int a = 0; a < N; ++a) {
            float4 v = *reinterpret_cast<const float4*>(&I[(size_t)a * N + b0]);
#pragma unroll
            for (int kt = 0; kt < TK; ++kt) {
                float2 w = Wl[a * TK + kt];
                acc[kt][0].x += w.x * v.x - w.y * v.y;
                acc[kt][1].x += w.x * v.z - w.y * v.w;
            }
        }
#pragma unroll
        for (int kt = 0; kt < TK; ++kt)
            m = fmaxf(m, fmaxf(acc[kt][0].x, acc[kt][1].x));
    }
    for (int off = 32; off > 0; off >>= 1)
        m = fmaxf(m, __shfl_down(m, off, 64));
    if (t == 0) {
        int slot = slotBase + ((g >> slotShift) * 81) + (g & slotMask);
        atomicMax(&gk[slot], fkey(m));
    }
}

// ---------------- classifier head ----------------
__global__ void k_linear(const unsigned* __restrict__ gk, const float* __restrict__ Wl,
                         const float* __restrict__ bl, float* __restrict__ out)
{
    int i = blockIdx.x * blockDim.x + threadIdx.x;
    if (i >= 16 * 1000) return;
    int b = i / 1000, o = i % 1000;
    float s = bl[o];
    for (int f = 0; f < 243; ++f)
        s += funkey(gk[b * 243 + f]) * Wl[o * 243 + f];
    out[i] = s;
}

// ---------------- launch ----------------
extern "C" void kernel_launch(void* const* d_in, const int* in_sizes, int n_in,
                              void* d_out, int out_size, void* d_ws, size_t ws_size,
                              hipStream_t stream)
{
    const float* x  = (const float*)d_in[0];
    const float* Wl = (const float*)d_in[1];
    const float* bl = (const float*)d_in[2];
    float* out = (float*)d_out;
    float* ws = (float*)d_ws;

    float2* FT224F = (float2*)(ws + OFF_FT224F);
    float2* FT224I = (float2*)(ws + OFF_FT224I);
    float2* FT112F = (float2*)(ws + OFF_FT112F);
    float2* FT112I = (float2*)(ws + OFF_FT112I);
    float2* FT56I  = (float2*)(ws + OFF_FT56I);
    float2* F56I  = (float2*)(ws + OFF_F56I);
    float* PSI0 = ws + OFF_PSI;
    float* PSI1 = ws + OFF_PSI + 8 * IMG224;
    float* PHI0 = ws + OFF_PHI0;
    float* PHI1 = ws + OFF_PHI1;
    unsigned* GK = (unsigned*)(ws + OFF_GK);
    float2* XH  = (float2*)(ws + OFF_XH);
    float* A0  = ws + OFF_POOL;          // 9633792 floats
    float* A1  = A0 + 9633792;           // 9633792
    float* A23 = A1 + 9633792;           // 9633792

    // tables (224 tables carry the r2 = 2x7 sections; new 56I factorized table)
    k_fact<<<4, 256, 0, stream>>>(FT224F, 16, 14, -1.0, 1.0, 1);
    k_fact<<<4, 256, 0, stream>>>(FT224I, 16, 14,  1.0, 1.0 / 224.0, 1);
    k_fact<<<4, 256, 0, stream>>>(FT112F, 16, 7,  -1.0, 1.0, 0);
    k_fact<<<4, 256, 0, stream>>>(FT112I, 16, 7,   1.0, 1.0 / 112.0, 0);
    k_fact<<<1, 256, 0, stream>>>(FT56I,  8, 7,    1.0, 1.0 / 56.0, 0);
    k_dft<<<(56*56 + 255) / 256, 256, 0, stream>>>(F56I, 56, 1.0, 1.0 / 56.0);
    k_psi<<<(16 * IMG224 + 255) / 256, 256, 0, stream>>>(ws + OFF_PSI);
    k_phi<<<(IMG224 + IMG112 + 255) / 256, 256, 0, stream>>>(PHI0, PHI1);
    k_zero<<<(3888 + 255) / 256, 256, 0, stream>>>(GK, 3888);

    // ---- fft2(x) -> XH ----
    rk<16, 14, 4, 1, 128, true, -1><<<dim3(48, 56), 128, 0, stream>>>(x, 0, nullptr, 0, FT224F, (float2*)A0, 0, 0, 0);
    ck1<16, 14, 2, 64, -1><<<dim3(96, 14), 64, 0, stream>>>((float2*)A0, FT224F, (float2*)A1);
    ck2<16, 14, 2, 0, 64><<<dim3(96, 16), 64, 0, stream>>>((float2*)A1, FT224F, XH, nullptr);

    // ---- s0 -> GK slot img*81+0 ----
    rk<8, 7, 8, 4, 64, false, 1><<<dim3(48, 7), 64, 0, stream>>>(XH, 0, PHI0, 0, FT56I, (float2*)A1, 0, 0, 0);
    colpass_max<56, 8, 64><<<dim3(48, 7), 64, 0, stream>>>((float2*)A1, F56I, GK, 0, 0, 0);

    // ---- pair-batched first order j1=0 (+ second order); g = img*2 + lc, l1 = 2c+lc ----
    for (int c = 0; c < 4; ++c) {
        // A: ifft rows of xh*psi0[l1] -> A0 (96 groups)
        rk<16, 14, 4, 1, 128, false, 1><<<dim3(96, 56), 128, 0, stream>>>(
            XH, 1, PSI0 + (size_t)(2 * c) * IMG224, 1, FT224I, (float2*)A0, 0, 0, 0);
        // B: ifft cols + |.| -> A23 (real u1)
        ck1<16, 14, 2, 64, 1><<<dim3(192, 14), 64, 0, stream>>>((float2*)A0, FT224I, (float2*)A1);
        ck2<16, 14, 2, 1, 64><<<dim3(192, 16), 64, 0, stream>>>((float2*)A1, FT224I, nullptr, A23);
        // C: fft rows of u1 (real) -> A0
        rk<16, 14, 4, 1, 128, true, -1><<<dim3(96, 56), 128, 0, stream>>>(A23, 0, nullptr, 0, FT224F, (float2*)A0, 0, 0, 0);
        // D: fft cols -> V1 (A0)
        ck1<16, 14, 2, 64, -1><<<dim3(192, 14), 64, 0, stream>>>((float2*)A0, FT224F, (float2*)A1);
        ck2<16, 14, 2, 0, 64><<<dim3(192, 16), 64, 0, stream>>>((float2*)A1, FT224F, (float2*)A0, nullptr);
        // E: s1 -> GK slot img*81 + 1 + 2c + lc
        rk<8, 7, 8, 4, 64, false, 1><<<dim3(96, 7), 64, 0, stream>>>((float2*)A0, 0, PHI0, 0, FT56I, (float2*)A1, 0, 0, 0);
        colpass_max<56, 8, 64><<<dim3(96, 7), 64, 0, stream>>>((float2*)A1, F56I, GK, 1 + 2 * c, 1, 1);
        // second order per l1 in pair (V1 stays live in A0)
        for (int lc = 0; lc < 2; ++lc) {
            int l1 = 2 * c + lc;
            // F: ifft112 rows of fold(V1*psi1[l2],2) [XCD swizzle] -> A1
            rk<16, 7, 8, 2, 128, false, 1><<<dim3(384, 14), 128, 0, stream>>>(
                (float2*)A0, 0, PSI1, 7, FT112I, (float2*)A1, 48, 2, lc);
            // G: ifft112 cols + |.| : A1 -> A23 (stage1) -> A1 (real u2)
            ck1<16, 7, 1, 64, 1><<<dim3(384, 7), 64, 0, stream>>>((float2*)A1, FT112I, (float2*)A23);
            ck2<16, 7, 1, 1, 64><<<dim3(384, 16), 64, 0, stream>>>((float2*)A23, FT112I, nullptr, A1);
            // H: fft112 rows of u2 (real) -> A23
            rk<16, 7, 8, 1, 128, true, -1><<<dim3(384, 14), 128, 0, stream>>>(A1, 0, nullptr, 0, FT112F, (float2*)A23, 0, 0, 0);
            // I: fft112 cols: A23 -> A1 (stage1) -> A23 (u2h)
            ck1<16, 7, 1, 64, -1><<<dim3(384, 7), 64, 0, stream>>>((float2*)A23, FT112F, (float2*)A1);
            ck2<16, 7, 1, 0, 64><<<dim3(384, 16), 64, 0, stream>>>((float2*)A1, FT112F, (float2*)A23, nullptr);
            // JK: s2 -> GK slot img*81 + 17 + 8*l1 + l2
            rk<8, 7, 8, 2, 64, false, 1><<<dim3(384, 7), 64, 0, stream>>>((float2*)A23, 0, PHI1, 0, FT56I, (float2*)A1, 0, 0, 0);
            colpass_max<56, 8, 64><<<dim3(384, 7), 64, 0, stream>>>((float2*)A1, F56I, GK, 17 + 8 * l1, 3, 7);
        }
    }

    // ---- first order j1=1 (8 orientations, g = img*8+l) ----
    rk<16, 7, 8, 2, 128, false, 1><<<dim3(384, 14), 128, 0, stream>>>(XH, 0, PSI1, 7, FT112I, (float2*)A1, 48, 1, 0);
    ck1<16, 7, 1, 64, 1><<<dim3(384, 7), 64, 0, stream>>>((float2*)A1, FT112I, (float2*)A23);
    ck2<16, 7, 1, 1, 64><<<dim3(384, 16), 64, 0, stream>>>((float2*)A23, FT112I, nullptr, A1);
    rk<16, 7, 8, 1, 128, true, -1><<<dim3(384, 14), 128, 0, stream>>>(A1, 0, nullptr, 0, FT112F, (float2*)A23, 0, 0, 0);
    ck1<16, 7, 1, 64, -1><<<dim3(384, 7), 64, 0, stream>>>((float2*)A23, FT112F, (float2*)A1);
    ck2<16, 7, 1, 0, 64><<<dim3(384, 16), 64, 0, stream>>>((float2*)A1, FT112F, (float2*)A23, nullptr);
    rk<8, 7, 8, 2, 64, false, 1><<<dim3(384, 7), 64, 0, stream>>>((float2*)A23, 0, PHI1, 0, FT56I, (float2*)A1, 0, 0, 0);
    colpass_max<56, 8, 64><<<dim3(384, 7), 64, 0, stream>>>((float2*)A1, F56I, GK, 9, 3, 7);

    // head
    k_linear<<<(16000 + 255) / 256, 256, 0, stream>>>(GK, Wl, bl, out);
}

// Round 16
// 2201.445 us; speedup vs baseline: 1.9024x; 1.0260x over previous
//
#include <hip/hip_runtime.h>
#include <math.h>

#define PI_D 3.14159265358979323846

// ---------------- workspace layout (float units) ----------------
#define IMG224 50176
#define IMG112 12544
// factorized DFT tables per (N,dir): [W1:N1*N1 | W2:N2*N2 | TW:N2*N1 | (r2: W7:49 | T14:14)]
static const size_t OFF_FT224F = 0;
static const size_t OFF_FT224I = 2048;
static const size_t OFF_FT112F = 4096;
static const size_t OFF_FT112I = 6144;
static const size_t OFF_FT56I  = 8192;     // [W1:64|W2:49|TW:56] = 169 float2
static const size_t OFF_F56I  = 250880;    // 6272 (dense 56 inverse, for colpass_max)
static const size_t OFF_PSI   = 257152;    // 16*50176
static const size_t OFF_PHI0  = 1059968;
static const size_t OFF_PHI1  = 1110144;
static const size_t OFF_GK    = 1122688;   // 3888 keys
static const size_t OFF_XH    = 1126784;   // 4816896
static const size_t OFF_POOL  = 5943680;
// unbatched pools: A0,A1,A23 = 9633792 each (~149MB total, known-fits)
// lc-batched pools: A0=9633792, A1b=A23b=19267584 (~216MB total; runtime-gated)

// ---------------- helpers ----------------
__device__ inline unsigned fkey(float v) {
    int b = __float_as_int(v);
    return (b >= 0) ? ((unsigned)b | 0x80000000u) : ~(unsigned)b;
}
__device__ inline float funkey(unsigned u) {
    int b = (u & 0x80000000u) ? (int)(u & 0x7fffffffu) : (int)~u;
    return __int_as_float(b);
}
__device__ inline void cmac(float2& a, float2 z, float2 w) {
    a.x += z.x * w.x - z.y * w.y;
    a.y += z.x * w.y + z.y * w.x;
}
__device__ inline float2 cmulc(float2 v, float c, float s) {
    return make_float2(v.x * c - v.y * s, v.x * s + v.y * c);
}

// 16-point DFT, radix-4 x radix-4, constant twiddles. R13-proven.
template<int SGN>
__device__ inline void fft16(float2* x) {
    const float C8  = 0.70710678118654752f;
    const float C16 = 0.92387953251128674f;
    const float S16 = 0.38268343236508977f;
    const float sg = (float)SGN;
    float2 g[16];
#pragma unroll
    for (int b = 0; b < 4; ++b) {
        float2 x0 = x[b], x1 = x[4 + b], x2 = x[8 + b], x3 = x[12 + b];
        float2 e0 = make_float2(x0.x + x2.x, x0.y + x2.y);
        float2 e1 = make_float2(x0.x - x2.x, x0.y - x2.y);
        float2 o0 = make_float2(x1.x + x3.x, x1.y + x3.y);
        float2 o1 = make_float2(x1.x - x3.x, x1.y - x3.y);
        float2 io1 = (SGN > 0) ? make_float2(-o1.y, o1.x) : make_float2(o1.y, -o1.x);
        g[b * 4 + 0] = make_float2(e0.x + o0.x, e0.y + o0.y);
        g[b * 4 + 2] = make_float2(e0.x - o0.x, e0.y - o0.y);
        g[b * 4 + 1] = make_float2(e1.x + io1.x, e1.y + io1.y);
        g[b * 4 + 3] = make_float2(e1.x - io1.x, e1.y - io1.y);
    }
    g[5]  = cmulc(g[5],  C16,  sg * S16);
    g[6]  = cmulc(g[6],  C8,   sg * C8);
    g[7]  = cmulc(g[7],  S16,  sg * C16);
    g[9]  = cmulc(g[9],  C8,   sg * C8);
    g[10] = (SGN > 0) ? make_float2(-g[10].y, g[10].x)
                      : make_float2(g[10].y, -g[10].x);
    g[11] = cmulc(g[11], -C8,  sg * C8);
    g[13] = cmulc(g[13], S16,  sg * C16);
    g[14] = cmulc(g[14], -C8,  sg * C8);
    g[15] = cmulc(g[15], -C16, -sg * S16);
#pragma unroll
    for (int p = 0; p < 4; ++p) {
        float2 x0 = g[p], x1 = g[4 + p], x2 = g[8 + p], x3 = g[12 + p];
        float2 e0 = make_float2(x0.x + x2.x, x0.y + x2.y);
        float2 e1 = make_float2(x0.x - x2.x, x0.y - x2.y);
        float2 o0 = make_float2(x1.x + x3.x, x1.y + x3.y);
        float2 o1 = make_float2(x1.x - x3.x, x1.y - x3.y);
        float2 io1 = (SGN > 0) ? make_float2(-o1.y, o1.x) : make_float2(o1.y, -o1.x);
        x[p + 0]  = make_float2(e0.x + o0.x, e0.y + o0.y);
        x[p + 8]  = make_float2(e0.x - o0.x, e0.y - o0.y);
        x[p + 4]  = make_float2(e1.x + io1.x, e1.y + io1.y);
        x[p + 12] = make_float2(e1.x - io1.x, e1.y - io1.y);
    }
}

// 8-point DFT, DIT 2x fft4 + constant w8 twiddles. R15-proven.
template<int SGN>
__device__ inline void fft8(float2* x) {
    const float C8 = 0.70710678118654752f;
    const float sg = (float)SGN;
    float2 E[4], O[4];
    {
        float2 e0 = make_float2(x[0].x + x[4].x, x[0].y + x[4].y);
        float2 e1 = make_float2(x[0].x - x[4].x, x[0].y - x[4].y);
        float2 o0 = make_float2(x[2].x + x[6].x, x[2].y + x[6].y);
        float2 o1 = make_float2(x[2].x - x[6].x, x[2].y - x[6].y);
        float2 io1 = (SGN > 0) ? make_float2(-o1.y, o1.x) : make_float2(o1.y, -o1.x);
        E[0] = make_float2(e0.x + o0.x, e0.y + o0.y);
        E[2] = make_float2(e0.x - o0.x, e0.y - o0.y);
        E[1] = make_float2(e1.x + io1.x, e1.y + io1.y);
        E[3] = make_float2(e1.x - io1.x, e1.y - io1.y);
    }
    {
        float2 e0 = make_float2(x[1].x + x[5].x, x[1].y + x[5].y);
        float2 e1 = make_float2(x[1].x - x[5].x, x[1].y - x[5].y);
        float2 o0 = make_float2(x[3].x + x[7].x, x[3].y + x[7].y);
        float2 o1 = make_float2(x[3].x - x[7].x, x[3].y - x[7].y);
        float2 io1 = (SGN > 0) ? make_float2(-o1.y, o1.x) : make_float2(o1.y, -o1.x);
        O[0] = make_float2(e0.x + o0.x, e0.y + o0.y);
        O[2] = make_float2(e0.x - o0.x, e0.y - o0.y);
        O[1] = make_float2(e1.x + io1.x, e1.y + io1.y);
        O[3] = make_float2(e1.x - io1.x, e1.y - io1.y);
    }
    float2 t0 = O[0];
    float2 t1 = cmulc(O[1], C8, sg * C8);
    float2 t2 = (SGN > 0) ? make_float2(-O[2].y, O[2].x) : make_float2(O[2].y, -O[2].x);
    float2 t3 = cmulc(O[3], -C8, sg * C8);
    x[0] = make_float2(E[0].x + t0.x, E[0].y + t0.y);
    x[4] = make_float2(E[0].x - t0.x, E[0].y - t0.y);
    x[1] = make_float2(E[1].x + t1.x, E[1].y + t1.y);
    x[5] = make_float2(E[1].x - t1.x, E[1].y - t1.y);
    x[2] = make_float2(E[2].x + t2.x, E[2].y + t2.y);
    x[6] = make_float2(E[2].x - t2.x, E[2].y - t2.y);
    x[3] = make_float2(E[3].x + t3.x, E[3].y + t3.y);
    x[7] = make_float2(E[3].x - t3.x, E[3].y - t3.y);
}

// ---------------- table builders ----------------
__global__ void k_dft(float2* out, int n, double sign, double scale) {
    int i = blockIdx.x * blockDim.x + threadIdx.x;
    if (i >= n * n) return;
    int c = i / n, k = i % n;
    int m = (c * k) % n;
    double ang = sign * 2.0 * PI_D * (double)m / (double)n;
    out[i] = make_float2((float)(scale * cos(ang)), (float)(scale * sin(ang)));
}

__global__ void k_fact(float2* o, int N1, int N2, double sign, double scale, int r2) {
    int base3 = N1 * N1 + N2 * N2 + N2 * N1;
    int total = base3 + (r2 ? 63 : 0);
    int N = N1 * N2;
    for (int i = blockIdx.x * blockDim.x + threadIdx.x; i < total; i += blockDim.x * gridDim.x) {
        double ang; double sc = 1.0;
        if (i < N1 * N1) {
            int n1 = i / N1, k1 = i % N1;
            ang = sign * 2.0 * PI_D * (double)((n1 * k1) % N1) / (double)N1;
        } else if (i < N1 * N1 + N2 * N2) {
            int j = i - N1 * N1; int n2 = j / N2, k2 = j % N2;
            ang = sign * 2.0 * PI_D * (double)((n2 * k2) % N2) / (double)N2;
            sc = scale;
        } else if (i < base3) {
            int j = i - N1 * N1 - N2 * N2; int n2 = j / N1, k1 = j % N1;
            ang = sign * 2.0 * PI_D * (double)((n2 * k1) % N) / (double)N;
        } else if (i < base3 + 49) {
            int j = i - base3; int n = j / 7, k = j % 7;
            ang = sign * 2.0 * PI_D * (double)((n * k) % 7) / 7.0;
            sc = scale;
        } else {
            int k = i - base3 - 49;
            ang = sign * 2.0 * PI_D * (double)k / 14.0;
        }
        o[i] = make_float2((float)(sc * cos(ang)), (float)(sc * sin(ang)));
    }
}

__global__ void k_psi(float* out) {
    int i = blockIdx.x * blockDim.x + threadIdx.x;
    if (i >= 16 * IMG224) return;
    int jl = i / IMG224, p = i % IMG224;
    int r = p / 224, c = p % 224;
    int j = jl >> 3, l = jl & 7;
    double fr = (r < 112) ? (double)r : (double)(r - 224);
    double fc = (c < 112) ? (double)c : (double)(c - 224);
    double wx = 2.0 * PI_D * fr / 224.0;
    double wy = 2.0 * PI_D * fc / 224.0;
    double theta = (double)l * PI_D / 8.0;
    double xi = (3.0 * PI_D / 4.0) / (double)(1 << j);
    double sg = 0.8 * (double)(1 << j);
    double ct = cos(theta), st = sin(theta);
    double u = ct * wx + st * wy;
    double v = -st * wx + ct * wy;
    double vs = v / 0.5;
    double s2 = 0.5 * sg * sg;
    double gab = exp(-s2 * ((u - xi) * (u - xi) + vs * vs));
    double gau = exp(-s2 * (u * u + vs * vs));
    double kap = exp(-s2 * xi * xi);
    out[i] = (float)(gab - kap * gau);
}

__global__ void k_phi(float* phi0, float* phi1) {
    int i = blockIdx.x * blockDim.x + threadIdx.x;
    const double sp = 1.6;
    const double s2 = 0.5 * sp * sp;
    if (i < IMG224) {
        int r = i / 224, c = i % 224;
        double fr = (r < 112) ? (double)r : (double)(r - 224);
        double fc = (c < 112) ? (double)c : (double)(c - 224);
        double wx = 2.0 * PI_D * fr / 224.0;
        double wy = 2.0 * PI_D * fc / 224.0;
        phi0[i] = (float)exp(-s2 * (wx * wx + wy * wy));
    } else if (i < IMG224 + IMG112) {
        int p = i - IMG224, a = p / 112, b = p % 112;
        double sum = 0.0;
        for (int ii = 0; ii < 2; ++ii)
            for (int jj = 0; jj < 2; ++jj) {
                int r = a + 112 * ii, c = b + 112 * jj;
                double fr = (r < 112) ? (double)r : (double)(r - 224);
                double fc = (c < 112) ? (double)c : (double)(c - 224);
                double wx = 2.0 * PI_D * fr / 224.0;
                double wy = 2.0 * PI_D * fc / 224.0;
                sum += exp(-s2 * (wx * wx + wy * wy));
            }
        phi1[p] = (float)(0.25 * sum);
    }
}

__global__ void k_zero(unsigned* gk, int n) {
    int i = blockIdx.x * blockDim.x + threadIdx.x;
    if (i < n) gk[i] = 0u;
}

// ---------------- rk: row pass, two-stage (N=N1*N2), fused in LDS ----------------
// R8 two-buffer structure; pass-1 fftN1 (const twiddles); pass-2 DIT 2x7 (N2=14) or
// dense. swz path (R16): sub = bx/swzImg may carry extra lc bits above the filter
// bits: gIn = img*inStride + inOff + (sub>>3); gFlt = sub & fltMask. Degenerates to
// R15 behavior when gridDim.x/swzImg <= 8.
template<int N1, int N2, int TA, int FOLD, int BS, bool REAL, int SGN>
__global__ __launch_bounds__(BS) void rk(
    const void* __restrict__ inBase, int inShift,
    const float* __restrict__ fltBase, int fltMask,
    const float2* __restrict__ FT, float2* __restrict__ out,
    int swzImg, int inStride, int inOff)
{
    constexpr int N = N1 * N2;
    constexpr int NIN = N * FOLD;
    constexpr int ZS = N + 2;
    constexpr int TS = N2 * (N1 + 1);
    constexpr int K1H = N1 / 2;
    __shared__ float2 Z[TA * ZS];
    __shared__ float2 T[TA * TS];
    const float2* W2 = FT + N1 * N1;
    const float2* TW = FT + N1 * N1 + N2 * N2;
    const int bx = blockIdx.x, a0 = blockIdx.y * TA, t = threadIdx.x;
    int gIn, gFlt, gOut;
    if (swzImg > 0) {
        int img = bx % swzImg, sub = bx / swzImg;
        gIn = img * inStride + inOff + (sub >> 3);
        gFlt = sub & fltMask;
        gOut = img * (gridDim.x / swzImg) + sub;
    } else {
        gIn = bx >> inShift; gFlt = bx & fltMask; gOut = bx;
    }

    if (REAL) {
        const float* in = (const float*)inBase + (size_t)gIn * N * N;
        for (int r = 0; r < TA; ++r)
            for (int b = t; b < N; b += BS)
                Z[r * ZS + b] = make_float2(in[(size_t)(a0 + r) * N + b], 0.f);
    } else {
        const float2* in = (const float2*)inBase + (size_t)gIn * (NIN * NIN);
        const float* flt = fltBase + (size_t)gFlt * (NIN * NIN);
        const float s = 1.0f / (float)(FOLD * FOLD);
        for (int r = 0; r < TA; ++r) {
            int a = a0 + r;
            for (int b = t; b < N; b += BS) {
                float re = 0.f, im = 0.f;
#pragma unroll
                for (int i = 0; i < FOLD; ++i)
#pragma unroll
                    for (int j = 0; j < FOLD; ++j) {
                        int idx = (a + N * i) * NIN + (b + N * j);
                        float2 v = in[idx];
                        float f = flt[idx];
                        re += v.x * f; im += v.y * f;
                    }
                Z[r * ZS + b] = make_float2(re * s, im * s);
            }
        }
    }
    __syncthreads();
    // pass 1: fftN1 per (r, n2); h in {0,1} redundant compute, disjoint TW'd writes.
    for (int idx = t; idx < TA * N2 * 2; idx += BS) {
        int r = idx / (N2 * 2);
        int rem = idx % (N2 * 2);
        int n2 = rem / 2, h = rem % 2;
        float2 xx[N1];
#pragma unroll
        for (int n1 = 0; n1 < N1; ++n1) xx[n1] = Z[r * ZS + n1 * N2 + n2];
        if constexpr (N1 == 16) fft16<SGN>(xx); else fft8<SGN>(xx);
#pragma unroll
        for (int kk = 0; kk < K1H; ++kk) {
            int k1 = h * K1H + kk;
            float2 tw = TW[n2 * N1 + k1];
            T[r * TS + n2 * (N1 + 1) + k1] = cmulc(xx[k1], tw.x, tw.y);
        }
    }
    __syncthreads();
    // pass 2
    if constexpr (N2 == 14) {
        const float2* W7  = FT + N1 * N1 + N2 * N2 + N2 * N1;
        const float2* T14 = W7 + 49;
        for (int idx = t; idx < TA * N1; idx += BS) {
            int r = idx / N1, k1 = idx % N1;
            float2 E[7], O[7];
#pragma unroll
            for (int k = 0; k < 7; ++k) { E[k] = make_float2(0.f, 0.f); O[k] = make_float2(0.f, 0.f); }
            for (int m = 0; m < 7; ++m) {
                float2 te = T[r * TS + (2 * m) * (N1 + 1) + k1];
                float2 to = T[r * TS + (2 * m + 1) * (N1 + 1) + k1];
#pragma unroll
                for (int k = 0; k < 7; ++k) {
                    float2 w = W7[m * 7 + k];
                    cmac(E[k], te, w);
                    cmac(O[k], to, w);
                }
            }
#pragma unroll
            for (int k = 0; k < 14; ++k) {
                float2 tw = T14[k];
                float2 o_ = O[k % 7];
                float2 X = E[k % 7];
                X.x += o_.x * tw.x - o_.y * tw.y;
                X.y += o_.x * tw.y + o_.y * tw.x;
                Z[r * ZS + k1 + N1 * k] = X;
            }
        }
    } else {
        for (int idx = t; idx < TA * N1; idx += BS) {
            int r = idx / N1, k1 = idx % N1;
            float2 acc[N2];
#pragma unroll
            for (int kk = 0; kk < N2; ++kk) acc[kk] = make_float2(0.f, 0.f);
            for (int n2 = 0; n2 < N2; ++n2) {
                float2 tv = T[r * TS + n2 * (N1 + 1) + k1];
#pragma unroll
                for (int kk = 0; kk < N2; ++kk) cmac(acc[kk], tv, W2[n2 * N2 + kk]);
            }
#pragma unroll
            for (int kk = 0; kk < N2; ++kk) Z[r * ZS + k1 + N1 * kk] = acc[kk];
        }
    }
    __syncthreads();
    for (int r = 0; r < TA; ++r) {
        float2* o = out + ((size_t)gOut * N + (a0 + r)) * N;
        for (int b = t; b < N; b += BS) o[b] = Z[r * ZS + b];
    }
}

// ---------------- ck1: col pass stage 1 — fft16 columns (R13-proven) ----------------
template<int N1, int N2, int SPLIT, int BS, int SGN>
__global__ __launch_bounds__(BS) void ck1(
    const float2* __restrict__ in, const float2* __restrict__ FT, float2* __restrict__ out)
{
    constexpr int N = N1 * N2;
    constexpr int NC = N / SPLIT;
    const float2* TW = FT + N1 * N1 + N2 * N2;
    const int g = blockIdx.x / SPLIT, half = blockIdx.x % SPLIT;
    const int n2 = blockIdx.y, t = threadIdx.x;
    if (2 * t >= NC) return;
    const int b0 = 2 * t + half * NC;
    const float2* I = in + (size_t)g * N * N;
    float2 a0[16], a1[16];
#pragma unroll
    for (int n1 = 0; n1 < 16; ++n1) {
        float4 v = *reinterpret_cast<const float4*>(&I[(size_t)(n1 * N2 + n2) * N + b0]);
        a0[n1] = make_float2(v.x, v.y);
        a1[n1] = make_float2(v.z, v.w);
    }
    fft16<SGN>(a0);
    fft16<SGN>(a1);
#pragma unroll
    for (int k1 = 0; k1 < 16; ++k1) {
        float2 tw = TW[n2 * N1 + k1];
        float2 r0 = cmulc(a0[k1], tw.x, tw.y);
        float2 r1 = cmulc(a1[k1], tw.x, tw.y);
        *reinterpret_cast<float4*>(&out[((size_t)g * N + (k1 * N2 + n2)) * N + b0]) =
            make_float4(r0.x, r0.y, r1.x, r1.y);
    }
}

// ---------------- ck2: col pass stage 2 + MODE (R14: N2=14 DIT; N2=7 dense) ----------------
template<int N1, int N2, int SPLIT, int MODE, int BS>
__global__ __launch_bounds__(BS) void ck2(
    const float2* __restrict__ in, const float2* __restrict__ FT,
    float2* __restrict__ outc, float* __restrict__ outr)
{
    constexpr int N = N1 * N2;
    constexpr int NC = N / SPLIT;
    const float2* W2 = FT + N1 * N1;
    const int g = blockIdx.x / SPLIT, half = blockIdx.x % SPLIT;
    const int k1 = blockIdx.y, t = threadIdx.x;
    if (2 * t >= NC) return;
    const int b0 = 2 * t + half * NC;
    const float2* I = in + (size_t)g * N * N;
    if constexpr (N2 == 14) {
        const float2* W7  = FT + N1 * N1 + N2 * N2 + N2 * N1;
        const float2* T14 = W7 + 49;
        float2 E0[7], E1[7], O0[7], O1[7];
#pragma unroll
        for (int k = 0; k < 7; ++k) {
            E0[k] = make_float2(0.f, 0.f); E1[k] = make_float2(0.f, 0.f);
            O0[k] = make_float2(0.f, 0.f); O1[k] = make_float2(0.f, 0.f);
        }
        for (int m = 0; m < 7; ++m) {
            float4 ve = *reinterpret_cast<const float4*>(&I[(size_t)(k1 * 14 + 2 * m) * N + b0]);
            float4 vo = *reinterpret_cast<const float4*>(&I[(size_t)(k1 * 14 + 2 * m + 1) * N + b0]);
            float2 ve0 = make_float2(ve.x, ve.y), ve1 = make_float2(ve.z, ve.w);
            float2 vo0 = make_float2(vo.x, vo.y), vo1 = make_float2(vo.z, vo.w);
#pragma unroll
            for (int k = 0; k < 7; ++k) {
                float2 w = W7[m * 7 + k];
                cmac(E0[k], ve0, w); cmac(E1[k], ve1, w);
                cmac(O0[k], vo0, w); cmac(O1[k], vo1, w);
            }
        }
#pragma unroll
        for (int k = 0; k < 14; ++k) {
            float2 tw = T14[k];
            float2 r0 = E0[k % 7], r1 = E1[k % 7];
            float2 o0 = O0[k % 7], o1 = O1[k % 7];
            r0.x += o0.x * tw.x - o0.y * tw.y;
            r0.y += o0.x * tw.y + o0.y * tw.x;
            r1.x += o1.x * tw.x - o1.y * tw.y;
            r1.y += o1.x * tw.y + o1.y * tw.x;
            if (MODE == 0) {
                *reinterpret_cast<float4*>(&outc[((size_t)g * N + (k1 + N1 * k)) * N + b0]) =
                    make_float4(r0.x, r0.y, r1.x, r1.y);
            } else {
                size_t o = ((size_t)g * N + (k1 + N1 * k)) * N + b0;
                outr[o]     = sqrtf(r0.x * r0.x + r0.y * r0.y);
                outr[o + 1] = sqrtf(r1.x * r1.x + r1.y * r1.y);
            }
        }
    } else {
        float2 acc[N2][2];
#pragma unroll
        for (int k2 = 0; k2 < N2; ++k2) { acc[k2][0] = make_float2(0.f, 0.f); acc[k2][1] = make_float2(0.f, 0.f); }
        for (int n2 = 0; n2 < N2; ++n2) {
            float4 v = *reinterpret_cast<const float4*>(&I[(size_t)(k1 * N2 + n2) * N + b0]);
            float2 v0 = make_float2(v.x, v.y), v1 = make_float2(v.z, v.w);
#pragma unroll
            for (int k2 = 0; k2 < N2; ++k2) {
                float2 w = W2[n2 * N2 + k2];
                cmac(acc[k2][0], v0, w);
                cmac(acc[k2][1], v1, w);
            }
        }
        if (MODE == 0) {
#pragma unroll
            for (int k2 = 0; k2 < N2; ++k2)
                *reinterpret_cast<float4*>(&outc[((size_t)g * N + (k1 + N1 * k2)) * N + b0]) =
                    make_float4(acc[k2][0].x, acc[k2][0].y, acc[k2][1].x, acc[k2][1].y);
        } else {
#pragma unroll
            for (int k2 = 0; k2 < N2; ++k2) {
                size_t o = ((size_t)g * N + (k1 + N1 * k2)) * N + b0;
                outr[o]     = sqrtf(acc[k2][0].x * acc[k2][0].x + acc[k2][0].y * acc[k2][0].y);
                outr[o + 1] = sqrtf(acc[k2][1].x * acc[k2][1].x + acc[k2][1].y * acc[k2][1].y);
            }
        }
    }
}

// ---------------- colpass_max: dense 56-col pass + real + max (R6-proven) ----------------
template<int N, int TK, int BS>
__global__ __launch_bounds__(BS) void colpass_max(
    const float2* __restrict__ in, const float2* __restrict__ W,
    unsigned* __restrict__ gk, int slotBase, int slotShift, int slotMask)
{
    __shared__ float2 Wl[N * TK];
    const int g = blockIdx.x;
    const int k0 = blockIdx.y * TK;
    const float2* I = in + (size_t)g * (N * N);
    const int t = threadIdx.x;
    for (int idx = t; idx < N * TK; idx += BS) {
        int a = idx / TK, kt = idx % TK;
        Wl[idx] = W[a * N + k0 + kt];
    }
    __syncthreads();
    const int b0 = 2 * t;
    float m = -INFINITY;
    if (b0 < N) {
        float2 acc[TK][2];
#pragma unroll
        for (int kt = 0; kt < TK; ++kt) {
            acc[kt][0] = make_float2(0.f, 0.f);
            acc[kt][1] = make_float2(0.f, 0.f);
        }
        for (int a = 0; a < N; ++a) {
            float4 v = *reinterpret_cast<const float4*>(&I[(size_t)a * N + b0]);
#pragma unroll
            for (int kt = 0; kt < TK; ++kt) {
                float2 w = Wl[a * TK + kt];
                acc[kt][0].x += w.x * v.x - w.y * v.y;
                acc[kt][1].x += w.x * v.z - w.y * v.w;
            }
        }
#pragma unroll
        for (int kt = 0; kt < TK; ++kt)
            m = fmaxf(m, fmaxf(acc[kt][0].x, acc[kt][1].x));
    }
    for (int off = 32; off > 0; off >>= 1)
        m = fmaxf(m, __shfl_down(m, off, 64));
    if (t == 0) {
        int slot = slotBase + ((g >> slotShift) * 81) + (g & slotMask);
        atomicMax(&gk[slot], fkey(m));
    }
}

// ---------------- classifier head ----------------
__global__ void k_linear(const unsigned* __restrict__ gk, const float* __restrict__ Wl,
                         const float* __restrict__ bl, float* __restrict__ out)
{
    int i = blockIdx.x * blockDim.x + threadIdx.x;
    if (i >= 16 * 1000) return;
    int b = i / 1000, o = i % 1000;
    float s = bl[o];
    for (int f = 0; f < 243; ++f)
        s += funkey(gk[b * 243 + f]) * Wl[o * 243 + f];
    out[i] = s;
}

// ---------------- launch ----------------
extern "C" void kernel_launch(void* const* d_in, const int* in_sizes, int n_in,
                              void* d_out, int out_size, void* d_ws, size_t ws_size,
                              hipStream_t stream)
{
    const float* x  = (const float*)d_in[0];
    const float* Wl = (const float*)d_in[1];
    const float* bl = (const float*)d_in[2];
    float* out = (float*)d_out;
    float* ws = (float*)d_ws;

    float2* FT224F = (float2*)(ws + OFF_FT224F);
    float2* FT224I = (float2*)(ws + OFF_FT224I);
    float2* FT112F = (float2*)(ws + OFF_FT112F);
    float2* FT112I = (float2*)(ws + OFF_FT112I);
    float2* FT56I  = (float2*)(ws + OFF_FT56I);
    float2* F56I  = (float2*)(ws + OFF_F56I);
    float* PSI0 = ws + OFF_PSI;
    float* PSI1 = ws + OFF_PSI + 8 * IMG224;
    float* PHI0 = ws + OFF_PHI0;
    float* PHI1 = ws + OFF_PHI1;
    unsigned* GK = (unsigned*)(ws + OFF_GK);
    float2* XH  = (float2*)(ws + OFF_XH);
    float* A0  = ws + OFF_POOL;                       // 9633792 floats (V1 pair)

    // lc-batched second-order chain needs A1/A23 at 768-group size (216.5MB total).
    const size_t NEED_BATCH = OFF_POOL + 9633792 + 2 * (size_t)19267584;
    const bool batch = (ws_size / 4) >= NEED_BATCH;
    float* A1  = A0 + 9633792;
    float* A23 = A1 + (batch ? 19267584 : 9633792);

    // tables
    k_fact<<<4, 256, 0, stream>>>(FT224F, 16, 14, -1.0, 1.0, 1);
    k_fact<<<4, 256, 0, stream>>>(FT224I, 16, 14,  1.0, 1.0 / 224.0, 1);
    k_fact<<<4, 256, 0, stream>>>(FT112F, 16, 7,  -1.0, 1.0, 0);
    k_fact<<<4, 256, 0, stream>>>(FT112I, 16, 7,   1.0, 1.0 / 112.0, 0);
    k_fact<<<1, 256, 0, stream>>>(FT56I,  8, 7,    1.0, 1.0 / 56.0, 0);
    k_dft<<<(56*56 + 255) / 256, 256, 0, stream>>>(F56I, 56, 1.0, 1.0 / 56.0);
    k_psi<<<(16 * IMG224 + 255) / 256, 256, 0, stream>>>(ws + OFF_PSI);
    k_phi<<<(IMG224 + IMG112 + 255) / 256, 256, 0, stream>>>(PHI0, PHI1);
    k_zero<<<(3888 + 255) / 256, 256, 0, stream>>>(GK, 3888);

    // ---- fft2(x) -> XH ----
    rk<16, 14, 4, 1, 128, true, -1><<<dim3(48, 56), 128, 0, stream>>>(x, 0, nullptr, 0, FT224F, (float2*)A0, 0, 0, 0);
    ck1<16, 14, 2, 64, -1><<<dim3(96, 14), 64, 0, stream>>>((float2*)A0, FT224F, (float2*)A1);
    ck2<16, 14, 2, 0, 64><<<dim3(96, 16), 64, 0, stream>>>((float2*)A1, FT224F, XH, nullptr);

    // ---- s0 -> GK slot img*81+0 ----
    rk<8, 7, 8, 4, 64, false, 1><<<dim3(48, 7), 64, 0, stream>>>(XH, 0, PHI0, 0, FT56I, (float2*)A1, 0, 0, 0);
    colpass_max<56, 8, 64><<<dim3(48, 7), 64, 0, stream>>>((float2*)A1, F56I, GK, 0, 0, 0);

    // ---- pair-batched first order j1=0 (+ second order); g = img*2 + lc, l1 = 2c+lc ----
    for (int c = 0; c < 4; ++c) {
        // A: ifft rows of xh*psi0[l1] -> A0 (96 groups)
        rk<16, 14, 4, 1, 128, false, 1><<<dim3(96, 56), 128, 0, stream>>>(
            XH, 1, PSI0 + (size_t)(2 * c) * IMG224, 1, FT224I, (float2*)A0, 0, 0, 0);
        // B: ifft cols + |.| -> A23 (real u1)
        ck1<16, 14, 2, 64, 1><<<dim3(192, 14), 64, 0, stream>>>((float2*)A0, FT224I, (float2*)A1);
        ck2<16, 14, 2, 1, 64><<<dim3(192, 16), 64, 0, stream>>>((float2*)A1, FT224I, nullptr, A23);
        // C: fft rows of u1 (real) -> A0
        rk<16, 14, 4, 1, 128, true, -1><<<dim3(96, 56), 128, 0, stream>>>(A23, 0, nullptr, 0, FT224F, (float2*)A0, 0, 0, 0);
        // D: fft cols -> V1 (A0)
        ck1<16, 14, 2, 64, -1><<<dim3(192, 14), 64, 0, stream>>>((float2*)A0, FT224F, (float2*)A1);
        ck2<16, 14, 2, 0, 64><<<dim3(192, 16), 64, 0, stream>>>((float2*)A1, FT224F, (float2*)A0, nullptr);
        // E: s1 -> GK slot img*81 + 1 + 2c + lc
        rk<8, 7, 8, 4, 64, false, 1><<<dim3(96, 7), 64, 0, stream>>>((float2*)A0, 0, PHI0, 0, FT56I, (float2*)A1, 0, 0, 0);
        colpass_max<56, 8, 64><<<dim3(96, 7), 64, 0, stream>>>((float2*)A1, F56I, GK, 1 + 2 * c, 1, 1);
        if (batch) {
            // second order, both lc at once: 768 groups, g = img*16 + lc*8 + l2
            rk<16, 7, 8, 2, 128, false, 1><<<dim3(768, 14), 128, 0, stream>>>(
                (float2*)A0, 0, PSI1, 7, FT112I, (float2*)A1, 48, 2, 0);
            ck1<16, 7, 1, 64, 1><<<dim3(768, 7), 64, 0, stream>>>((float2*)A1, FT112I, (float2*)A23);
            ck2<16, 7, 1, 1, 64><<<dim3(768, 16), 64, 0, stream>>>((float2*)A23, FT112I, nullptr, A1);
            rk<16, 7, 8, 1, 128, true, -1><<<dim3(768, 14), 128, 0, stream>>>(A1, 0, nullptr, 0, FT112F, (float2*)A23, 0, 0, 0);
            ck1<16, 7, 1, 64, -1><<<dim3(768, 7), 64, 0, stream>>>((float2*)A23, FT112F, (float2*)A1);
            ck2<16, 7, 1, 0, 64><<<dim3(768, 16), 64, 0, stream>>>((float2*)A1, FT112F, (float2*)A23, nullptr);
            rk<8, 7, 8, 2, 64, false, 1><<<dim3(768, 7), 64, 0, stream>>>((float2*)A23, 0, PHI1, 0, FT56I, (float2*)A1, 0, 0, 0);
            colpass_max<56, 8, 64><<<dim3(768, 7), 64, 0, stream>>>((float2*)A1, F56I, GK, 17 + 16 * c, 4, 15);
        } else {
            for (int lc = 0; lc < 2; ++lc) {
                int l1 = 2 * c + lc;
                rk<16, 7, 8, 2, 128, false, 1><<<dim3(384, 14), 128, 0, stream>>>(
                    (float2*)A0, 0, PSI1, 7, FT112I, (float2*)A1, 48, 2, lc);
                ck1<16, 7, 1, 64, 1><<<dim3(384, 7), 64, 0, stream>>>((float2*)A1, FT112I, (float2*)A23);
                ck2<16, 7, 1, 1, 64><<<dim3(384, 16), 64, 0, stream>>>((float2*)A23, FT112I, nullptr, A1);
                rk<16, 7, 8, 1, 128, true, -1><<<dim3(384, 14), 128, 0, stream>>>(A1, 0, nullptr, 0, FT112F, (float2*)A23, 0, 0, 0);
                ck1<16, 7, 1, 64, -1><<<dim3(384, 7), 64, 0, stream>>>((float2*)A23, FT112F, (float2*)A1);
                ck2<16, 7, 1, 0, 64><<<dim3(384, 16), 64, 0, stream>>>((float2*)A1, FT112F, (float2*)A23, nullptr);
                rk<8, 7, 8, 2, 64, false, 1><<<dim3(384, 7), 64, 0, stream>>>((float2*)A23, 0, PHI1, 0, FT56I, (float2*)A1, 0, 0, 0);
                colpass_max<56, 8, 64><<<dim3(384, 7), 64, 0, stream>>>((float2*)A1, F56I, GK, 17 + 8 * l1, 3, 7);
            }
        }
    }

    // ---- first order j1=1 (8 orientations, g = img*8+l) ----
    rk<16, 7, 8, 2, 128, false, 1><<<dim3(384, 14), 128, 0, stream>>>(XH, 0, PSI1, 7, FT112I, (float2*)A1, 48, 1, 0);
    ck1<16, 7, 1, 64, 1><<<dim3(384, 7), 64, 0, stream>>>((float2*)A1, FT112I, (float2*)A23);
    ck2<16, 7, 1, 1, 64><<<dim3(384, 16), 64, 0, stream>>>((float2*)A23, FT112I, nullptr, A1);
    rk<16, 7, 8, 1, 128, true, -1><<<dim3(384, 14), 128, 0, stream>>>(A1, 0, nullptr, 0, FT112F, (float2*)A23, 0, 0, 0);
    ck1<16, 7, 1, 64, -1><<<dim3(384, 7), 64, 0, stream>>>((float2*)A23, FT112F, (float2*)A1);
    ck2<16, 7, 1, 0, 64><<<dim3(384, 16), 64, 0, stream>>>((float2*)A1, FT112F, (float2*)A23, nullptr);
    rk<8, 7, 8, 2, 64, false, 1><<<dim3(384, 7), 64, 0, stream>>>((float2*)A23, 0, PHI1, 0, FT56I, (float2*)A1, 0, 0, 0);
    colpass_max<56, 8, 64><<<dim3(384, 7), 64, 0, stream>>>((float2*)A1, F56I, GK, 9, 3, 7);

    // head
    k_linear<<<(16000 + 255) / 256, 256, 0, stream>>>(GK, Wl, bl, out);
}

// Round 17
// 2020.542 us; speedup vs baseline: 2.0728x; 1.0895x over previous
//
#include <hip/hip_runtime.h>
#include <math.h>

#define PI_D 3.14159265358979323846

// ---------------- workspace layout (float units) ----------------
#define IMG224 50176
#define IMG112 12544
// factorized DFT tables per (N,dir): [W1:N1*N1 | W2:N2*N2 | TW:N2*N1 | (r2: W7:49 | T14:14)]
static const size_t OFF_FT224F = 0;
static const size_t OFF_FT224I = 2048;
static const size_t OFF_FT112F = 4096;
static const size_t OFF_FT112I = 6144;
static const size_t OFF_FT56I  = 8192;     // [W1:64|W2:49|TW:56] = 169 float2
static const size_t OFF_PSI   = 257152;    // 16*50176
static const size_t OFF_PHI0  = 1059968;
static const size_t OFF_PHI1  = 1110144;
static const size_t OFF_GK    = 1122688;   // 3888 keys
static const size_t OFF_XH    = 1126784;   // 4816896
static const size_t OFF_POOL  = 5943680;
// unbatched pools: A0,A1,A23 = 9633792 each (~149MB, known-fits)
// lc-batched pools: A0=9633792, A1b=A23b=19267584 (~216MB; R16-measured to fit)

// ---------------- helpers ----------------
__device__ inline unsigned fkey(float v) {
    int b = __float_as_int(v);
    return (b >= 0) ? ((unsigned)b | 0x80000000u) : ~(unsigned)b;
}
__device__ inline float funkey(unsigned u) {
    int b = (u & 0x80000000u) ? (int)(u & 0x7fffffffu) : (int)~u;
    return __int_as_float(b);
}
__device__ inline void cmac(float2& a, float2 z, float2 w) {
    a.x += z.x * w.x - z.y * w.y;
    a.y += z.x * w.y + z.y * w.x;
}
__device__ inline float2 cmulc(float2 v, float c, float s) {
    return make_float2(v.x * c - v.y * s, v.x * s + v.y * c);
}

// 16-point DFT, radix-4 x radix-4, constant twiddles. R13-proven.
template<int SGN>
__device__ inline void fft16(float2* x) {
    const float C8  = 0.70710678118654752f;
    const float C16 = 0.92387953251128674f;
    const float S16 = 0.38268343236508977f;
    const float sg = (float)SGN;
    float2 g[16];
#pragma unroll
    for (int b = 0; b < 4; ++b) {
        float2 x0 = x[b], x1 = x[4 + b], x2 = x[8 + b], x3 = x[12 + b];
        float2 e0 = make_float2(x0.x + x2.x, x0.y + x2.y);
        float2 e1 = make_float2(x0.x - x2.x, x0.y - x2.y);
        float2 o0 = make_float2(x1.x + x3.x, x1.y + x3.y);
        float2 o1 = make_float2(x1.x - x3.x, x1.y - x3.y);
        float2 io1 = (SGN > 0) ? make_float2(-o1.y, o1.x) : make_float2(o1.y, -o1.x);
        g[b * 4 + 0] = make_float2(e0.x + o0.x, e0.y + o0.y);
        g[b * 4 + 2] = make_float2(e0.x - o0.x, e0.y - o0.y);
        g[b * 4 + 1] = make_float2(e1.x + io1.x, e1.y + io1.y);
        g[b * 4 + 3] = make_float2(e1.x - io1.x, e1.y - io1.y);
    }
    g[5]  = cmulc(g[5],  C16,  sg * S16);
    g[6]  = cmulc(g[6],  C8,   sg * C8);
    g[7]  = cmulc(g[7],  S16,  sg * C16);
    g[9]  = cmulc(g[9],  C8,   sg * C8);
    g[10] = (SGN > 0) ? make_float2(-g[10].y, g[10].x)
                      : make_float2(g[10].y, -g[10].x);
    g[11] = cmulc(g[11], -C8,  sg * C8);
    g[13] = cmulc(g[13], S16,  sg * C16);
    g[14] = cmulc(g[14], -C8,  sg * C8);
    g[15] = cmulc(g[15], -C16, -sg * S16);
#pragma unroll
    for (int p = 0; p < 4; ++p) {
        float2 x0 = g[p], x1 = g[4 + p], x2 = g[8 + p], x3 = g[12 + p];
        float2 e0 = make_float2(x0.x + x2.x, x0.y + x2.y);
        float2 e1 = make_float2(x0.x - x2.x, x0.y - x2.y);
        float2 o0 = make_float2(x1.x + x3.x, x1.y + x3.y);
        float2 o1 = make_float2(x1.x - x3.x, x1.y - x3.y);
        float2 io1 = (SGN > 0) ? make_float2(-o1.y, o1.x) : make_float2(o1.y, -o1.x);
        x[p + 0]  = make_float2(e0.x + o0.x, e0.y + o0.y);
        x[p + 8]  = make_float2(e0.x - o0.x, e0.y - o0.y);
        x[p + 4]  = make_float2(e1.x + io1.x, e1.y + io1.y);
        x[p + 12] = make_float2(e1.x - io1.x, e1.y - io1.y);
    }
}

// 8-point DFT, DIT 2x fft4 + constant w8 twiddles. R15-proven.
template<int SGN>
__device__ inline void fft8(float2* x) {
    const float C8 = 0.70710678118654752f;
    const float sg = (float)SGN;
    float2 E[4], O[4];
    {
        float2 e0 = make_float2(x[0].x + x[4].x, x[0].y + x[4].y);
        float2 e1 = make_float2(x[0].x - x[4].x, x[0].y - x[4].y);
        float2 o0 = make_float2(x[2].x + x[6].x, x[2].y + x[6].y);
        float2 o1 = make_float2(x[2].x - x[6].x, x[2].y - x[6].y);
        float2 io1 = (SGN > 0) ? make_float2(-o1.y, o1.x) : make_float2(o1.y, -o1.x);
        E[0] = make_float2(e0.x + o0.x, e0.y + o0.y);
        E[2] = make_float2(e0.x - o0.x, e0.y - o0.y);
        E[1] = make_float2(e1.x + io1.x, e1.y + io1.y);
        E[3] = make_float2(e1.x - io1.x, e1.y - io1.y);
    }
    {
        float2 e0 = make_float2(x[1].x + x[5].x, x[1].y + x[5].y);
        float2 e1 = make_float2(x[1].x - x[5].x, x[1].y - x[5].y);
        float2 o0 = make_float2(x[3].x + x[7].x, x[3].y + x[7].y);
        float2 o1 = make_float2(x[3].x - x[7].x, x[3].y - x[7].y);
        float2 io1 = (SGN > 0) ? make_float2(-o1.y, o1.x) : make_float2(o1.y, -o1.x);
        O[0] = make_float2(e0.x + o0.x, e0.y + o0.y);
        O[2] = make_float2(e0.x - o0.x, e0.y - o0.y);
        O[1] = make_float2(e1.x + io1.x, e1.y + io1.y);
        O[3] = make_float2(e1.x - io1.x, e1.y - io1.y);
    }
    float2 t0 = O[0];
    float2 t1 = cmulc(O[1], C8, sg * C8);
    float2 t2 = (SGN > 0) ? make_float2(-O[2].y, O[2].x) : make_float2(O[2].y, -O[2].x);
    float2 t3 = cmulc(O[3], -C8, sg * C8);
    x[0] = make_float2(E[0].x + t0.x, E[0].y + t0.y);
    x[4] = make_float2(E[0].x - t0.x, E[0].y - t0.y);
    x[1] = make_float2(E[1].x + t1.x, E[1].y + t1.y);
    x[5] = make_float2(E[1].x - t1.x, E[1].y - t1.y);
    x[2] = make_float2(E[2].x + t2.x, E[2].y + t2.y);
    x[6] = make_float2(E[2].x - t2.x, E[2].y - t2.y);
    x[3] = make_float2(E[3].x + t3.x, E[3].y + t3.y);
    x[7] = make_float2(E[3].x - t3.x, E[3].y - t3.y);
}

// ---------------- table builders ----------------
__global__ void k_fact(float2* o, int N1, int N2, double sign, double scale, int r2) {
    int base3 = N1 * N1 + N2 * N2 + N2 * N1;
    int total = base3 + (r2 ? 63 : 0);
    int N = N1 * N2;
    for (int i = blockIdx.x * blockDim.x + threadIdx.x; i < total; i += blockDim.x * gridDim.x) {
        double ang; double sc = 1.0;
        if (i < N1 * N1) {
            int n1 = i / N1, k1 = i % N1;
            ang = sign * 2.0 * PI_D * (double)((n1 * k1) % N1) / (double)N1;
        } else if (i < N1 * N1 + N2 * N2) {
            int j = i - N1 * N1; int n2 = j / N2, k2 = j % N2;
            ang = sign * 2.0 * PI_D * (double)((n2 * k2) % N2) / (double)N2;
            sc = scale;
        } else if (i < base3) {
            int j = i - N1 * N1 - N2 * N2; int n2 = j / N1, k1 = j % N1;
            ang = sign * 2.0 * PI_D * (double)((n2 * k1) % N) / (double)N;
        } else if (i < base3 + 49) {
            int j = i - base3; int n = j / 7, k = j % 7;
            ang = sign * 2.0 * PI_D * (double)((n * k) % 7) / 7.0;
            sc = scale;
        } else {
            int k = i - base3 - 49;
            ang = sign * 2.0 * PI_D * (double)k / 14.0;
        }
        o[i] = make_float2((float)(sc * cos(ang)), (float)(sc * sin(ang)));
    }
}

__global__ void k_psi(float* out) {
    int i = blockIdx.x * blockDim.x + threadIdx.x;
    if (i >= 16 * IMG224) return;
    int jl = i / IMG224, p = i % IMG224;
    int r = p / 224, c = p % 224;
    int j = jl >> 3, l = jl & 7;
    double fr = (r < 112) ? (double)r : (double)(r - 224);
    double fc = (c < 112) ? (double)c : (double)(c - 224);
    double wx = 2.0 * PI_D * fr / 224.0;
    double wy = 2.0 * PI_D * fc / 224.0;
    double theta = (double)l * PI_D / 8.0;
    double xi = (3.0 * PI_D / 4.0) / (double)(1 << j);
    double sg = 0.8 * (double)(1 << j);
    double ct = cos(theta), st = sin(theta);
    double u = ct * wx + st * wy;
    double v = -st * wx + ct * wy;
    double vs = v / 0.5;
    double s2 = 0.5 * sg * sg;
    double gab = exp(-s2 * ((u - xi) * (u - xi) + vs * vs));
    double gau = exp(-s2 * (u * u + vs * vs));
    double kap = exp(-s2 * xi * xi);
    out[i] = (float)(gab - kap * gau);
}

__global__ void k_phi(float* phi0, float* phi1) {
    int i = blockIdx.x * blockDim.x + threadIdx.x;
    const double sp = 1.6;
    const double s2 = 0.5 * sp * sp;
    if (i < IMG224) {
        int r = i / 224, c = i % 224;
        double fr = (r < 112) ? (double)r : (double)(r - 224);
        double fc = (c < 112) ? (double)c : (double)(c - 224);
        double wx = 2.0 * PI_D * fr / 224.0;
        double wy = 2.0 * PI_D * fc / 224.0;
        phi0[i] = (float)exp(-s2 * (wx * wx + wy * wy));
    } else if (i < IMG224 + IMG112) {
        int p = i - IMG224, a = p / 112, b = p % 112;
        double sum = 0.0;
        for (int ii = 0; ii < 2; ++ii)
            for (int jj = 0; jj < 2; ++jj) {
                int r = a + 112 * ii, c = b + 112 * jj;
                double fr = (r < 112) ? (double)r : (double)(r - 224);
                double fc = (c < 112) ? (double)c : (double)(c - 224);
                double wx = 2.0 * PI_D * fr / 224.0;
                double wy = 2.0 * PI_D * fc / 224.0;
                sum += exp(-s2 * (wx * wx + wy * wy));
            }
        phi1[p] = (float)(0.25 * sum);
    }
}

__global__ void k_zero(unsigned* gk, int n) {
    int i = blockIdx.x * blockDim.x + threadIdx.x;
    if (i < n) gk[i] = 0u;
}

// ---------------- rk: row pass, two-stage (N=N1*N2), fused in LDS (R8..R16-proven) ----
template<int N1, int N2, int TA, int FOLD, int BS, bool REAL, int SGN>
__global__ __launch_bounds__(BS) void rk(
    const void* __restrict__ inBase, int inShift,
    const float* __restrict__ fltBase, int fltMask,
    const float2* __restrict__ FT, float2* __restrict__ out,
    int swzImg, int inStride, int inOff)
{
    constexpr int N = N1 * N2;
    constexpr int NIN = N * FOLD;
    constexpr int ZS = N + 2;
    constexpr int TS = N2 * (N1 + 1);
    constexpr int K1H = N1 / 2;
    __shared__ float2 Z[TA * ZS];
    __shared__ float2 T[TA * TS];
    const float2* W2 = FT + N1 * N1;
    const float2* TW = FT + N1 * N1 + N2 * N2;
    const int bx = blockIdx.x, a0 = blockIdx.y * TA, t = threadIdx.x;
    int gIn, gFlt, gOut;
    if (swzImg > 0) {
        int img = bx % swzImg, sub = bx / swzImg;
        gIn = img * inStride + inOff + (sub >> 3);
        gFlt = sub & fltMask;
        gOut = img * (gridDim.x / swzImg) + sub;
    } else {
        gIn = bx >> inShift; gFlt = bx & fltMask; gOut = bx;
    }

    if (REAL) {
        const float* in = (const float*)inBase + (size_t)gIn * N * N;
        for (int r = 0; r < TA; ++r)
            for (int b = t; b < N; b += BS)
                Z[r * ZS + b] = make_float2(in[(size_t)(a0 + r) * N + b], 0.f);
    } else {
        const float2* in = (const float2*)inBase + (size_t)gIn * (NIN * NIN);
        const float* flt = fltBase + (size_t)gFlt * (NIN * NIN);
        const float s = 1.0f / (float)(FOLD * FOLD);
        for (int r = 0; r < TA; ++r) {
            int a = a0 + r;
            for (int b = t; b < N; b += BS) {
                float re = 0.f, im = 0.f;
#pragma unroll
                for (int i = 0; i < FOLD; ++i)
#pragma unroll
                    for (int j = 0; j < FOLD; ++j) {
                        int idx = (a + N * i) * NIN + (b + N * j);
                        float2 v = in[idx];
                        float f = flt[idx];
                        re += v.x * f; im += v.y * f;
                    }
                Z[r * ZS + b] = make_float2(re * s, im * s);
            }
        }
    }
    __syncthreads();
    for (int idx = t; idx < TA * N2 * 2; idx += BS) {
        int r = idx / (N2 * 2);
        int rem = idx % (N2 * 2);
        int n2 = rem / 2, h = rem % 2;
        float2 xx[N1];
#pragma unroll
        for (int n1 = 0; n1 < N1; ++n1) xx[n1] = Z[r * ZS + n1 * N2 + n2];
        if constexpr (N1 == 16) fft16<SGN>(xx); else fft8<SGN>(xx);
#pragma unroll
        for (int kk = 0; kk < K1H; ++kk) {
            int k1 = h * K1H + kk;
            float2 tw = TW[n2 * N1 + k1];
            T[r * TS + n2 * (N1 + 1) + k1] = cmulc(xx[k1], tw.x, tw.y);
        }
    }
    __syncthreads();
    if constexpr (N2 == 14) {
        const float2* W7  = FT + N1 * N1 + N2 * N2 + N2 * N1;
        const float2* T14 = W7 + 49;
        for (int idx = t; idx < TA * N1; idx += BS) {
            int r = idx / N1, k1 = idx % N1;
            float2 E[7], O[7];
#pragma unroll
            for (int k = 0; k < 7; ++k) { E[k] = make_float2(0.f, 0.f); O[k] = make_float2(0.f, 0.f); }
            for (int m = 0; m < 7; ++m) {
                float2 te = T[r * TS + (2 * m) * (N1 + 1) + k1];
                float2 to = T[r * TS + (2 * m + 1) * (N1 + 1) + k1];
#pragma unroll
                for (int k = 0; k < 7; ++k) {
                    float2 w = W7[m * 7 + k];
                    cmac(E[k], te, w);
                    cmac(O[k], to, w);
                }
            }
#pragma unroll
            for (int k = 0; k < 14; ++k) {
                float2 tw = T14[k];
                float2 o_ = O[k % 7];
                float2 X = E[k % 7];
                X.x += o_.x * tw.x - o_.y * tw.y;
                X.y += o_.x * tw.y + o_.y * tw.x;
                Z[r * ZS + k1 + N1 * k] = X;
            }
        }
    } else {
        for (int idx = t; idx < TA * N1; idx += BS) {
            int r = idx / N1, k1 = idx % N1;
            float2 acc[N2];
#pragma unroll
            for (int kk = 0; kk < N2; ++kk) acc[kk] = make_float2(0.f, 0.f);
            for (int n2 = 0; n2 < N2; ++n2) {
                float2 tv = T[r * TS + n2 * (N1 + 1) + k1];
#pragma unroll
                for (int kk = 0; kk < N2; ++kk) cmac(acc[kk], tv, W2[n2 * N2 + kk]);
            }
#pragma unroll
            for (int kk = 0; kk < N2; ++kk) Z[r * ZS + k1 + N1 * kk] = acc[kk];
        }
    }
    __syncthreads();
    for (int r = 0; r < TA; ++r) {
        float2* o = out + ((size_t)gOut * N + (a0 + r)) * N;
        for (int b = t; b < N; b += BS) o[b] = Z[r * ZS + b];
    }
}

// ---------------- ck1: col pass stage 1 — fft16 columns (R13-proven) ----------------
template<int N1, int N2, int SPLIT, int BS, int SGN>
__global__ __launch_bounds__(BS) void ck1(
    const float2* __restrict__ in, const float2* __restrict__ FT, float2* __restrict__ out)
{
    constexpr int N = N1 * N2;
    constexpr int NC = N / SPLIT;
    const float2* TW = FT + N1 * N1 + N2 * N2;
    const int g = blockIdx.x / SPLIT, half = blockIdx.x % SPLIT;
    const int n2 = blockIdx.y, t = threadIdx.x;
    if (2 * t >= NC) return;
    const int b0 = 2 * t + half * NC;
    const float2* I = in + (size_t)g * N * N;
    float2 a0[16], a1[16];
#pragma unroll
    for (int n1 = 0; n1 < 16; ++n1) {
        float4 v = *reinterpret_cast<const float4*>(&I[(size_t)(n1 * N2 + n2) * N + b0]);
        a0[n1] = make_float2(v.x, v.y);
        a1[n1] = make_float2(v.z, v.w);
    }
    fft16<SGN>(a0);
    fft16<SGN>(a1);
#pragma unroll
    for (int k1 = 0; k1 < 16; ++k1) {
        float2 tw = TW[n2 * N1 + k1];
        float2 r0 = cmulc(a0[k1], tw.x, tw.y);
        float2 r1 = cmulc(a1[k1], tw.x, tw.y);
        *reinterpret_cast<float4*>(&out[((size_t)g * N + (k1 * N2 + n2)) * N + b0]) =
            make_float4(r0.x, r0.y, r1.x, r1.y);
    }
}

// ---------------- ck2: col pass stage 2 + MODE (R14: N2=14 DIT; N2=7 dense) ----------------
template<int N1, int N2, int SPLIT, int MODE, int BS>
__global__ __launch_bounds__(BS) void ck2(
    const float2* __restrict__ in, const float2* __restrict__ FT,
    float2* __restrict__ outc, float* __restrict__ outr)
{
    constexpr int N = N1 * N2;
    constexpr int NC = N / SPLIT;
    const float2* W2 = FT + N1 * N1;
    const int g = blockIdx.x / SPLIT, half = blockIdx.x % SPLIT;
    const int k1 = blockIdx.y, t = threadIdx.x;
    if (2 * t >= NC) return;
    const int b0 = 2 * t + half * NC;
    const float2* I = in + (size_t)g * N * N;
    if constexpr (N2 == 14) {
        const float2* W7  = FT + N1 * N1 + N2 * N2 + N2 * N1;
        const float2* T14 = W7 + 49;
        float2 E0[7], E1[7], O0[7], O1[7];
#pragma unroll
        for (int k = 0; k < 7; ++k) {
            E0[k] = make_float2(0.f, 0.f); E1[k] = make_float2(0.f, 0.f);
            O0[k] = make_float2(0.f, 0.f); O1[k] = make_float2(0.f, 0.f);
        }
        for (int m = 0; m < 7; ++m) {
            float4 ve = *reinterpret_cast<const float4*>(&I[(size_t)(k1 * 14 + 2 * m) * N + b0]);
            float4 vo = *reinterpret_cast<const float4*>(&I[(size_t)(k1 * 14 + 2 * m + 1) * N + b0]);
            float2 ve0 = make_float2(ve.x, ve.y), ve1 = make_float2(ve.z, ve.w);
            float2 vo0 = make_float2(vo.x, vo.y), vo1 = make_float2(vo.z, vo.w);
#pragma unroll
            for (int k = 0; k < 7; ++k) {
                float2 w = W7[m * 7 + k];
                cmac(E0[k], ve0, w); cmac(E1[k], ve1, w);
                cmac(O0[k], vo0, w); cmac(O1[k], vo1, w);
            }
        }
#pragma unroll
        for (int k = 0; k < 14; ++k) {
            float2 tw = T14[k];
            float2 r0 = E0[k % 7], r1 = E1[k % 7];
            float2 o0 = O0[k % 7], o1 = O1[k % 7];
            r0.x += o0.x * tw.x - o0.y * tw.y;
            r0.y += o0.x * tw.y + o0.y * tw.x;
            r1.x += o1.x * tw.x - o1.y * tw.y;
            r1.y += o1.x * tw.y + o1.y * tw.x;
            if (MODE == 0) {
                *reinterpret_cast<float4*>(&outc[((size_t)g * N + (k1 + N1 * k)) * N + b0]) =
                    make_float4(r0.x, r0.y, r1.x, r1.y);
            } else {
                size_t o = ((size_t)g * N + (k1 + N1 * k)) * N + b0;
                outr[o]     = sqrtf(r0.x * r0.x + r0.y * r0.y);
                outr[o + 1] = sqrtf(r1.x * r1.x + r1.y * r1.y);
            }
        }
    } else {
        float2 acc[N2][2];
#pragma unroll
        for (int k2 = 0; k2 < N2; ++k2) { acc[k2][0] = make_float2(0.f, 0.f); acc[k2][1] = make_float2(0.f, 0.f); }
        for (int n2 = 0; n2 < N2; ++n2) {
            float4 v = *reinterpret_cast<const float4*>(&I[(size_t)(k1 * N2 + n2) * N + b0]);
            float2 v0 = make_float2(v.x, v.y), v1 = make_float2(v.z, v.w);
#pragma unroll
            for (int k2 = 0; k2 < N2; ++k2) {
                float2 w = W2[n2 * N2 + k2];
                cmac(acc[k2][0], v0, w);
                cmac(acc[k2][1], v1, w);
            }
        }
        if (MODE == 0) {
#pragma unroll
            for (int k2 = 0; k2 < N2; ++k2)
                *reinterpret_cast<float4*>(&outc[((size_t)g * N + (k1 + N1 * k2)) * N + b0]) =
                    make_float4(acc[k2][0].x, acc[k2][0].y, acc[k2][1].x, acc[k2][1].y);
        } else {
#pragma unroll
            for (int k2 = 0; k2 < N2; ++k2) {
                size_t o = ((size_t)g * N + (k1 + N1 * k2)) * N + b0;
                outr[o]     = sqrtf(acc[k2][0].x * acc[k2][0].x + acc[k2][0].y * acc[k2][0].y);
                outr[o + 1] = sqrtf(acc[k2][1].x * acc[k2][1].x + acc[k2][1].y * acc[k2][1].y);
            }
        }
    }
}

// ---------------- s56max: fused fold*phi -> ifft2(56) via 8x7 -> Re -> max -> atomicMax ----
// R17: one block per group; whole 56x56 tile in LDS (Z 25.5KB + T 25.5KB = 51KB < 64KB
// workgroup cap). Separate Z/T buffers throughout (R9 lesson: no in-place LDS aliasing).
// Rows: fft8+TW (phaseA Z->T), 7pt W2 (phaseB T->Z). Cols: same, final 7pt computes
// Re only + running max -> wave/block reduce -> one atomicMax. Replaces rk56+colpass_max.
template<int FOLD, int BS>
__global__ __launch_bounds__(BS) void s56max(
    const float2* __restrict__ in, const float* __restrict__ flt,
    const float2* __restrict__ FT, unsigned* __restrict__ gk,
    int slotBase, int slotShift, int slotMask)
{
    constexpr int N = 56, NIN = 56 * FOLD, ZS = 57;
    __shared__ float2 Z[N * ZS];
    __shared__ float2 T[N * ZS];
    __shared__ float red[BS / 64];
    const float2* W2 = FT + 64;        // 7x7, scale 1/56
    const float2* TW = FT + 64 + 49;   // 7x8
    const int g = blockIdx.x, t = threadIdx.x;
    const float2* I = in + (size_t)g * NIN * NIN;
    const float s = 1.0f / (float)(FOLD * FOLD);
    // stage 0: fold * filter
    for (int idx = t; idx < N * N; idx += BS) {
        int r = idx / N, b = idx % N;
        float re = 0.f, im = 0.f;
#pragma unroll
        for (int i = 0; i < FOLD; ++i)
#pragma unroll
            for (int j = 0; j < FOLD; ++j) {
                int p = (r + N * i) * NIN + (b + N * j);
                float2 v = I[p];
                float f = flt[p];
                re += v.x * f; im += v.y * f;
            }
        Z[r * ZS + b] = make_float2(re * s, im * s);
    }
    __syncthreads();
    // rows phase A: (r, n2): fft8 of residue class -> TW -> T
    for (int idx = t; idx < 7 * N; idx += BS) {
        int n2 = idx / N, r = idx % N;
        float2 xx[8];
#pragma unroll
        for (int n1 = 0; n1 < 8; ++n1) xx[n1] = Z[r * ZS + n1 * 7 + n2];
        fft8<1>(xx);
#pragma unroll
        for (int k1 = 0; k1 < 8; ++k1) {
            float2 tw = TW[n2 * 8 + k1];
            T[r * ZS + k1 * 7 + n2] = cmulc(xx[k1], tw.x, tw.y);
        }
    }
    __syncthreads();
    // rows phase B: (r, k1): 7pt -> Z natural order
    for (int idx = t; idx < 8 * N; idx += BS) {
        int k1 = idx / N, r = idx % N;
        float2 tv[7];
#pragma unroll
        for (int n2 = 0; n2 < 7; ++n2) tv[n2] = T[r * ZS + k1 * 7 + n2];
#pragma unroll
        for (int k2 = 0; k2 < 7; ++k2) {
            float2 acc = make_float2(0.f, 0.f);
#pragma unroll
            for (int n2 = 0; n2 < 7; ++n2) cmac(acc, tv[n2], W2[n2 * 7 + k2]);
            Z[r * ZS + k1 + 8 * k2] = acc;
        }
    }
    __syncthreads();
    // cols phase A: (b, n2): fft8 down column b -> TW -> T
    for (int idx = t; idx < 7 * N; idx += BS) {
        int n2 = idx / N, b = idx % N;
        float2 xx[8];
#pragma unroll
        for (int n1 = 0; n1 < 8; ++n1) xx[n1] = Z[(n1 * 7 + n2) * ZS + b];
        fft8<1>(xx);
#pragma unroll
        for (int k1 = 0; k1 < 8; ++k1) {
            float2 tw = TW[n2 * 8 + k1];
            T[(k1 * 7 + n2) * ZS + b] = cmulc(xx[k1], tw.x, tw.y);
        }
    }
    __syncthreads();
    // cols phase B: (b, k1): 7pt, REAL part only, running max
    float m = -INFINITY;
    for (int idx = t; idx < 8 * N; idx += BS) {
        int k1 = idx / N, b = idx % N;
        float2 tv[7];
#pragma unroll
        for (int n2 = 0; n2 < 7; ++n2) tv[n2] = T[(k1 * 7 + n2) * ZS + b];
#pragma unroll
        for (int k2 = 0; k2 < 7; ++k2) {
            float re = 0.f;
#pragma unroll
            for (int n2 = 0; n2 < 7; ++n2) {
                float2 w = W2[n2 * 7 + k2];
                re += tv[n2].x * w.x - tv[n2].y * w.y;
            }
            m = fmaxf(m, re);
        }
    }
    for (int off = 32; off > 0; off >>= 1) m = fmaxf(m, __shfl_down(m, off, 64));
    if ((t & 63) == 0) red[t >> 6] = m;
    __syncthreads();
    if (t == 0) {
#pragma unroll
        for (int w = 1; w < BS / 64; ++w) m = fmaxf(m, red[w]);
        int slot = slotBase + ((g >> slotShift) * 81) + (g & slotMask);
        atomicMax(&gk[slot], fkey(m));
    }
}

// ---------------- classifier head ----------------
__global__ void k_linear(const unsigned* __restrict__ gk, const float* __restrict__ Wl,
                         const float* __restrict__ bl, float* __restrict__ out)
{
    int i = blockIdx.x * blockDim.x + threadIdx.x;
    if (i >= 16 * 1000) return;
    int b = i / 1000, o = i % 1000;
    float s = bl[o];
    for (int f = 0; f < 243; ++f)
        s += funkey(gk[b * 243 + f]) * Wl[o * 243 + f];
    out[i] = s;
}

// ---------------- launch ----------------
extern "C" void kernel_launch(void* const* d_in, const int* in_sizes, int n_in,
                              void* d_out, int out_size, void* d_ws, size_t ws_size,
                              hipStream_t stream)
{
    const float* x  = (const float*)d_in[0];
    const float* Wl = (const float*)d_in[1];
    const float* bl = (const float*)d_in[2];
    float* out = (float*)d_out;
    float* ws = (float*)d_ws;

    float2* FT224F = (float2*)(ws + OFF_FT224F);
    float2* FT224I = (float2*)(ws + OFF_FT224I);
    float2* FT112F = (float2*)(ws + OFF_FT112F);
    float2* FT112I = (float2*)(ws + OFF_FT112I);
    float2* FT56I  = (float2*)(ws + OFF_FT56I);
    float* PSI0 = ws + OFF_PSI;
    float* PSI1 = ws + OFF_PSI + 8 * IMG224;
    float* PHI0 = ws + OFF_PHI0;
    float* PHI1 = ws + OFF_PHI1;
    unsigned* GK = (unsigned*)(ws + OFF_GK);
    float2* XH  = (float2*)(ws + OFF_XH);
    float* A0  = ws + OFF_POOL;                       // 9633792 floats (V1 pair)

    const size_t NEED_BATCH = OFF_POOL + 9633792 + 2 * (size_t)19267584;
    const bool batch = (ws_size / 4) >= NEED_BATCH;   // R16: measured to fit
    float* A1  = A0 + 9633792;
    float* A23 = A1 + (batch ? 19267584 : 9633792);

    // tables
    k_fact<<<4, 256, 0, stream>>>(FT224F, 16, 14, -1.0, 1.0, 1);
    k_fact<<<4, 256, 0, stream>>>(FT224I, 16, 14,  1.0, 1.0 / 224.0, 1);
    k_fact<<<4, 256, 0, stream>>>(FT112F, 16, 7,  -1.0, 1.0, 0);
    k_fact<<<4, 256, 0, stream>>>(FT112I, 16, 7,   1.0, 1.0 / 112.0, 0);
    k_fact<<<1, 256, 0, stream>>>(FT56I,  8, 7,    1.0, 1.0 / 56.0, 0);
    k_psi<<<(16 * IMG224 + 255) / 256, 256, 0, stream>>>(ws + OFF_PSI);
    k_phi<<<(IMG224 + IMG112 + 255) / 256, 256, 0, stream>>>(PHI0, PHI1);
    k_zero<<<(3888 + 255) / 256, 256, 0, stream>>>(GK, 3888);

    // ---- fft2(x) -> XH ----
    rk<16, 14, 4, 1, 128, true, -1><<<dim3(48, 56), 128, 0, stream>>>(x, 0, nullptr, 0, FT224F, (float2*)A0, 0, 0, 0);
    ck1<16, 14, 2, 64, -1><<<dim3(96, 14), 64, 0, stream>>>((float2*)A0, FT224F, (float2*)A1);
    ck2<16, 14, 2, 0, 64><<<dim3(96, 16), 64, 0, stream>>>((float2*)A1, FT224F, XH, nullptr);

    // ---- s0 -> GK slot img*81+0 ----
    s56max<4, 256><<<48, 256, 0, stream>>>(XH, PHI0, FT56I, GK, 0, 0, 0);

    // ---- pair-batched first order j1=0 (+ second order); g = img*2 + lc, l1 = 2c+lc ----
    for (int c = 0; c < 4; ++c) {
        // A: ifft rows of xh*psi0[l1] -> A0 (96 groups)
        rk<16, 14, 4, 1, 128, false, 1><<<dim3(96, 56), 128, 0, stream>>>(
            XH, 1, PSI0 + (size_t)(2 * c) * IMG224, 1, FT224I, (float2*)A0, 0, 0, 0);
        // B: ifft cols + |.| -> A23 (real u1)
        ck1<16, 14, 2, 64, 1><<<dim3(192, 14), 64, 0, stream>>>((float2*)A0, FT224I, (float2*)A1);
        ck2<16, 14, 2, 1, 64><<<dim3(192, 16), 64, 0, stream>>>((float2*)A1, FT224I, nullptr, A23);
        // C: fft rows of u1 (real) -> A0
        rk<16, 14, 4, 1, 128, true, -1><<<dim3(96, 56), 128, 0, stream>>>(A23, 0, nullptr, 0, FT224F, (float2*)A0, 0, 0, 0);
        // D: fft cols -> V1 (A0)
        ck1<16, 14, 2, 64, -1><<<dim3(192, 14), 64, 0, stream>>>((float2*)A0, FT224F, (float2*)A1);
        ck2<16, 14, 2, 0, 64><<<dim3(192, 16), 64, 0, stream>>>((float2*)A1, FT224F, (float2*)A0, nullptr);
        // E: s1 -> GK slot img*81 + 1 + 2c + lc
        s56max<4, 256><<<96, 256, 0, stream>>>((float2*)A0, PHI0, FT56I, GK, 1 + 2 * c, 1, 1);
        if (batch) {
            // second order, both lc at once: 768 groups, g = img*16 + lc*8 + l2
            rk<16, 7, 8, 2, 128, false, 1><<<dim3(768, 14), 128, 0, stream>>>(
                (float2*)A0, 0, PSI1, 7, FT112I, (float2*)A1, 48, 2, 0);
            ck1<16, 7, 1, 64, 1><<<dim3(768, 7), 64, 0, stream>>>((float2*)A1, FT112I, (float2*)A23);
            ck2<16, 7, 1, 1, 64><<<dim3(768, 16), 64, 0, stream>>>((float2*)A23, FT112I, nullptr, A1);
            rk<16, 7, 8, 1, 128, true, -1><<<dim3(768, 14), 128, 0, stream>>>(A1, 0, nullptr, 0, FT112F, (float2*)A23, 0, 0, 0);
            ck1<16, 7, 1, 64, -1><<<dim3(768, 7), 64, 0, stream>>>((float2*)A23, FT112F, (float2*)A1);
            ck2<16, 7, 1, 0, 64><<<dim3(768, 16), 64, 0, stream>>>((float2*)A1, FT112F, (float2*)A23, nullptr);
            s56max<2, 256><<<768, 256, 0, stream>>>((float2*)A23, PHI1, FT56I, GK, 17 + 16 * c, 4, 15);
        } else {
            for (int lc = 0; lc < 2; ++lc) {
                int l1 = 2 * c + lc;
                rk<16, 7, 8, 2, 128, false, 1><<<dim3(384, 14), 128, 0, stream>>>(
                    (float2*)A0, 0, PSI1, 7, FT112I, (float2*)A1, 48, 2, lc);
                ck1<16, 7, 1, 64, 1><<<dim3(384, 7), 64, 0, stream>>>((float2*)A1, FT112I, (float2*)A23);
                ck2<16, 7, 1, 1, 64><<<dim3(384, 16), 64, 0, stream>>>((float2*)A23, FT112I, nullptr, A1);
                rk<16, 7, 8, 1, 128, true, -1><<<dim3(384, 14), 128, 0, stream>>>(A1, 0, nullptr, 0, FT112F, (float2*)A23, 0, 0, 0);
                ck1<16, 7, 1, 64, -1><<<dim3(384, 7), 64, 0, stream>>>((float2*)A23, FT112F, (float2*)A1);
                ck2<16, 7, 1, 0, 64><<<dim3(384, 16), 64, 0, stream>>>((float2*)A1, FT112F, (float2*)A23, nullptr);
                s56max<2, 256><<<384, 256, 0, stream>>>((float2*)A23, PHI1, FT56I, GK, 17 + 8 * l1, 3, 7);
            }
        }
    }

    // ---- first order j1=1 (8 orientations, g = img*8+l) ----
    rk<16, 7, 8, 2, 128, false, 1><<<dim3(384, 14), 128, 0, stream>>>(XH, 0, PSI1, 7, FT112I, (float2*)A1, 48, 1, 0);
    ck1<16, 7, 1, 64, 1><<<dim3(384, 7), 64, 0, stream>>>((float2*)A1, FT112I, (float2*)A23);
    ck2<16, 7, 1, 1, 64><<<dim3(384, 16), 64, 0, stream>>>((float2*)A23, FT112I, nullptr, A1);
    rk<16, 7, 8, 1, 128, true, -1><<<dim3(384, 14), 128, 0, stream>>>(A1, 0, nullptr, 0, FT112F, (float2*)A23, 0, 0, 0);
    ck1<16, 7, 1, 64, -1><<<dim3(384, 7), 64, 0, stream>>>((float2*)A23, FT112F, (float2*)A1);
    ck2<16, 7, 1, 0, 64><<<dim3(384, 16), 64, 0, stream>>>((float2*)A1, FT112F, (float2*)A23, nullptr);
    s56max<2, 256><<<384, 256, 0, stream>>>((float2*)A23, PHI1, FT56I, GK, 9, 3, 7);

    // head
    k_linear<<<(16000 + 255) / 256, 256, 0, stream>>>(GK, Wl, bl, out);
}

// Round 18
// 2017.594 us; speedup vs baseline: 2.0758x; 1.0015x over previous
//
#include <hip/hip_runtime.h>
#include <math.h>

#define PI_D 3.14159265358979323846

// ---------------- workspace layout (float units) ----------------
#define IMG224 50176
#define IMG112 12544
// factorized DFT tables per (N,dir): [W1:N1*N1 | W2:N2*N2 | TW:N2*N1 | (r2: W7:49 | T14:14)]
static const size_t OFF_FT224F = 0;
static const size_t OFF_FT224I = 2048;
static const size_t OFF_FT112F = 4096;
static const size_t OFF_FT112I = 6144;
static const size_t OFF_FT56I  = 8192;     // [W1:64|W2:49|TW:56] = 169 float2
static const size_t OFF_PSI   = 257152;    // 16*50176
static const size_t OFF_PHI0  = 1059968;
static const size_t OFF_PHI1  = 1110144;
static const size_t OFF_GK    = 1122688;   // 3888 keys
static const size_t OFF_XH    = 1126784;   // 4816896
static const size_t OFF_POOL  = 5943680;
// unbatched pools: A0,A1,A23 = 9633792 each (~149MB, known-fits)
// lc-batched pools: A0=9633792, A1b=A23b=19267584 (~216MB; R16-measured to fit)

// ---------------- helpers ----------------
__device__ inline unsigned fkey(float v) {
    int b = __float_as_int(v);
    return (b >= 0) ? ((unsigned)b | 0x80000000u) : ~(unsigned)b;
}
__device__ inline float funkey(unsigned u) {
    int b = (u & 0x80000000u) ? (int)(u & 0x7fffffffu) : (int)~u;
    return __int_as_float(b);
}
__device__ inline void cmac(float2& a, float2 z, float2 w) {
    a.x += z.x * w.x - z.y * w.y;
    a.y += z.x * w.y + z.y * w.x;
}
__device__ inline float2 cmulc(float2 v, float c, float s) {
    return make_float2(v.x * c - v.y * s, v.x * s + v.y * c);
}

// 16-point DFT, radix-4 x radix-4, constant twiddles. R13-proven.
template<int SGN>
__device__ inline void fft16(float2* x) {
    const float C8  = 0.70710678118654752f;
    const float C16 = 0.92387953251128674f;
    const float S16 = 0.38268343236508977f;
    const float sg = (float)SGN;
    float2 g[16];
#pragma unroll
    for (int b = 0; b < 4; ++b) {
        float2 x0 = x[b], x1 = x[4 + b], x2 = x[8 + b], x3 = x[12 + b];
        float2 e0 = make_float2(x0.x + x2.x, x0.y + x2.y);
        float2 e1 = make_float2(x0.x - x2.x, x0.y - x2.y);
        float2 o0 = make_float2(x1.x + x3.x, x1.y + x3.y);
        float2 o1 = make_float2(x1.x - x3.x, x1.y - x3.y);
        float2 io1 = (SGN > 0) ? make_float2(-o1.y, o1.x) : make_float2(o1.y, -o1.x);
        g[b * 4 + 0] = make_float2(e0.x + o0.x, e0.y + o0.y);
        g[b * 4 + 2] = make_float2(e0.x - o0.x, e0.y - o0.y);
        g[b * 4 + 1] = make_float2(e1.x + io1.x, e1.y + io1.y);
        g[b * 4 + 3] = make_float2(e1.x - io1.x, e1.y - io1.y);
    }
    g[5]  = cmulc(g[5],  C16,  sg * S16);
    g[6]  = cmulc(g[6],  C8,   sg * C8);
    g[7]  = cmulc(g[7],  S16,  sg * C16);
    g[9]  = cmulc(g[9],  C8,   sg * C8);
    g[10] = (SGN > 0) ? make_float2(-g[10].y, g[10].x)
                      : make_float2(g[10].y, -g[10].x);
    g[11] = cmulc(g[11], -C8,  sg * C8);
    g[13] = cmulc(g[13], S16,  sg * C16);
    g[14] = cmulc(g[14], -C8,  sg * C8);
    g[15] = cmulc(g[15], -C16, -sg * S16);
#pragma unroll
    for (int p = 0; p < 4; ++p) {
        float2 x0 = g[p], x1 = g[4 + p], x2 = g[8 + p], x3 = g[12 + p];
        float2 e0 = make_float2(x0.x + x2.x, x0.y + x2.y);
        float2 e1 = make_float2(x0.x - x2.x, x0.y - x2.y);
        float2 o0 = make_float2(x1.x + x3.x, x1.y + x3.y);
        float2 o1 = make_float2(x1.x - x3.x, x1.y - x3.y);
        float2 io1 = (SGN > 0) ? make_float2(-o1.y, o1.x) : make_float2(o1.y, -o1.x);
        x[p + 0]  = make_float2(e0.x + o0.x, e0.y + o0.y);
        x[p + 8]  = make_float2(e0.x - o0.x, e0.y - o0.y);
        x[p + 4]  = make_float2(e1.x + io1.x, e1.y + io1.y);
        x[p + 12] = make_float2(e1.x - io1.x, e1.y - io1.y);
    }
}

// 8-point DFT, DIT 2x fft4 + constant w8 twiddles. R15-proven.
template<int SGN>
__device__ inline void fft8(float2* x) {
    const float C8 = 0.70710678118654752f;
    const float sg = (float)SGN;
    float2 E[4], O[4];
    {
        float2 e0 = make_float2(x[0].x + x[4].x, x[0].y + x[4].y);
        float2 e1 = make_float2(x[0].x - x[4].x, x[0].y - x[4].y);
        float2 o0 = make_float2(x[2].x + x[6].x, x[2].y + x[6].y);
        float2 o1 = make_float2(x[2].x - x[6].x, x[2].y - x[6].y);
        float2 io1 = (SGN > 0) ? make_float2(-o1.y, o1.x) : make_float2(o1.y, -o1.x);
        E[0] = make_float2(e0.x + o0.x, e0.y + o0.y);
        E[2] = make_float2(e0.x - o0.x, e0.y - o0.y);
        E[1] = make_float2(e1.x + io1.x, e1.y + io1.y);
        E[3] = make_float2(e1.x - io1.x, e1.y - io1.y);
    }
    {
        float2 e0 = make_float2(x[1].x + x[5].x, x[1].y + x[5].y);
        float2 e1 = make_float2(x[1].x - x[5].x, x[1].y - x[5].y);
        float2 o0 = make_float2(x[3].x + x[7].x, x[3].y + x[7].y);
        float2 o1 = make_float2(x[3].x - x[7].x, x[3].y - x[7].y);
        float2 io1 = (SGN > 0) ? make_float2(-o1.y, o1.x) : make_float2(o1.y, -o1.x);
        O[0] = make_float2(e0.x + o0.x, e0.y + o0.y);
        O[2] = make_float2(e0.x - o0.x, e0.y - o0.y);
        O[1] = make_float2(e1.x + io1.x, e1.y + io1.y);
        O[3] = make_float2(e1.x - io1.x, e1.y - io1.y);
    }
    float2 t0 = O[0];
    float2 t1 = cmulc(O[1], C8, sg * C8);
    float2 t2 = (SGN > 0) ? make_float2(-O[2].y, O[2].x) : make_float2(O[2].y, -O[2].x);
    float2 t3 = cmulc(O[3], -C8, sg * C8);
    x[0] = make_float2(E[0].x + t0.x, E[0].y + t0.y);
    x[4] = make_float2(E[0].x - t0.x, E[0].y - t0.y);
    x[1] = make_float2(E[1].x + t1.x, E[1].y + t1.y);
    x[5] = make_float2(E[1].x - t1.x, E[1].y - t1.y);
    x[2] = make_float2(E[2].x + t2.x, E[2].y + t2.y);
    x[6] = make_float2(E[2].x - t2.x, E[2].y - t2.y);
    x[3] = make_float2(E[3].x + t3.x, E[3].y + t3.y);
    x[7] = make_float2(E[3].x - t3.x, E[3].y - t3.y);
}

// ---------------- table builders ----------------
__global__ void k_fact(float2* o, int N1, int N2, double sign, double scale, int r2) {
    int base3 = N1 * N1 + N2 * N2 + N2 * N1;
    int total = base3 + (r2 ? 63 : 0);
    int N = N1 * N2;
    for (int i = blockIdx.x * blockDim.x + threadIdx.x; i < total; i += blockDim.x * gridDim.x) {
        double ang; double sc = 1.0;
        if (i < N1 * N1) {
            int n1 = i / N1, k1 = i % N1;
            ang = sign * 2.0 * PI_D * (double)((n1 * k1) % N1) / (double)N1;
        } else if (i < N1 * N1 + N2 * N2) {
            int j = i - N1 * N1; int n2 = j / N2, k2 = j % N2;
            ang = sign * 2.0 * PI_D * (double)((n2 * k2) % N2) / (double)N2;
            sc = scale;
        } else if (i < base3) {
            int j = i - N1 * N1 - N2 * N2; int n2 = j / N1, k1 = j % N1;
            ang = sign * 2.0 * PI_D * (double)((n2 * k1) % N) / (double)N;
        } else if (i < base3 + 49) {
            int j = i - base3; int n = j / 7, k = j % 7;
            ang = sign * 2.0 * PI_D * (double)((n * k) % 7) / 7.0;
            sc = scale;
        } else {
            int k = i - base3 - 49;
            ang = sign * 2.0 * PI_D * (double)k / 14.0;
        }
        o[i] = make_float2((float)(sc * cos(ang)), (float)(sc * sin(ang)));
    }
}

__global__ void k_psi(float* out) {
    int i = blockIdx.x * blockDim.x + threadIdx.x;
    if (i >= 16 * IMG224) return;
    int jl = i / IMG224, p = i % IMG224;
    int r = p / 224, c = p % 224;
    int j = jl >> 3, l = jl & 7;
    double fr = (r < 112) ? (double)r : (double)(r - 224);
    double fc = (c < 112) ? (double)c : (double)(c - 224);
    double wx = 2.0 * PI_D * fr / 224.0;
    double wy = 2.0 * PI_D * fc / 224.0;
    double theta = (double)l * PI_D / 8.0;
    double xi = (3.0 * PI_D / 4.0) / (double)(1 << j);
    double sg = 0.8 * (double)(1 << j);
    double ct = cos(theta), st = sin(theta);
    double u = ct * wx + st * wy;
    double v = -st * wx + ct * wy;
    double vs = v / 0.5;
    double s2 = 0.5 * sg * sg;
    double gab = exp(-s2 * ((u - xi) * (u - xi) + vs * vs));
    double gau = exp(-s2 * (u * u + vs * vs));
    double kap = exp(-s2 * xi * xi);
    out[i] = (float)(gab - kap * gau);
}

__global__ void k_phi(float* phi0, float* phi1) {
    int i = blockIdx.x * blockDim.x + threadIdx.x;
    const double sp = 1.6;
    const double s2 = 0.5 * sp * sp;
    if (i < IMG224) {
        int r = i / 224, c = i % 224;
        double fr = (r < 112) ? (double)r : (double)(r - 224);
        double fc = (c < 112) ? (double)c : (double)(c - 224);
        double wx = 2.0 * PI_D * fr / 224.0;
        double wy = 2.0 * PI_D * fc / 224.0;
        phi0[i] = (float)exp(-s2 * (wx * wx + wy * wy));
    } else if (i < IMG224 + IMG112) {
        int p = i - IMG224, a = p / 112, b = p % 112;
        double sum = 0.0;
        for (int ii = 0; ii < 2; ++ii)
            for (int jj = 0; jj < 2; ++jj) {
                int r = a + 112 * ii, c = b + 112 * jj;
                double fr = (r < 112) ? (double)r : (double)(r - 224);
                double fc = (c < 112) ? (double)c : (double)(c - 224);
                double wx = 2.0 * PI_D * fr / 224.0;
                double wy = 2.0 * PI_D * fc / 224.0;
                sum += exp(-s2 * (wx * wx + wy * wy));
            }
        phi1[p] = (float)(0.25 * sum);
    }
}

__global__ void k_zero(unsigned* gk, int n) {
    int i = blockIdx.x * blockDim.x + threadIdx.x;
    if (i < n) gk[i] = 0u;
}

// ---------------- rk: row pass, two-stage (N=N1*N2), fused in LDS (R8..R17-proven) ----
// R18: staging r-loops unrolled for memory-level parallelism (hot rk was latency-bound
// on staging loads at VALU 24%, HBM 20%: 8 serial iters x 8 loads -> all in flight).
template<int N1, int N2, int TA, int FOLD, int BS, bool REAL, int SGN>
__global__ __launch_bounds__(BS) void rk(
    const void* __restrict__ inBase, int inShift,
    const float* __restrict__ fltBase, int fltMask,
    const float2* __restrict__ FT, float2* __restrict__ out,
    int swzImg, int inStride, int inOff)
{
    constexpr int N = N1 * N2;
    constexpr int NIN = N * FOLD;
    constexpr int ZS = N + 2;
    constexpr int TS = N2 * (N1 + 1);
    constexpr int K1H = N1 / 2;
    __shared__ float2 Z[TA * ZS];
    __shared__ float2 T[TA * TS];
    const float2* W2 = FT + N1 * N1;
    const float2* TW = FT + N1 * N1 + N2 * N2;
    const int bx = blockIdx.x, a0 = blockIdx.y * TA, t = threadIdx.x;
    int gIn, gFlt, gOut;
    if (swzImg > 0) {
        int img = bx % swzImg, sub = bx / swzImg;
        gIn = img * inStride + inOff + (sub >> 3);
        gFlt = sub & fltMask;
        gOut = img * (gridDim.x / swzImg) + sub;
    } else {
        gIn = bx >> inShift; gFlt = bx & fltMask; gOut = bx;
    }

    if (REAL) {
        const float* in = (const float*)inBase + (size_t)gIn * N * N;
#pragma unroll
        for (int r = 0; r < TA; ++r)
            for (int b = t; b < N; b += BS)
                Z[r * ZS + b] = make_float2(in[(size_t)(a0 + r) * N + b], 0.f);
    } else {
        const float2* in = (const float2*)inBase + (size_t)gIn * (NIN * NIN);
        const float* flt = fltBase + (size_t)gFlt * (NIN * NIN);
        const float s = 1.0f / (float)(FOLD * FOLD);
#pragma unroll
        for (int r = 0; r < TA; ++r) {
            int a = a0 + r;
            for (int b = t; b < N; b += BS) {
                float re = 0.f, im = 0.f;
#pragma unroll
                for (int i = 0; i < FOLD; ++i)
#pragma unroll
                    for (int j = 0; j < FOLD; ++j) {
                        int idx = (a + N * i) * NIN + (b + N * j);
                        float2 v = in[idx];
                        float f = flt[idx];
                        re += v.x * f; im += v.y * f;
                    }
                Z[r * ZS + b] = make_float2(re * s, im * s);
            }
        }
    }
    __syncthreads();
    for (int idx = t; idx < TA * N2 * 2; idx += BS) {
        int r = idx / (N2 * 2);
        int rem = idx % (N2 * 2);
        int n2 = rem / 2, h = rem % 2;
        float2 xx[N1];
#pragma unroll
        for (int n1 = 0; n1 < N1; ++n1) xx[n1] = Z[r * ZS + n1 * N2 + n2];
        if constexpr (N1 == 16) fft16<SGN>(xx); else fft8<SGN>(xx);
#pragma unroll
        for (int kk = 0; kk < K1H; ++kk) {
            int k1 = h * K1H + kk;
            float2 tw = TW[n2 * N1 + k1];
            T[r * TS + n2 * (N1 + 1) + k1] = cmulc(xx[k1], tw.x, tw.y);
        }
    }
    __syncthreads();
    if constexpr (N2 == 14) {
        const float2* W7  = FT + N1 * N1 + N2 * N2 + N2 * N1;
        const float2* T14 = W7 + 49;
        for (int idx = t; idx < TA * N1; idx += BS) {
            int r = idx / N1, k1 = idx % N1;
            float2 E[7], O[7];
#pragma unroll
            for (int k = 0; k < 7; ++k) { E[k] = make_float2(0.f, 0.f); O[k] = make_float2(0.f, 0.f); }
            for (int m = 0; m < 7; ++m) {
                float2 te = T[r * TS + (2 * m) * (N1 + 1) + k1];
                float2 to = T[r * TS + (2 * m + 1) * (N1 + 1) + k1];
#pragma unroll
                for (int k = 0; k < 7; ++k) {
                    float2 w = W7[m * 7 + k];
                    cmac(E[k], te, w);
                    cmac(O[k], to, w);
                }
            }
#pragma unroll
            for (int k = 0; k < 14; ++k) {
                float2 tw = T14[k];
                float2 o_ = O[k % 7];
                float2 X = E[k % 7];
                X.x += o_.x * tw.x - o_.y * tw.y;
                X.y += o_.x * tw.y + o_.y * tw.x;
                Z[r * ZS + k1 + N1 * k] = X;
            }
        }
    } else {
        for (int idx = t; idx < TA * N1; idx += BS) {
            int r = idx / N1, k1 = idx % N1;
            float2 acc[N2];
#pragma unroll
            for (int kk = 0; kk < N2; ++kk) acc[kk] = make_float2(0.f, 0.f);
            for (int n2 = 0; n2 < N2; ++n2) {
                float2 tv = T[r * TS + n2 * (N1 + 1) + k1];
#pragma unroll
                for (int kk = 0; kk < N2; ++kk) cmac(acc[kk], tv, W2[n2 * N2 + kk]);
            }
#pragma unroll
            for (int kk = 0; kk < N2; ++kk) Z[r * ZS + k1 + N1 * kk] = acc[kk];
        }
    }
    __syncthreads();
#pragma unroll
    for (int r = 0; r < TA; ++r) {
        float2* o = out + ((size_t)gOut * N + (a0 + r)) * N;
        for (int b = t; b < N; b += BS) o[b] = Z[r * ZS + b];
    }
}

// ---------------- ck1: col pass stage 1 — fft16 columns (R13-proven) ----------------
template<int N1, int N2, int SPLIT, int BS, int SGN>
__global__ __launch_bounds__(BS) void ck1(
    const float2* __restrict__ in, const float2* __restrict__ FT, float2* __restrict__ out)
{
    constexpr int N = N1 * N2;
    constexpr int NC = N / SPLIT;
    const float2* TW = FT + N1 * N1 + N2 * N2;
    const int g = blockIdx.x / SPLIT, half = blockIdx.x % SPLIT;
    const int n2 = blockIdx.y, t = threadIdx.x;
    if (2 * t >= NC) return;
    const int b0 = 2 * t + half * NC;
    const float2* I = in + (size_t)g * N * N;
    float2 a0[16], a1[16];
#pragma unroll
    for (int n1 = 0; n1 < 16; ++n1) {
        float4 v = *reinterpret_cast<const float4*>(&I[(size_t)(n1 * N2 + n2) * N + b0]);
        a0[n1] = make_float2(v.x, v.y);
        a1[n1] = make_float2(v.z, v.w);
    }
    fft16<SGN>(a0);
    fft16<SGN>(a1);
#pragma unroll
    for (int k1 = 0; k1 < 16; ++k1) {
        float2 tw = TW[n2 * N1 + k1];
        float2 r0 = cmulc(a0[k1], tw.x, tw.y);
        float2 r1 = cmulc(a1[k1], tw.x, tw.y);
        *reinterpret_cast<float4*>(&out[((size_t)g * N + (k1 * N2 + n2)) * N + b0]) =
            make_float4(r0.x, r0.y, r1.x, r1.y);
    }
}

// ---------------- ck2: col pass stage 2 + MODE (R14: N2=14 DIT; N2=7 dense) ----------------
template<int N1, int N2, int SPLIT, int MODE, int BS>
__global__ __launch_bounds__(BS) void ck2(
    const float2* __restrict__ in, const float2* __restrict__ FT,
    float2* __restrict__ outc, float* __restrict__ outr)
{
    constexpr int N = N1 * N2;
    constexpr int NC = N / SPLIT;
    const float2* W2 = FT + N1 * N1;
    const int g = blockIdx.x / SPLIT, half = blockIdx.x % SPLIT;
    const int k1 = blockIdx.y, t = threadIdx.x;
    if (2 * t >= NC) return;
    const int b0 = 2 * t + half * NC;
    const float2* I = in + (size_t)g * N * N;
    if constexpr (N2 == 14) {
        const float2* W7  = FT + N1 * N1 + N2 * N2 + N2 * N1;
        const float2* T14 = W7 + 49;
        float2 E0[7], E1[7], O0[7], O1[7];
#pragma unroll
        for (int k = 0; k < 7; ++k) {
            E0[k] = make_float2(0.f, 0.f); E1[k] = make_float2(0.f, 0.f);
            O0[k] = make_float2(0.f, 0.f); O1[k] = make_float2(0.f, 0.f);
        }
#pragma unroll
        for (int m = 0; m < 7; ++m) {
            float4 ve = *reinterpret_cast<const float4*>(&I[(size_t)(k1 * 14 + 2 * m) * N + b0]);
            float4 vo = *reinterpret_cast<const float4*>(&I[(size_t)(k1 * 14 + 2 * m + 1) * N + b0]);
            float2 ve0 = make_float2(ve.x, ve.y), ve1 = make_float2(ve.z, ve.w);
            float2 vo0 = make_float2(vo.x, vo.y), vo1 = make_float2(vo.z, vo.w);
#pragma unroll
            for (int k = 0; k < 7; ++k) {
                float2 w = W7[m * 7 + k];
                cmac(E0[k], ve0, w); cmac(E1[k], ve1, w);
                cmac(O0[k], vo0, w); cmac(O1[k], vo1, w);
            }
        }
#pragma unroll
        for (int k = 0; k < 14; ++k) {
            float2 tw = T14[k];
            float2 r0 = E0[k % 7], r1 = E1[k % 7];
            float2 o0 = O0[k % 7], o1 = O1[k % 7];
            r0.x += o0.x * tw.x - o0.y * tw.y;
            r0.y += o0.x * tw.y + o0.y * tw.x;
            r1.x += o1.x * tw.x - o1.y * tw.y;
            r1.y += o1.x * tw.y + o1.y * tw.x;
            if (MODE == 0) {
                *reinterpret_cast<float4*>(&outc[((size_t)g * N + (k1 + N1 * k)) * N + b0]) =
                    make_float4(r0.x, r0.y, r1.x, r1.y);
            } else {
                size_t o = ((size_t)g * N + (k1 + N1 * k)) * N + b0;
                outr[o]     = sqrtf(r0.x * r0.x + r0.y * r0.y);
                outr[o + 1] = sqrtf(r1.x * r1.x + r1.y * r1.y);
            }
        }
    } else {
        float2 acc[N2][2];
#pragma unroll
        for (int k2 = 0; k2 < N2; ++k2) { acc[k2][0] = make_float2(0.f, 0.f); acc[k2][1] = make_float2(0.f, 0.f); }
#pragma unroll
        for (int n2 = 0; n2 < N2; ++n2) {
            float4 v = *reinterpret_cast<const float4*>(&I[(size_t)(k1 * N2 + n2) * N + b0]);
            float2 v0 = make_float2(v.x, v.y), v1 = make_float2(v.z, v.w);
#pragma unroll
            for (int k2 = 0; k2 < N2; ++k2) {
                float2 w = W2[n2 * N2 + k2];
                cmac(acc[k2][0], v0, w);
                cmac(acc[k2][1], v1, w);
            }
        }
        if (MODE == 0) {
#pragma unroll
            for (int k2 = 0; k2 < N2; ++k2)
                *reinterpret_cast<float4*>(&outc[((size_t)g * N + (k1 + N1 * k2)) * N + b0]) =
                    make_float4(acc[k2][0].x, acc[k2][0].y, acc[k2][1].x, acc[k2][1].y);
        } else {
#pragma unroll
            for (int k2 = 0; k2 < N2; ++k2) {
                size_t o = ((size_t)g * N + (k1 + N1 * k2)) * N + b0;
                outr[o]     = sqrtf(acc[k2][0].x * acc[k2][0].x + acc[k2][0].y * acc[k2][0].y);
                outr[o + 1] = sqrtf(acc[k2][1].x * acc[k2][1].x + acc[k2][1].y * acc[k2][1].y);
            }
        }
    }
}

// ---------------- s56max: fused fold*phi -> ifft2(56) via 8x7 -> Re -> max -> atomicMax ----
template<int FOLD, int BS>
__global__ __launch_bounds__(BS) void s56max(
    const float2* __restrict__ in, const float* __restrict__ flt,
    const float2* __restrict__ FT, unsigned* __restrict__ gk,
    int slotBase, int slotShift, int slotMask)
{
    constexpr int N = 56, NIN = 56 * FOLD, ZS = 57;
    __shared__ float2 Z[N * ZS];
    __shared__ float2 T[N * ZS];
    __shared__ float red[BS / 64];
    const float2* W2 = FT + 64;        // 7x7, scale 1/56
    const float2* TW = FT + 64 + 49;   // 7x8
    const int g = blockIdx.x, t = threadIdx.x;
    const float2* I = in + (size_t)g * NIN * NIN;
    const float s = 1.0f / (float)(FOLD * FOLD);
#pragma unroll 4
    for (int idx = t; idx < N * N; idx += BS) {
        int r = idx / N, b = idx % N;
        float re = 0.f, im = 0.f;
#pragma unroll
        for (int i = 0; i < FOLD; ++i)
#pragma unroll
            for (int j = 0; j < FOLD; ++j) {
                int p = (r + N * i) * NIN + (b + N * j);
                float2 v = I[p];
                float f = flt[p];
                re += v.x * f; im += v.y * f;
            }
        Z[r * ZS + b] = make_float2(re * s, im * s);
    }
    __syncthreads();
    for (int idx = t; idx < 7 * N; idx += BS) {
        int n2 = idx / N, r = idx % N;
        float2 xx[8];
#pragma unroll
        for (int n1 = 0; n1 < 8; ++n1) xx[n1] = Z[r * ZS + n1 * 7 + n2];
        fft8<1>(xx);
#pragma unroll
        for (int k1 = 0; k1 < 8; ++k1) {
            float2 tw = TW[n2 * 8 + k1];
            T[r * ZS + k1 * 7 + n2] = cmulc(xx[k1], tw.x, tw.y);
        }
    }
    __syncthreads();
    for (int idx = t; idx < 8 * N; idx += BS) {
        int k1 = idx / N, r = idx % N;
        float2 tv[7];
#pragma unroll
        for (int n2 = 0; n2 < 7; ++n2) tv[n2] = T[r * ZS + k1 * 7 + n2];
#pragma unroll
        for (int k2 = 0; k2 < 7; ++k2) {
            float2 acc = make_float2(0.f, 0.f);
#pragma unroll
            for (int n2 = 0; n2 < 7; ++n2) cmac(acc, tv[n2], W2[n2 * 7 + k2]);
            Z[r * ZS + k1 + 8 * k2] = acc;
        }
    }
    __syncthreads();
    for (int idx = t; idx < 7 * N; idx += BS) {
        int n2 = idx / N, b = idx % N;
        float2 xx[8];
#pragma unroll
        for (int n1 = 0; n1 < 8; ++n1) xx[n1] = Z[(n1 * 7 + n2) * ZS + b];
        fft8<1>(xx);
#pragma unroll
        for (int k1 = 0; k1 < 8; ++k1) {
            float2 tw = TW[n2 * 8 + k1];
            T[(k1 * 7 + n2) * ZS + b] = cmulc(xx[k1], tw.x, tw.y);
        }
    }
    __syncthreads();
    float m = -INFINITY;
    for (int idx = t; idx < 8 * N; idx += BS) {
        int k1 = idx / N, b = idx % N;
        float2 tv[7];
#pragma unroll
        for (int n2 = 0; n2 < 7; ++n2) tv[n2] = T[(k1 * 7 + n2) * ZS + b];
#pragma unroll
        for (int k2 = 0; k2 < 7; ++k2) {
            float re = 0.f;
#pragma unroll
            for (int n2 = 0; n2 < 7; ++n2) {
                float2 w = W2[n2 * 7 + k2];
                re += tv[n2].x * w.x - tv[n2].y * w.y;
            }
            m = fmaxf(m, re);
        }
    }
    for (int off = 32; off > 0; off >>= 1) m = fmaxf(m, __shfl_down(m, off, 64));
    if ((t & 63) == 0) red[t >> 6] = m;
    __syncthreads();
    if (t == 0) {
#pragma unroll
        for (int w = 1; w < BS / 64; ++w) m = fmaxf(m, red[w]);
        int slot = slotBase + ((g >> slotShift) * 81) + (g & slotMask);
        atomicMax(&gk[slot], fkey(m));
    }
}

// ---------------- classifier head ----------------
__global__ void k_linear(const unsigned* __restrict__ gk, const float* __restrict__ Wl,
                         const float* __restrict__ bl, float* __restrict__ out)
{
    int i = blockIdx.x * blockDim.x + threadIdx.x;
    if (i >= 16 * 1000) return;
    int b = i / 1000, o = i % 1000;
    float s = bl[o];
    for (int f = 0; f < 243; ++f)
        s += funkey(gk[b * 243 + f]) * Wl[o * 243 + f];
    out[i] = s;
}

// ---------------- launch ----------------
extern "C" void kernel_launch(void* const* d_in, const int* in_sizes, int n_in,
                              void* d_out, int out_size, void* d_ws, size_t ws_size,
                              hipStream_t stream)
{
    const float* x  = (const float*)d_in[0];
    const float* Wl = (const float*)d_in[1];
    const float* bl = (const float*)d_in[2];
    float* out = (float*)d_out;
    float* ws = (float*)d_ws;

    float2* FT224F = (float2*)(ws + OFF_FT224F);
    float2* FT224I = (float2*)(ws + OFF_FT224I);
    float2* FT112F = (float2*)(ws + OFF_FT112F);
    float2* FT112I = (float2*)(ws + OFF_FT112I);
    float2* FT56I  = (float2*)(ws + OFF_FT56I);
    float* PSI0 = ws + OFF_PSI;
    float* PSI1 = ws + OFF_PSI + 8 * IMG224;
    float* PHI0 = ws + OFF_PHI0;
    float* PHI1 = ws + OFF_PHI1;
    unsigned* GK = (unsigned*)(ws + OFF_GK);
    float2* XH  = (float2*)(ws + OFF_XH);
    float* A0  = ws + OFF_POOL;                       // 9633792 floats (V1 pair)

    const size_t NEED_BATCH = OFF_POOL + 9633792 + 2 * (size_t)19267584;
    const bool batch = (ws_size / 4) >= NEED_BATCH;   // R16: measured to fit
    float* A1  = A0 + 9633792;
    float* A23 = A1 + (batch ? 19267584 : 9633792);

    // tables
    k_fact<<<4, 256, 0, stream>>>(FT224F, 16, 14, -1.0, 1.0, 1);
    k_fact<<<4, 256, 0, stream>>>(FT224I, 16, 14,  1.0, 1.0 / 224.0, 1);
    k_fact<<<4, 256, 0, stream>>>(FT112F, 16, 7,  -1.0, 1.0, 0);
    k_fact<<<4, 256, 0, stream>>>(FT112I, 16, 7,   1.0, 1.0 / 112.0, 0);
    k_fact<<<1, 256, 0, stream>>>(FT56I,  8, 7,    1.0, 1.0 / 56.0, 0);
    k_psi<<<(16 * IMG224 + 255) / 256, 256, 0, stream>>>(ws + OFF_PSI);
    k_phi<<<(IMG224 + IMG112 + 255) / 256, 256, 0, stream>>>(PHI0, PHI1);
    k_zero<<<(3888 + 255) / 256, 256, 0, stream>>>(GK, 3888);

    // ---- fft2(x) -> XH ----
    rk<16, 14, 4, 1, 128, true, -1><<<dim3(48, 56), 128, 0, stream>>>(x, 0, nullptr, 0, FT224F, (float2*)A0, 0, 0, 0);
    ck1<16, 14, 2, 64, -1><<<dim3(96, 14), 64, 0, stream>>>((float2*)A0, FT224F, (float2*)A1);
    ck2<16, 14, 2, 0, 64><<<dim3(96, 16), 64, 0, stream>>>((float2*)A1, FT224F, XH, nullptr);

    // ---- s0 -> GK slot img*81+0 ----
    s56max<4, 256><<<48, 256, 0, stream>>>(XH, PHI0, FT56I, GK, 0, 0, 0);

    // ---- pair-batched first order j1=0 (+ second order); g = img*2 + lc, l1 = 2c+lc ----
    for (int c = 0; c < 4; ++c) {
        // A: ifft rows of xh*psi0[l1] -> A0 (96 groups)
        rk<16, 14, 4, 1, 128, false, 1><<<dim3(96, 56), 128, 0, stream>>>(
            XH, 1, PSI0 + (size_t)(2 * c) * IMG224, 1, FT224I, (float2*)A0, 0, 0, 0);
        // B: ifft cols + |.| -> A23 (real u1)
        ck1<16, 14, 2, 64, 1><<<dim3(192, 14), 64, 0, stream>>>((float2*)A0, FT224I, (float2*)A1);
        ck2<16, 14, 2, 1, 64><<<dim3(192, 16), 64, 0, stream>>>((float2*)A1, FT224I, nullptr, A23);
        // C: fft rows of u1 (real) -> A0
        rk<16, 14, 4, 1, 128, true, -1><<<dim3(96, 56), 128, 0, stream>>>(A23, 0, nullptr, 0, FT224F, (float2*)A0, 0, 0, 0);
        // D: fft cols -> V1 (A0)
        ck1<16, 14, 2, 64, -1><<<dim3(192, 14), 64, 0, stream>>>((float2*)A0, FT224F, (float2*)A1);
        ck2<16, 14, 2, 0, 64><<<dim3(192, 16), 64, 0, stream>>>((float2*)A1, FT224F, (float2*)A0, nullptr);
        // E: s1 -> GK slot img*81 + 1 + 2c + lc
        s56max<4, 256><<<96, 256, 0, stream>>>((float2*)A0, PHI0, FT56I, GK, 1 + 2 * c, 1, 1);
        if (batch) {
            // second order, both lc at once: 768 groups, g = img*16 + lc*8 + l2
            rk<16, 7, 8, 2, 128, false, 1><<<dim3(768, 14), 128, 0, stream>>>(
                (float2*)A0, 0, PSI1, 7, FT112I, (float2*)A1, 48, 2, 0);
            ck1<16, 7, 1, 64, 1><<<dim3(768, 7), 64, 0, stream>>>((float2*)A1, FT112I, (float2*)A23);
            ck2<16, 7, 1, 1, 64><<<dim3(768, 16), 64, 0, stream>>>((float2*)A23, FT112I, nullptr, A1);
            rk<16, 7, 8, 1, 128, true, -1><<<dim3(768, 14), 128, 0, stream>>>(A1, 0, nullptr, 0, FT112F, (float2*)A23, 0, 0, 0);
            ck1<16, 7, 1, 64, -1><<<dim3(768, 7), 64, 0, stream>>>((float2*)A23, FT112F, (float2*)A1);
            ck2<16, 7, 1, 0, 64><<<dim3(768, 16), 64, 0, stream>>>((float2*)A1, FT112F, (float2*)A23, nullptr);
            s56max<2, 256><<<768, 256, 0, stream>>>((float2*)A23, PHI1, FT56I, GK, 17 + 16 * c, 4, 15);
        } else {
            for (int lc = 0; lc < 2; ++lc) {
                int l1 = 2 * c + lc;
                rk<16, 7, 8, 2, 128, false, 1><<<dim3(384, 14), 128, 0, stream>>>(
                    (float2*)A0, 0, PSI1, 7, FT112I, (float2*)A1, 48, 2, lc);
                ck1<16, 7, 1, 64, 1><<<dim3(384, 7), 64, 0, stream>>>((float2*)A1, FT112I, (float2*)A23);
                ck2<16, 7, 1, 1, 64><<<dim3(384, 16), 64, 0, stream>>>((float2*)A23, FT112I, nullptr, A1);
                rk<16, 7, 8, 1, 128, true, -1><<<dim3(384, 14), 128, 0, stream>>>(A1, 0, nullptr, 0, FT112F, (float2*)A23, 0, 0, 0);
                ck1<16, 7, 1, 64, -1><<<dim3(384, 7), 64, 0, stream>>>((float2*)A23, FT112F, (float2*)A1);
                ck2<16, 7, 1, 0, 64><<<dim3(384, 16), 64, 0, stream>>>((float2*)A1, FT112F, (float2*)A23, nullptr);
                s56max<2, 256><<<384, 256, 0, stream>>>((float2*)A23, PHI1, FT56I, GK, 17 + 8 * l1, 3, 7);
            }
        }
    }

    // ---- first order j1=1 (8 orientations, g = img*8+l) ----
    rk<16, 7, 8, 2, 128, false, 1><<<dim3(384, 14), 128, 0, stream>>>(XH, 0, PSI1, 7, FT112I, (float2*)A1, 48, 1, 0);
    ck1<16, 7, 1, 64, 1><<<dim3(384, 7), 64, 0, stream>>>((float2*)A1, FT112I, (float2*)A23);
    ck2<16, 7, 1, 1, 64><<<dim3(384, 16), 64, 0, stream>>>((float2*)A23, FT112I, nullptr, A1);
    rk<16, 7, 8, 1, 128, true, -1><<<dim3(384, 14), 128, 0, stream>>>(A1, 0, nullptr, 0, FT112F, (float2*)A23, 0, 0, 0);
    ck1<16, 7, 1, 64, -1><<<dim3(384, 7), 64, 0, stream>>>((float2*)A23, FT112F, (float2*)A1);
    ck2<16, 7, 1, 0, 64><<<dim3(384, 16), 64, 0, stream>>>((float2*)A1, FT112F, (float2*)A23, nullptr);
    s56max<2, 256><<<384, 256, 0, stream>>>((float2*)A23, PHI1, FT56I, GK, 9, 3, 7);

    // head
    k_linear<<<(16000 + 255) / 256, 256, 0, stream>>>(GK, Wl, bl, out);
}